// Round 1
// baseline (2743.736 us; speedup 1.0000x reference)
//
#include <hip/hip_runtime.h>
#include <hip/hip_bf16.h>

#define NB 32  // num_graphs (in_sizes[9]==1, value fixed by harness setup)

__device__ __forceinline__ float wave_sum(float v) {
#pragma unroll
  for (int off = 32; off; off >>= 1) v += __shfl_xor(v, off);
  return v;
}

// ---- out[rows,128] = X[rows,128] @ W[128,128] (+ bias) ----
__global__ __launch_bounds__(256) void gemm128(const float* __restrict__ X,
                                               const float* __restrict__ W,
                                               const float* __restrict__ bias,
                                               float* __restrict__ out, int rows) {
  __shared__ float xs[8][128];
  const int t = threadIdx.x;
  const int row = t >> 5, c4 = t & 31;
  const float4* W4 = (const float4*)W;
  float4 b4 = make_float4(0.f, 0.f, 0.f, 0.f);
  if (bias) b4 = ((const float4*)bias)[c4];
  const int r0 = blockIdx.x * 64;
  for (int rb = 0; rb < 64; rb += 8) {
    const int rr = r0 + rb + row;
    __syncthreads();
    if (rr < rows) ((float4*)xs[row])[c4] = ((const float4*)X)[(size_t)rr * 32 + c4];
    __syncthreads();
    if (rr < rows) {
      float4 acc = b4;
#pragma unroll 16
      for (int k = 0; k < 128; k++) {
        const float xv = xs[row][k];
        const float4 w4 = W4[k * 32 + c4];
        acc.x = fmaf(xv, w4.x, acc.x);
        acc.y = fmaf(xv, w4.y, acc.y);
        acc.z = fmaf(xv, w4.z, acc.z);
        acc.w = fmaf(xv, w4.w, acc.w);
      }
      ((float4*)out)[(size_t)rr * 32 + c4] = acc;
    }
  }
}

__global__ void count_nnz(const int* __restrict__ ni, const int* __restrict__ ei,
                          float* cnt_n, float* cnt_e, int nnz) {
  int i = blockIdx.x * blockDim.x + threadIdx.x;
  if (i < nnz) {
    atomicAdd(&cnt_n[ni[i]], 1.f);
    atomicAdd(&cnt_e[ei[i]], 1.f);
  }
}

__global__ void count_idx(const int* __restrict__ idx, float* cnt, int n) {
  int i = blockIdx.x * blockDim.x + threadIdx.x;
  if (i < n) atomicAdd(&cnt[idx[i]], 1.f);
}

// one wave per incidence pair: scatter xw->e_conv, ew->z_conv, coord->ec_sum, phi
__global__ __launch_bounds__(256) void scatter_nnz(
    const float* __restrict__ xw, const float* __restrict__ ew,
    const float* __restrict__ coord, const int* __restrict__ ni,
    const int* __restrict__ ei, float* e_conv, float* z_conv, float* ec_sum,
    float* phi, int nnz) {
  const int w = (blockIdx.x * blockDim.x + threadIdx.x) >> 6;
  const int lane = threadIdx.x & 63;
  if (w >= nnz) return;
  const int n = ni[w], e = ei[w];
  const float2 a = ((const float2*)xw)[(size_t)n * 64 + lane];
  const float2 b = ((const float2*)ew)[(size_t)e * 64 + lane];
  atomicAdd(&e_conv[(size_t)e * 128 + lane * 2], a.x);
  atomicAdd(&e_conv[(size_t)e * 128 + lane * 2 + 1], a.y);
  atomicAdd(&z_conv[(size_t)n * 128 + lane * 2], b.x);
  atomicAdd(&z_conv[(size_t)n * 128 + lane * 2 + 1], b.y);
  float dot = wave_sum(fmaf(a.x, b.x, a.y * b.y));
  if (lane == 0) phi[w] = tanhf(dot * 0.08838834764831845f);  // 1/sqrt(128)
  if (lane < 3) atomicAdd(&ec_sum[e * 3 + lane], coord[n * 3 + lane]);
}

__global__ void div_cnt(float* buf, const float* __restrict__ cnt, long rows, int C) {
  long i = (long)blockIdx.x * blockDim.x + threadIdx.x;
  if (i < rows * C) buf[i] /= fmaxf(cnt[i / C], 1.f);
}

__global__ void scatter_rel(const float* __restrict__ coord,
                            const float* __restrict__ ec,
                            const float* __restrict__ phi,
                            const int* __restrict__ ni, const int* __restrict__ ei,
                            float* relphi, int nnz) {
  int j = blockIdx.x * blockDim.x + threadIdx.x;
  if (j >= nnz) return;
  int n = ni[j], e = ei[j];
  float p = phi[j];
#pragma unroll
  for (int c = 0; c < 3; c++)
    atomicAdd(&relphi[n * 3 + c], (coord[n * 3 + c] - ec[e * 3 + c]) * p);
}

__global__ void coord_fin(const float* __restrict__ coord,
                          const float* __restrict__ relphi,
                          const float* __restrict__ cnt_n, float* out, int n3) {
  int i = blockIdx.x * blockDim.x + threadIdx.x;
  if (i < n3) out[i] = coord[i] + relphi[i] / fmaxf(cnt_n[i / 3], 1.f);
}

// one wave per graph edge: out[dst] += rsqrt(deg_s*deg_d) * xw[src]
__global__ __launch_bounds__(256) void gcn_scatter(const float* __restrict__ xw,
                                                   const int* __restrict__ src,
                                                   const int* __restrict__ dst,
                                                   const float* __restrict__ indeg,
                                                   float* out, int ne) {
  const int w = (blockIdx.x * blockDim.x + threadIdx.x) >> 6;
  const int lane = threadIdx.x & 63;
  if (w >= ne) return;
  const int s = src[w], d = dst[w];
  const float nrm = rsqrtf((1.f + indeg[s]) * (1.f + indeg[d]));
  const float2 v = ((const float2*)xw)[(size_t)s * 64 + lane];
  atomicAdd(&out[(size_t)d * 128 + lane * 2], nrm * v.x);
  atomicAdd(&out[(size_t)d * 128 + lane * 2 + 1], nrm * v.y);
}

__global__ void gcn_fin(float* out, const float* __restrict__ xw,
                        const float* __restrict__ indeg,
                        const float* __restrict__ bias, long rows) {
  long i = (long)blockIdx.x * blockDim.x + threadIdx.x;
  if (i >= rows * 128) return;
  int r = (int)(i >> 7), c = (int)(i & 127);
  out[i] += xw[i] / (1.f + indeg[r]) + bias[c];
}

__global__ __launch_bounds__(128) void colstats(const float* __restrict__ Z, int n,
                                                float* sum, float* ssq) {
  const int c = threadIdx.x;
  const int r0 = blockIdx.x * 512;
  const int re = min(r0 + 512, n);
  float s = 0.f, q = 0.f;
  for (int r = r0; r < re; r++) {
    float v = Z[(size_t)r * 128 + c];
    s += v;
    q = fmaf(v, v, q);
  }
  atomicAdd(&sum[c], s);
  atomicAdd(&ssq[c], q);
}

// G[128][128] += Z1^T Z2 over a 256-row chunk per block
__global__ __launch_bounds__(256) void gram128(const float* __restrict__ Z1,
                                               const float* __restrict__ Z2, int n,
                                               float* G) {
  __shared__ float4 s1[256], s2[256];  // 8 rows x 32 float4 each
  const int t = threadIdx.x;
  const int ti = t >> 4, tj = t & 15;
  float acc[8][8];
#pragma unroll
  for (int i = 0; i < 8; i++)
#pragma unroll
    for (int j = 0; j < 8; j++) acc[i][j] = 0.f;
  const int r0 = blockIdx.x * 256;
  const int rend = min(r0 + 256, n);
  for (int rb = r0; rb < rend; rb += 8) {
    const int nr = min(8, rend - rb);
    __syncthreads();
    if (t < nr * 32) {
      const int rr = rb + (t >> 5);
      s1[t] = ((const float4*)Z1)[(size_t)rr * 32 + (t & 31)];
      s2[t] = ((const float4*)Z2)[(size_t)rr * 32 + (t & 31)];
    }
    __syncthreads();
    for (int r = 0; r < nr; r++) {
      const float4 a0 = s1[r * 32 + ti * 2], a1 = s1[r * 32 + ti * 2 + 1];
      const float4 b0 = s2[r * 32 + tj * 2], b1 = s2[r * 32 + tj * 2 + 1];
      const float av[8] = {a0.x, a0.y, a0.z, a0.w, a1.x, a1.y, a1.z, a1.w};
      const float bv[8] = {b0.x, b0.y, b0.z, b0.w, b1.x, b1.y, b1.z, b1.w};
#pragma unroll
      for (int i = 0; i < 8; i++)
#pragma unroll
        for (int j = 0; j < 8; j++) acc[i][j] = fmaf(av[i], bv[j], acc[i][j]);
    }
  }
#pragma unroll
  for (int i = 0; i < 8; i++)
#pragma unroll
    for (int j = 0; j < 8; j++)
      atomicAdd(&G[(ti * 8 + i) * 128 + (tj * 8 + j)], acc[i][j]);
}

// closed-form barlow: a = (z-mu)/(sigma_unbiased*sqrt((n-1)/n + eps))
__global__ __launch_bounds__(256) void barlow_fin(
    const float* __restrict__ G, const float* __restrict__ sum1,
    const float* __restrict__ ssq1, const float* __restrict__ sum2,
    const float* __restrict__ ssq2, float n, float* out) {
  __shared__ float s1s[128], m1s[128], s2s[128], m2s[128];
  __shared__ float red[256];
  const int t = threadIdx.x;
  if (t < 128) {
    const float inv_n = 1.f / n;
    const float bnf = (n - 1.f) * inv_n + 1e-5f;
    float mu = sum1[t] * inv_n;
    float vu = (ssq1[t] * inv_n - mu * mu) * n / (n - 1.f);
    s1s[t] = rsqrtf(vu * bnf);
    m1s[t] = mu;
    mu = sum2[t] * inv_n;
    vu = (ssq2[t] * inv_n - mu * mu) * n / (n - 1.f);
    s2s[t] = rsqrtf(vu * bnf);
    m2s[t] = mu;
  }
  __syncthreads();
  float on = 0.f, off = 0.f;
  for (int idx = t; idx < 16384; idx += 256) {
    const int i = idx >> 7, j = idx & 127;
    const float c = s1s[i] * s2s[j] * (G[idx] - n * m1s[i] * m2s[j]) * (1.f / 32.f);
    if (i == j) {
      const float dd = c - 1.f;
      on += dd * dd;
    } else {
      off += c * c;
    }
  }
  red[t] = on + 0.005f * off;
  __syncthreads();
  for (int s = 128; s; s >>= 1) {
    if (t < s) red[t] += red[t + s];
    __syncthreads();
  }
  if (t == 0) atomicAdd(out, red[0]);
}

// wave per row: layernorm -> exact gelu -> + residual
__global__ __launch_bounds__(256) void ln_gelu_res(
    const float* __restrict__ conv, const float* __restrict__ resid,
    const float* __restrict__ g, const float* __restrict__ b, float* out, int rows) {
  const int w = (blockIdx.x * blockDim.x + threadIdx.x) >> 6;
  const int lane = threadIdx.x & 63;
  if (w >= rows) return;
  const float2 v = ((const float2*)conv)[(size_t)w * 64 + lane];
  const float m = wave_sum(v.x + v.y) * (1.f / 128.f);
  const float q = wave_sum(fmaf(v.x, v.x, v.y * v.y)) * (1.f / 128.f);
  const float rstd = rsqrtf(q - m * m + 1e-5f);
  const float2 gg = ((const float2*)g)[lane];
  const float2 bb = ((const float2*)b)[lane];
  const float2 rr = ((const float2*)resid)[(size_t)w * 64 + lane];
  float y0 = fmaf(gg.x, (v.x - m) * rstd, bb.x);
  float y1 = fmaf(gg.y, (v.y - m) * rstd, bb.y);
  y0 = 0.5f * y0 * (1.f + erff(y0 * 0.7071067811865476f));
  y1 = 0.5f * y1 * (1.f + erff(y1 * 0.7071067811865476f));
  float2 o;
  o.x = y0 + rr.x;
  o.y = y1 + rr.y;
  ((float2*)out)[(size_t)w * 64 + lane] = o;
}

// sorted-segment pooling: thread=col, block walks 256 consecutive rows
__global__ __launch_bounds__(128) void seg_pool(const float* __restrict__ Z,
                                                const int* __restrict__ bidx, int n,
                                                float* pool) {
  const int c = threadIdx.x;
  const int r0 = blockIdx.x * 256;
  const int re = min(r0 + 256, n);
  float acc = 0.f;
  int cur = bidx[r0];
  for (int r = r0; r < re; r++) {
    const int bb = bidx[r];
    if (bb != cur) {
      atomicAdd(&pool[cur * 128 + c], acc);
      acc = 0.f;
      cur = bb;
    }
    acc += Z[(size_t)r * 128 + c];
  }
  atomicAdd(&pool[cur * 128 + c], acc);
}

__global__ __launch_bounds__(128) void graph_gemm(
    const float* __restrict__ zg, const float* __restrict__ eg,
    const float* __restrict__ cnz, const float* __restrict__ cne,
    const float* __restrict__ Wf, const float* __restrict__ bf, float* out) {
  __shared__ float cat[256];
  const int g = blockIdx.x, t = threadIdx.x;
  cat[t] = zg[g * 128 + t] / fmaxf(cnz[g], 1.f);
  cat[128 + t] = eg[g * 128 + t] / fmaxf(cne[g], 1.f);
  __syncthreads();
  float acc = bf[t];
#pragma unroll 8
  for (int k = 0; k < 256; k++) acc = fmaf(cat[k], Wf[k * 128 + t], acc);
  out[g * 128 + t] = acc;
}

extern "C" void kernel_launch(void* const* d_in, const int* in_sizes, int n_in,
                              void* d_out, int out_size, void* d_ws, size_t ws_size,
                              hipStream_t stream) {
  const float* x = (const float*)d_in[0];
  const float* hf = (const float*)d_in[1];
  const float* coord = (const float*)d_in[2];
  const int* ni = (const int*)d_in[3];
  const int* ei = (const int*)d_in[4];
  const int* nb = (const int*)d_in[5];
  const int* hb = (const int*)d_in[6];
  const int* xx = (const int*)d_in[7];
  const int* ee = (const int*)d_in[8];
  const float* Wv = (const float*)d_in[10];
  const float* bv = (const float*)d_in[11];
  const float* We = (const float*)d_in[12];
  const float* be = (const float*)d_in[13];
  const float* Wx = (const float*)d_in[14];
  const float* bx = (const float*)d_in[15];
  const float* Weg = (const float*)d_in[16];
  const float* beg = (const float*)d_in[17];
  const float* lng = (const float*)d_in[18];
  const float* lnb = (const float*)d_in[19];
  const float* Wf = (const float*)d_in[20];
  const float* bf = (const float*)d_in[21];

  const int N = in_sizes[0] / 128;
  const int M = in_sizes[1] / 128;
  const int NNZ = in_sizes[3];
  const int EG = in_sizes[7] / 2;
  const int EE = in_sizes[8] / 2;

  float* ws = (float*)d_ws;
  size_t o = 0;
  float* xw = ws + o;   o += (size_t)N * 128;
  float* ew = ws + o;   o += (size_t)M * 128;
  float* xw2 = ws + o;  o += (size_t)N * 128;
  float* ew2 = ws + o;  o += (size_t)M * 128;
  float* phi = ws + o;  o += NNZ;
  const size_t acc0 = o;
  float* z_conv = ws + o;  o += (size_t)N * 128;
  float* e_conv = ws + o;  o += (size_t)M * 128;
  float* ec = ws + o;      o += (size_t)M * 3;
  float* relphi = ws + o;  o += (size_t)N * 3;
  float* cnt_n = ws + o;   o += N;
  float* cnt_e = ws + o;   o += M;
  float* indeg_n = ws + o; o += N;
  float* indeg_e = ws + o; o += M;
  float* G1 = ws + o;      o += 16384;
  float* G2 = ws + o;      o += 16384;
  float* st = ws + o;      o += 1024;  // [8][128] colsum/colssq x4
  float* zg = ws + o;      o += NB * 128;
  float* eg = ws + o;      o += NB * 128;
  float* cbn = ws + o;     o += NB;
  float* cbe = ws + o;     o += NB;

  float* outz = (float*)d_out;               // temporarily holds z_imp
  float* oute = outz + (size_t)N * 128;      // temporarily holds e_imp
  float* outc = oute + (size_t)M * 128;
  float* outg = outc + (size_t)N * 3;
  float* outbt = outg + NB * 128;

  hipMemsetAsync(d_out, 0, (size_t)out_size * 4, stream);
  hipMemsetAsync(ws + acc0, 0, (o - acc0) * 4, stream);

  // GEMMs
  gemm128<<<(N + 63) / 64, 256, 0, stream>>>(x, Wv, bv, xw, N);
  gemm128<<<(M + 63) / 64, 256, 0, stream>>>(hf, We, be, ew, M);
  gemm128<<<(N + 63) / 64, 256, 0, stream>>>(x, Wx, nullptr, xw2, N);
  gemm128<<<(M + 63) / 64, 256, 0, stream>>>(hf, Weg, nullptr, ew2, M);

  // counts / degrees
  count_nnz<<<(NNZ + 255) / 256, 256, 0, stream>>>(ni, ei, cnt_n, cnt_e, NNZ);
  count_idx<<<(EG + 255) / 256, 256, 0, stream>>>(xx + EG, indeg_n, EG);
  count_idx<<<(EE + 255) / 256, 256, 0, stream>>>(ee + EE, indeg_e, EE);
  count_idx<<<(N + 255) / 256, 256, 0, stream>>>(nb, cbn, N);
  count_idx<<<(M + 255) / 256, 256, 0, stream>>>(hb, cbe, M);

  // hypergraph bipartite scatter + coord update
  scatter_nnz<<<(NNZ + 3) / 4, 256, 0, stream>>>(xw, ew, coord, ni, ei, e_conv,
                                                 z_conv, ec, phi, NNZ);
  div_cnt<<<(int)(((size_t)M * 128 + 255) / 256), 256, 0, stream>>>(e_conv, cnt_e, M, 128);
  div_cnt<<<(int)(((size_t)N * 128 + 255) / 256), 256, 0, stream>>>(z_conv, cnt_n, N, 128);
  div_cnt<<<(M * 3 + 255) / 256, 256, 0, stream>>>(ec, cnt_e, M, 3);
  scatter_rel<<<(NNZ + 255) / 256, 256, 0, stream>>>(coord, ec, phi, ni, ei, relphi, NNZ);
  coord_fin<<<(N * 3 + 255) / 256, 256, 0, stream>>>(coord, relphi, cnt_n, outc, N * 3);

  // GCN branches (accumulate into d_out z/e regions = z_imp/e_imp)
  gcn_scatter<<<(EG + 3) / 4, 256, 0, stream>>>(xw2, xx, xx + EG, indeg_n, outz, EG);
  gcn_scatter<<<(EE + 3) / 4, 256, 0, stream>>>(ew2, ee, ee + EE, indeg_e, oute, EE);
  gcn_fin<<<(int)(((size_t)N * 128 + 255) / 256), 256, 0, stream>>>(outz, xw2, indeg_n, bx, N);
  gcn_fin<<<(int)(((size_t)M * 128 + 255) / 256), 256, 0, stream>>>(oute, ew2, indeg_e, beg, M);

  // barlow-twins stats
  colstats<<<(N + 511) / 512, 128, 0, stream>>>(outz, N, st + 0 * 128, st + 1 * 128);
  colstats<<<(N + 511) / 512, 128, 0, stream>>>(z_conv, N, st + 2 * 128, st + 3 * 128);
  colstats<<<(M + 511) / 512, 128, 0, stream>>>(oute, M, st + 4 * 128, st + 5 * 128);
  colstats<<<(M + 511) / 512, 128, 0, stream>>>(e_conv, M, st + 6 * 128, st + 7 * 128);
  gram128<<<(N + 255) / 256, 256, 0, stream>>>(outz, z_conv, N, G1);
  gram128<<<(M + 255) / 256, 256, 0, stream>>>(oute, e_conv, M, G2);
  barlow_fin<<<1, 256, 0, stream>>>(G1, st + 0, st + 128, st + 256, st + 384, (float)N, outbt);
  barlow_fin<<<1, 256, 0, stream>>>(G2, st + 512, st + 640, st + 768, st + 896, (float)M, outbt);

  // final z/e (overwrite z_imp/e_imp regions AFTER barlow consumed them)
  ln_gelu_res<<<(N + 3) / 4, 256, 0, stream>>>(z_conv, x, lng, lnb, outz, N);
  ln_gelu_res<<<(M + 3) / 4, 256, 0, stream>>>(e_conv, hf, lng, lnb, oute, M);

  // graph pooling + output linear
  seg_pool<<<(N + 255) / 256, 128, 0, stream>>>(outz, nb, N, zg);
  seg_pool<<<(M + 255) / 256, 128, 0, stream>>>(oute, hb, M, eg);
  graph_gemm<<<NB, 128, 0, stream>>>(zg, eg, cbn, cbe, Wf, bf, outg);
}

// Round 2
// 1699.715 us; speedup vs baseline: 1.6142x; 1.6142x over previous
//
#include <hip/hip_runtime.h>
#include <hip/hip_bf16.h>

#define NB 32  // num_graphs

__device__ __forceinline__ float wave_sum(float v) {
#pragma unroll
  for (int off = 32; off; off >>= 1) v += __shfl_xor(v, off);
  return v;
}

// ---- out[rows,128] = X[rows,128] @ W[128,128] (+ bias) ----
__global__ __launch_bounds__(256) void gemm128(const float* __restrict__ X,
                                               const float* __restrict__ W,
                                               const float* __restrict__ bias,
                                               float* __restrict__ out, int rows) {
  __shared__ float xs[8][128];
  const int t = threadIdx.x;
  const int row = t >> 5, c4 = t & 31;
  const float4* W4 = (const float4*)W;
  float4 b4 = make_float4(0.f, 0.f, 0.f, 0.f);
  if (bias) b4 = ((const float4*)bias)[c4];
  const int r0 = blockIdx.x * 64;
  for (int rb = 0; rb < 64; rb += 8) {
    const int rr = r0 + rb + row;
    __syncthreads();
    if (rr < rows) ((float4*)xs[row])[c4] = ((const float4*)X)[(size_t)rr * 32 + c4];
    __syncthreads();
    if (rr < rows) {
      float4 acc = b4;
#pragma unroll 16
      for (int k = 0; k < 128; k++) {
        const float xv = xs[row][k];
        const float4 w4 = W4[k * 32 + c4];
        acc.x = fmaf(xv, w4.x, acc.x);
        acc.y = fmaf(xv, w4.y, acc.y);
        acc.z = fmaf(xv, w4.z, acc.z);
        acc.w = fmaf(xv, w4.w, acc.w);
      }
      ((float4*)out)[(size_t)rr * 32 + c4] = acc;
    }
  }
}

// ---------- CSR build ----------
__global__ void count_pairs(const int* __restrict__ ni, const int* __restrict__ ei,
                            int* cn, int* ce, int nnz) {
  int i = blockIdx.x * blockDim.x + threadIdx.x;
  if (i < nnz) {
    atomicAdd(&cn[ni[i]], 1);
    atomicAdd(&ce[ei[i]], 1);
  }
}

__global__ void count_dst(const int* __restrict__ dst, int* cnt, int ne) {
  int i = blockIdx.x * blockDim.x + threadIdx.x;
  if (i < ne) atomicAdd(&cnt[dst[i]], 1);
}

__global__ __launch_bounds__(1024) void exscan(const int* __restrict__ cnt,
                                               int* __restrict__ rowptr, int n) {
  __shared__ int part[1024];
  const int t = threadIdx.x;
  const int chunk = (n + 1023) >> 10;
  const int lo = t * chunk, hi = min(lo + chunk, n);
  int s = 0;
  for (int i = lo; i < hi; i++) s += cnt[i];
  part[t] = s;
  __syncthreads();
  for (int off = 1; off < 1024; off <<= 1) {
    int v = (t >= off) ? part[t - off] : 0;
    __syncthreads();
    part[t] += v;
    __syncthreads();
  }
  int base = (t == 0) ? 0 : part[t - 1];
  for (int i = lo; i < hi; i++) {
    rowptr[i] = base;
    base += cnt[i];
  }
  if (t == 1023) rowptr[n] = part[1023];
}

__global__ void copy_i32(const int* __restrict__ a, int* __restrict__ b, int n) {
  int i = blockIdx.x * blockDim.x + threadIdx.x;
  if (i < n) b[i] = a[i];
}

__global__ void fill_pairs(const int* __restrict__ ni, const int* __restrict__ ei,
                           int nnz, int* cur_n, int* cur_e, int* adj_n, int* adj_e) {
  int i = blockIdx.x * blockDim.x + threadIdx.x;
  if (i < nnz) {
    const int n = ni[i], e = ei[i];
    adj_n[atomicAdd(&cur_n[n], 1)] = e;
    adj_e[atomicAdd(&cur_e[e], 1)] = n;
  }
}

__global__ void fill_edges(const int* __restrict__ src, const int* __restrict__ dst,
                           int ne, int* cur, int* adj) {
  int i = blockIdx.x * blockDim.x + threadIdx.x;
  if (i < ne) adj[atomicAdd(&cur[dst[i]], 1)] = src[i];
}

__global__ void make_rs(const int* __restrict__ rowptr, float* __restrict__ rs, int n) {
  int i = blockIdx.x * blockDim.x + threadIdx.x;
  if (i < n) rs[i] = rsqrtf(1.f + (float)(rowptr[i + 1] - rowptr[i]));
}

__global__ void batch_counts(const int* __restrict__ idx, int n, int* __restrict__ cnt,
                             int nb) {
  int b = threadIdx.x;
  if (b >= nb) return;
  int lo = 0, hi = n;
  while (lo < hi) { int mid = (lo + hi) >> 1; if (idx[mid] < b) lo = mid + 1; else hi = mid; }
  const int l = lo;
  lo = 0; hi = n;
  while (lo < hi) { int mid = (lo + hi) >> 1; if (idx[mid] < b + 1) lo = mid + 1; else hi = mid; }
  cnt[b] = lo - l;
}

// ---------- gathers ----------
// hyperedge update: e_conv[e] = mean xw[n], ecoord[e] = mean coord[n]
__global__ __launch_bounds__(256) void hedge_gather(
    const float* __restrict__ xw, const float* __restrict__ coord,
    const int* __restrict__ rowptr, const int* __restrict__ adj,
    float* __restrict__ e_conv, float* __restrict__ ecoord, int m) {
  const int e = (blockIdx.x * blockDim.x + threadIdx.x) >> 6;
  const int lane = threadIdx.x & 63;
  if (e >= m) return;
  const int lo = rowptr[e], hi = rowptr[e + 1];
  float2 acc = make_float2(0.f, 0.f);
  float cacc = 0.f;
  for (int base = lo; base < hi; base += 64) {
    const int mm = min(64, hi - base);
    int aj = (base + lane < hi) ? adj[base + lane] : 0;
    for (int j = 0; j < mm; j++) {
      const int nidx = __shfl(aj, j);
      const float2 v = ((const float2*)xw)[(size_t)nidx * 64 + lane];
      acc.x += v.x;
      acc.y += v.y;
      if (lane < 3) cacc += coord[nidx * 3 + lane];
    }
  }
  const float inv = 1.f / fmaxf((float)(hi - lo), 1.f);
  ((float2*)e_conv)[(size_t)e * 64 + lane] = make_float2(acc.x * inv, acc.y * inv);
  if (lane < 3) ecoord[e * 3 + lane] = cacc * inv;
}

// node update: z_conv[n] = mean ew[e]; outc = coord + mean((coord-ecoord)*phi)
__global__ __launch_bounds__(256) void node_gather(
    const float* __restrict__ ew, const float* __restrict__ xw,
    const float* __restrict__ coord, const float* __restrict__ ecoord,
    const int* __restrict__ rowptr, const int* __restrict__ adj,
    float* __restrict__ z_conv, float* __restrict__ outc, int n) {
  const int r = (blockIdx.x * blockDim.x + threadIdx.x) >> 6;
  const int lane = threadIdx.x & 63;
  if (r >= n) return;
  const int lo = rowptr[r], hi = rowptr[r + 1];
  const float2 a = ((const float2*)xw)[(size_t)r * 64 + lane];
  const float myc = (lane < 3) ? coord[r * 3 + lane] : 0.f;
  float2 acc = make_float2(0.f, 0.f);
  float cacc = 0.f;
  for (int base = lo; base < hi; base += 64) {
    const int mm = min(64, hi - base);
    int aj = (base + lane < hi) ? adj[base + lane] : 0;
    for (int j = 0; j < mm; j++) {
      const int e = __shfl(aj, j);
      const float2 b = ((const float2*)ew)[(size_t)e * 64 + lane];
      acc.x += b.x;
      acc.y += b.y;
      const float dot = wave_sum(fmaf(a.x, b.x, a.y * b.y));
      const float ph = tanhf(dot * 0.08838834764831845f);  // 1/sqrt(128)
      if (lane < 3) cacc = fmaf(myc - ecoord[e * 3 + lane], ph, cacc);
    }
  }
  const float inv = 1.f / fmaxf((float)(hi - lo), 1.f);
  ((float2*)z_conv)[(size_t)r * 64 + lane] = make_float2(acc.x * inv, acc.y * inv);
  if (lane < 3) outc[r * 3 + lane] = myc + cacc * inv;
}

// GCN: out[d] = rs[d]*sum_s rs[s]*xw[s] + rs[d]^2*xw[d] + bias
__global__ __launch_bounds__(256) void gcn_gather(
    const float* __restrict__ xw, const int* __restrict__ rowptr,
    const int* __restrict__ adj, const float* __restrict__ rs,
    const float* __restrict__ bias, float* __restrict__ out, int n) {
  const int r = (blockIdx.x * blockDim.x + threadIdx.x) >> 6;
  const int lane = threadIdx.x & 63;
  if (r >= n) return;
  const int lo = rowptr[r], hi = rowptr[r + 1];
  const float rd = rs[r];
  float2 acc = make_float2(0.f, 0.f);
  for (int base = lo; base < hi; base += 64) {
    const int mm = min(64, hi - base);
    int aj = 0;
    float rj = 0.f;
    if (base + lane < hi) {
      aj = adj[base + lane];
      rj = rs[aj];
    }
    for (int j = 0; j < mm; j++) {
      const int s = __shfl(aj, j);
      const float w = __shfl(rj, j);
      const float2 v = ((const float2*)xw)[(size_t)s * 64 + lane];
      acc.x = fmaf(w, v.x, acc.x);
      acc.y = fmaf(w, v.y, acc.y);
    }
  }
  const float2 self = ((const float2*)xw)[(size_t)r * 64 + lane];
  const float2 bb = ((const float2*)bias)[lane];
  float2 o;
  o.x = fmaf(rd, acc.x, fmaf(rd * rd, self.x, bb.x));
  o.y = fmaf(rd, acc.y, fmaf(rd * rd, self.y, bb.y));
  ((float2*)out)[(size_t)r * 64 + lane] = o;
}

// ---------- barlow ----------
__global__ __launch_bounds__(128) void colstats(const float* __restrict__ Z, int n,
                                                float* sum, float* ssq) {
  const int c = threadIdx.x;
  const int r0 = blockIdx.x * 512;
  const int re = min(r0 + 512, n);
  float s = 0.f, q = 0.f;
  for (int r = r0; r < re; r++) {
    float v = Z[(size_t)r * 128 + c];
    s += v;
    q = fmaf(v, v, q);
  }
  atomicAdd(&sum[c], s);
  atomicAdd(&ssq[c], q);
}

__global__ __launch_bounds__(256) void gram128(const float* __restrict__ Z1,
                                               const float* __restrict__ Z2, int n,
                                               float* G) {
  __shared__ float4 s1[256], s2[256];
  const int t = threadIdx.x;
  const int ti = t >> 4, tj = t & 15;
  float acc[8][8];
#pragma unroll
  for (int i = 0; i < 8; i++)
#pragma unroll
    for (int j = 0; j < 8; j++) acc[i][j] = 0.f;
  const int r0 = blockIdx.x * 256;
  const int rend = min(r0 + 256, n);
  for (int rb = r0; rb < rend; rb += 8) {
    const int nr = min(8, rend - rb);
    __syncthreads();
    if (t < nr * 32) {
      const int rr = rb + (t >> 5);
      s1[t] = ((const float4*)Z1)[(size_t)rr * 32 + (t & 31)];
      s2[t] = ((const float4*)Z2)[(size_t)rr * 32 + (t & 31)];
    }
    __syncthreads();
    for (int r = 0; r < nr; r++) {
      const float4 a0 = s1[r * 32 + ti * 2], a1 = s1[r * 32 + ti * 2 + 1];
      const float4 b0 = s2[r * 32 + tj * 2], b1 = s2[r * 32 + tj * 2 + 1];
      const float av[8] = {a0.x, a0.y, a0.z, a0.w, a1.x, a1.y, a1.z, a1.w};
      const float bv[8] = {b0.x, b0.y, b0.z, b0.w, b1.x, b1.y, b1.z, b1.w};
#pragma unroll
      for (int i = 0; i < 8; i++)
#pragma unroll
        for (int j = 0; j < 8; j++) acc[i][j] = fmaf(av[i], bv[j], acc[i][j]);
    }
  }
#pragma unroll
  for (int i = 0; i < 8; i++)
#pragma unroll
    for (int j = 0; j < 8; j++)
      atomicAdd(&G[(ti * 8 + i) * 128 + (tj * 8 + j)], acc[i][j]);
}

__global__ __launch_bounds__(256) void barlow_fin(
    const float* __restrict__ G, const float* __restrict__ sum1,
    const float* __restrict__ ssq1, const float* __restrict__ sum2,
    const float* __restrict__ ssq2, float n, float* out) {
  __shared__ float s1s[128], m1s[128], s2s[128], m2s[128];
  __shared__ float red[256];
  const int t = threadIdx.x;
  if (t < 128) {
    const float inv_n = 1.f / n;
    const float bnf = (n - 1.f) * inv_n + 1e-5f;
    float mu = sum1[t] * inv_n;
    float vu = (ssq1[t] * inv_n - mu * mu) * n / (n - 1.f);
    s1s[t] = rsqrtf(vu * bnf);
    m1s[t] = mu;
    mu = sum2[t] * inv_n;
    vu = (ssq2[t] * inv_n - mu * mu) * n / (n - 1.f);
    s2s[t] = rsqrtf(vu * bnf);
    m2s[t] = mu;
  }
  __syncthreads();
  float on = 0.f, off = 0.f;
  for (int idx = t; idx < 16384; idx += 256) {
    const int i = idx >> 7, j = idx & 127;
    const float c = s1s[i] * s2s[j] * (G[idx] - n * m1s[i] * m2s[j]) * (1.f / 32.f);
    if (i == j) {
      const float dd = c - 1.f;
      on += dd * dd;
    } else {
      off += c * c;
    }
  }
  red[t] = on + 0.005f * off;
  __syncthreads();
  for (int s = 128; s; s >>= 1) {
    if (t < s) red[t] += red[t + s];
    __syncthreads();
  }
  if (t == 0) atomicAdd(out, red[0]);
}

// ---------- epilogue ----------
__global__ __launch_bounds__(256) void ln_gelu_res(
    const float* __restrict__ conv, const float* __restrict__ resid,
    const float* __restrict__ g, const float* __restrict__ b, float* out, int rows) {
  const int w = (blockIdx.x * blockDim.x + threadIdx.x) >> 6;
  const int lane = threadIdx.x & 63;
  if (w >= rows) return;
  const float2 v = ((const float2*)conv)[(size_t)w * 64 + lane];
  const float m = wave_sum(v.x + v.y) * (1.f / 128.f);
  const float q = wave_sum(fmaf(v.x, v.x, v.y * v.y)) * (1.f / 128.f);
  const float rstd = rsqrtf(q - m * m + 1e-5f);
  const float2 gg = ((const float2*)g)[lane];
  const float2 bb = ((const float2*)b)[lane];
  const float2 rr = ((const float2*)resid)[(size_t)w * 64 + lane];
  float y0 = fmaf(gg.x, (v.x - m) * rstd, bb.x);
  float y1 = fmaf(gg.y, (v.y - m) * rstd, bb.y);
  y0 = 0.5f * y0 * (1.f + erff(y0 * 0.7071067811865476f));
  y1 = 0.5f * y1 * (1.f + erff(y1 * 0.7071067811865476f));
  float2 o;
  o.x = y0 + rr.x;
  o.y = y1 + rr.y;
  ((float2*)out)[(size_t)w * 64 + lane] = o;
}

__global__ __launch_bounds__(128) void seg_pool(const float* __restrict__ Z,
                                                const int* __restrict__ bidx, int n,
                                                float* pool) {
  const int c = threadIdx.x;
  const int r0 = blockIdx.x * 256;
  const int re = min(r0 + 256, n);
  float acc = 0.f;
  int cur = bidx[r0];
  for (int r = r0; r < re; r++) {
    const int bb = bidx[r];
    if (bb != cur) {
      atomicAdd(&pool[cur * 128 + c], acc);
      acc = 0.f;
      cur = bb;
    }
    acc += Z[(size_t)r * 128 + c];
  }
  atomicAdd(&pool[cur * 128 + c], acc);
}

__global__ __launch_bounds__(128) void graph_gemm(
    const float* __restrict__ zg, const float* __restrict__ eg,
    const int* __restrict__ cnz, const int* __restrict__ cne,
    const float* __restrict__ Wf, const float* __restrict__ bf, float* out) {
  __shared__ float cat[256];
  const int g = blockIdx.x, t = threadIdx.x;
  cat[t] = zg[g * 128 + t] / fmaxf((float)cnz[g], 1.f);
  cat[128 + t] = eg[g * 128 + t] / fmaxf((float)cne[g], 1.f);
  __syncthreads();
  float acc = bf[t];
#pragma unroll 8
  for (int k = 0; k < 256; k++) acc = fmaf(cat[k], Wf[k * 128 + t], acc);
  out[g * 128 + t] = acc;
}

extern "C" void kernel_launch(void* const* d_in, const int* in_sizes, int n_in,
                              void* d_out, int out_size, void* d_ws, size_t ws_size,
                              hipStream_t stream) {
  const float* x = (const float*)d_in[0];
  const float* hf = (const float*)d_in[1];
  const float* coord = (const float*)d_in[2];
  const int* ni = (const int*)d_in[3];
  const int* ei = (const int*)d_in[4];
  const int* nb = (const int*)d_in[5];
  const int* hb = (const int*)d_in[6];
  const int* xx = (const int*)d_in[7];
  const int* ee = (const int*)d_in[8];
  const float* Wv = (const float*)d_in[10];
  const float* bv = (const float*)d_in[11];
  const float* We = (const float*)d_in[12];
  const float* be = (const float*)d_in[13];
  const float* Wx = (const float*)d_in[14];
  const float* bx = (const float*)d_in[15];
  const float* Weg = (const float*)d_in[16];
  const float* beg = (const float*)d_in[17];
  const float* lng = (const float*)d_in[18];
  const float* lnb = (const float*)d_in[19];
  const float* Wf = (const float*)d_in[20];
  const float* bf = (const float*)d_in[21];

  const int N = in_sizes[0] / 128;
  const int M = in_sizes[1] / 128;
  const int NNZ = in_sizes[3];
  const int EG = in_sizes[7] / 2;
  const int EE = in_sizes[8] / 2;

  float* ws = (float*)d_ws;
  size_t o = 0;
  float* xw = ws + o;     o += (size_t)N * 128;
  float* ew = ws + o;     o += (size_t)M * 128;
  float* xw2 = ws + o;    o += (size_t)N * 128;
  float* ew2 = ws + o;    o += (size_t)M * 128;
  float* z_conv = ws + o; o += (size_t)N * 128;
  float* e_conv = ws + o; o += (size_t)M * 128;
  float* ecoord = ws + o; o += (size_t)M * 3;
  float* rs_gx = ws + o;  o += N;
  float* rs_ge = ws + o;  o += M;
  const size_t fz0 = o;  // zeroed float block
  float* G1 = ws + o; o += 16384;
  float* G2 = ws + o; o += 16384;
  float* st = ws + o; o += 1024;
  float* zg = ws + o; o += NB * 128;
  float* eg = ws + o; o += NB * 128;
  const size_t fz1 = o;
  int* wsi = (int*)(ws + o);
  size_t oi = 0;
  int* cnt_n = wsi + oi;  oi += N;  // doubles as cursor after scan
  int* cnt_e = wsi + oi;  oi += M;
  int* cnt_gx = wsi + oi; oi += N;
  int* cnt_ge = wsi + oi; oi += M;
  const size_t iz1 = oi;
  int* rp_n = wsi + oi;   oi += N + 1;
  int* rp_e = wsi + oi;   oi += M + 1;
  int* rp_gx = wsi + oi;  oi += N + 1;
  int* rp_ge = wsi + oi;  oi += M + 1;
  int* adj_n = wsi + oi;  oi += NNZ;  // node -> incident hyperedges
  int* adj_e = wsi + oi;  oi += NNZ;  // hyperedge -> member nodes
  int* adj_gx = wsi + oi; oi += EG;
  int* adj_ge = wsi + oi; oi += EE;
  int* cbn = wsi + oi;    oi += NB;
  int* cbe = wsi + oi;    oi += NB;

  float* outz = (float*)d_out;           // temporarily z_imp
  float* oute = outz + (size_t)N * 128;  // temporarily e_imp
  float* outc = oute + (size_t)M * 128;
  float* outg = outc + (size_t)N * 3;
  float* outbt = outg + NB * 128;

  hipMemsetAsync(ws + fz0, 0, (fz1 - fz0) * 4, stream);
  hipMemsetAsync(wsi, 0, iz1 * 4, stream);
  hipMemsetAsync(outbt, 0, 4, stream);

  // dense projections
  gemm128<<<(N + 63) / 64, 256, 0, stream>>>(x, Wv, bv, xw, N);
  gemm128<<<(M + 63) / 64, 256, 0, stream>>>(hf, We, be, ew, M);
  gemm128<<<(N + 63) / 64, 256, 0, stream>>>(x, Wx, nullptr, xw2, N);
  gemm128<<<(M + 63) / 64, 256, 0, stream>>>(hf, Weg, nullptr, ew2, M);

  // CSR build
  count_pairs<<<(NNZ + 255) / 256, 256, 0, stream>>>(ni, ei, cnt_n, cnt_e, NNZ);
  count_dst<<<(EG + 255) / 256, 256, 0, stream>>>(xx + EG, cnt_gx, EG);
  count_dst<<<(EE + 255) / 256, 256, 0, stream>>>(ee + EE, cnt_ge, EE);
  exscan<<<1, 1024, 0, stream>>>(cnt_n, rp_n, N);
  exscan<<<1, 1024, 0, stream>>>(cnt_e, rp_e, M);
  exscan<<<1, 1024, 0, stream>>>(cnt_gx, rp_gx, N);
  exscan<<<1, 1024, 0, stream>>>(cnt_ge, rp_ge, M);
  copy_i32<<<(N + 255) / 256, 256, 0, stream>>>(rp_n, cnt_n, N);
  copy_i32<<<(M + 255) / 256, 256, 0, stream>>>(rp_e, cnt_e, M);
  copy_i32<<<(N + 255) / 256, 256, 0, stream>>>(rp_gx, cnt_gx, N);
  copy_i32<<<(M + 255) / 256, 256, 0, stream>>>(rp_ge, cnt_ge, M);
  fill_pairs<<<(NNZ + 255) / 256, 256, 0, stream>>>(ni, ei, NNZ, cnt_n, cnt_e, adj_n, adj_e);
  fill_edges<<<(EG + 255) / 256, 256, 0, stream>>>(xx, xx + EG, EG, cnt_gx, adj_gx);
  fill_edges<<<(EE + 255) / 256, 256, 0, stream>>>(ee, ee + EE, EE, cnt_ge, adj_ge);
  make_rs<<<(N + 255) / 256, 256, 0, stream>>>(rp_gx, rs_gx, N);
  make_rs<<<(M + 255) / 256, 256, 0, stream>>>(rp_ge, rs_ge, M);
  batch_counts<<<1, 64, 0, stream>>>(nb, N, cbn, NB);
  batch_counts<<<1, 64, 0, stream>>>(hb, M, cbe, NB);

  // hypergraph conv (gather form) + coord update
  hedge_gather<<<(M + 3) / 4, 256, 0, stream>>>(xw, coord, rp_e, adj_e, e_conv, ecoord, M);
  node_gather<<<(N + 3) / 4, 256, 0, stream>>>(ew, xw, coord, ecoord, rp_n, adj_n,
                                               z_conv, outc, N);

  // GCN branches (fused self-term + bias), results into d_out z/e regions
  gcn_gather<<<(N + 3) / 4, 256, 0, stream>>>(xw2, rp_gx, adj_gx, rs_gx, bx, outz, N);
  gcn_gather<<<(M + 3) / 4, 256, 0, stream>>>(ew2, rp_ge, adj_ge, rs_ge, beg, oute, M);

  // barlow-twins
  colstats<<<(N + 511) / 512, 128, 0, stream>>>(outz, N, st + 0 * 128, st + 1 * 128);
  colstats<<<(N + 511) / 512, 128, 0, stream>>>(z_conv, N, st + 2 * 128, st + 3 * 128);
  colstats<<<(M + 511) / 512, 128, 0, stream>>>(oute, M, st + 4 * 128, st + 5 * 128);
  colstats<<<(M + 511) / 512, 128, 0, stream>>>(e_conv, M, st + 6 * 128, st + 7 * 128);
  gram128<<<(N + 255) / 256, 256, 0, stream>>>(outz, z_conv, N, G1);
  gram128<<<(M + 255) / 256, 256, 0, stream>>>(oute, e_conv, M, G2);
  barlow_fin<<<1, 256, 0, stream>>>(G1, st + 0, st + 128, st + 256, st + 384, (float)N, outbt);
  barlow_fin<<<1, 256, 0, stream>>>(G2, st + 512, st + 640, st + 768, st + 896, (float)M, outbt);

  // final z/e (overwrite z_imp/e_imp AFTER barlow consumed them)
  ln_gelu_res<<<(N + 3) / 4, 256, 0, stream>>>(z_conv, x, lng, lnb, outz, N);
  ln_gelu_res<<<(M + 3) / 4, 256, 0, stream>>>(e_conv, hf, lng, lnb, oute, M);

  // pooling + output linear
  seg_pool<<<(N + 255) / 256, 128, 0, stream>>>(outz, nb, N, zg);
  seg_pool<<<(M + 255) / 256, 128, 0, stream>>>(oute, hb, M, eg);
  graph_gemm<<<NB, 128, 0, stream>>>(zg, eg, cbn, cbe, Wf, bf, outg);
}

// Round 3
// 960.607 us; speedup vs baseline: 2.8563x; 1.7694x over previous
//
#include <hip/hip_runtime.h>
#include <hip/hip_bf16.h>

#define NB 32      // num_graphs
#define GPARTS 512 // split-K parts for gram

__device__ __forceinline__ float wave_sum(float v) {
#pragma unroll
  for (int off = 32; off; off >>= 1) v += __shfl_xor(v, off);
  return v;
}

// ---- out[rows,128] = X[rows,128] @ W[128,128] (+ bias) ----
__global__ __launch_bounds__(256) void gemm128(const float* __restrict__ X,
                                               const float* __restrict__ W,
                                               const float* __restrict__ bias,
                                               float* __restrict__ out, int rows) {
  __shared__ float xs[8][128];
  const int t = threadIdx.x;
  const int row = t >> 5, c4 = t & 31;
  const float4* W4 = (const float4*)W;
  float4 b4 = make_float4(0.f, 0.f, 0.f, 0.f);
  if (bias) b4 = ((const float4*)bias)[c4];
  const int r0 = blockIdx.x * 64;
  for (int rb = 0; rb < 64; rb += 8) {
    const int rr = r0 + rb + row;
    __syncthreads();
    if (rr < rows) ((float4*)xs[row])[c4] = ((const float4*)X)[(size_t)rr * 32 + c4];
    __syncthreads();
    if (rr < rows) {
      float4 acc = b4;
#pragma unroll 16
      for (int k = 0; k < 128; k++) {
        const float xv = xs[row][k];
        const float4 w4 = W4[k * 32 + c4];
        acc.x = fmaf(xv, w4.x, acc.x);
        acc.y = fmaf(xv, w4.y, acc.y);
        acc.z = fmaf(xv, w4.z, acc.z);
        acc.w = fmaf(xv, w4.w, acc.w);
      }
      ((float4*)out)[(size_t)rr * 32 + c4] = acc;
    }
  }
}

// ---------- CSR build (fused) ----------
__global__ void count_all(const int* __restrict__ ni, const int* __restrict__ ei,
                          int nnz, const int* __restrict__ xx, int eg,
                          const int* __restrict__ ee, int eeN, int* cn, int* ce,
                          int* cgx, int* cge) {
  int i = blockIdx.x * blockDim.x + threadIdx.x;
  if (i < nnz) {
    atomicAdd(&cn[ni[i]], 1);
    atomicAdd(&ce[ei[i]], 1);
  } else if (i < nnz + eg) {
    atomicAdd(&cgx[xx[eg + (i - nnz)]], 1);
  } else if (i < nnz + eg + eeN) {
    atomicAdd(&cge[ee[eeN + (i - nnz - eg)]], 1);
  }
}

// 4 arrays in one launch: block b scans array b, writes rowptr, cursor(=in-place
// over cnt), and optional rsqrt(1+deg)
__global__ __launch_bounds__(1024) void exscan4(int* __restrict__ c0, int* rp0, float* rs0, int n0,
                                                int* __restrict__ c1, int* rp1, float* rs1, int n1,
                                                int* __restrict__ c2, int* rp2, float* rs2, int n2,
                                                int* __restrict__ c3, int* rp3, float* rs3, int n3) {
  __shared__ int part[1024];
  int* cnt;
  int* rowptr;
  float* rs;
  int n;
  switch (blockIdx.x) {
    case 0: cnt = c0; rowptr = rp0; rs = rs0; n = n0; break;
    case 1: cnt = c1; rowptr = rp1; rs = rs1; n = n1; break;
    case 2: cnt = c2; rowptr = rp2; rs = rs2; n = n2; break;
    default: cnt = c3; rowptr = rp3; rs = rs3; n = n3; break;
  }
  const int t = threadIdx.x;
  const int chunk = (n + 1023) >> 10;
  const int lo = t * chunk, hi = min(lo + chunk, n);
  int s = 0;
  for (int i = lo; i < hi; i++) s += cnt[i];
  part[t] = s;
  __syncthreads();
  for (int off = 1; off < 1024; off <<= 1) {
    int v = (t >= off) ? part[t - off] : 0;
    __syncthreads();
    part[t] += v;
    __syncthreads();
  }
  int base = (t == 0) ? 0 : part[t - 1];
  for (int i = lo; i < hi; i++) {
    const int c = cnt[i];
    rowptr[i] = base;
    cnt[i] = base;  // cursor for fill
    if (rs) rs[i] = rsqrtf(1.f + (float)c);
    base += c;
  }
  if (t == 1023) rowptr[n] = part[1023];
}

__global__ void fill_all(const int* __restrict__ ni, const int* __restrict__ ei,
                         int nnz, const int* __restrict__ xx, int eg,
                         const int* __restrict__ ee, int eeN, int* cur_n, int* cur_e,
                         int* cur_gx, int* cur_ge, int* adj_n, int* adj_e,
                         int* adj_gx, int* adj_ge) {
  int i = blockIdx.x * blockDim.x + threadIdx.x;
  if (i < nnz) {
    const int n = ni[i], e = ei[i];
    adj_n[atomicAdd(&cur_n[n], 1)] = e;
    adj_e[atomicAdd(&cur_e[e], 1)] = n;
  } else if (i < nnz + eg) {
    const int j = i - nnz;
    adj_gx[atomicAdd(&cur_gx[xx[eg + j]], 1)] = xx[j];
  } else if (i < nnz + eg + eeN) {
    const int j = i - nnz - eg;
    adj_ge[atomicAdd(&cur_ge[ee[eeN + j]], 1)] = ee[j];
  }
}

__global__ void batch_counts(const int* __restrict__ idx, int n, int* __restrict__ cnt,
                             int nb) {
  int b = threadIdx.x;
  if (b >= nb) return;
  int lo = 0, hi = n;
  while (lo < hi) { int mid = (lo + hi) >> 1; if (idx[mid] < b) lo = mid + 1; else hi = mid; }
  const int l = lo;
  lo = 0; hi = n;
  while (lo < hi) { int mid = (lo + hi) >> 1; if (idx[mid] < b + 1) lo = mid + 1; else hi = mid; }
  cnt[b] = lo - l;
}

// ---------- gathers ----------
__global__ __launch_bounds__(256) void hedge_gather(
    const float* __restrict__ xw, const float* __restrict__ coord,
    const int* __restrict__ rowptr, const int* __restrict__ adj,
    float* __restrict__ e_conv, float* __restrict__ ecoord, int m) {
  const int e = (blockIdx.x * blockDim.x + threadIdx.x) >> 6;
  const int lane = threadIdx.x & 63;
  if (e >= m) return;
  const int lo = rowptr[e], hi = rowptr[e + 1];
  float2 acc = make_float2(0.f, 0.f);
  float cacc = 0.f;
  for (int base = lo; base < hi; base += 64) {
    const int mm = min(64, hi - base);
    int aj = (base + lane < hi) ? adj[base + lane] : 0;
    for (int j = 0; j < mm; j++) {
      const int nidx = __shfl(aj, j);
      const float2 v = ((const float2*)xw)[(size_t)nidx * 64 + lane];
      acc.x += v.x;
      acc.y += v.y;
      if (lane < 3) cacc += coord[nidx * 3 + lane];
    }
  }
  const float inv = 1.f / fmaxf((float)(hi - lo), 1.f);
  ((float2*)e_conv)[(size_t)e * 64 + lane] = make_float2(acc.x * inv, acc.y * inv);
  if (lane < 3) ecoord[e * 3 + lane] = cacc * inv;
}

__global__ __launch_bounds__(256) void node_gather(
    const float* __restrict__ ew, const float* __restrict__ xw,
    const float* __restrict__ coord, const float* __restrict__ ecoord,
    const int* __restrict__ rowptr, const int* __restrict__ adj,
    float* __restrict__ z_conv, float* __restrict__ outc, int n) {
  const int r = (blockIdx.x * blockDim.x + threadIdx.x) >> 6;
  const int lane = threadIdx.x & 63;
  if (r >= n) return;
  const int lo = rowptr[r], hi = rowptr[r + 1];
  const float2 a = ((const float2*)xw)[(size_t)r * 64 + lane];
  const float myc = (lane < 3) ? coord[r * 3 + lane] : 0.f;
  float2 acc = make_float2(0.f, 0.f);
  float cacc = 0.f;
  for (int base = lo; base < hi; base += 64) {
    const int mm = min(64, hi - base);
    int aj = (base + lane < hi) ? adj[base + lane] : 0;
    for (int j = 0; j < mm; j++) {
      const int e = __shfl(aj, j);
      const float2 b = ((const float2*)ew)[(size_t)e * 64 + lane];
      acc.x += b.x;
      acc.y += b.y;
      const float dot = wave_sum(fmaf(a.x, b.x, a.y * b.y));
      const float ph = tanhf(dot * 0.08838834764831845f);  // 1/sqrt(128)
      if (lane < 3) cacc = fmaf(myc - ecoord[e * 3 + lane], ph, cacc);
    }
  }
  const float inv = 1.f / fmaxf((float)(hi - lo), 1.f);
  ((float2*)z_conv)[(size_t)r * 64 + lane] = make_float2(acc.x * inv, acc.y * inv);
  if (lane < 3) outc[r * 3 + lane] = myc + cacc * inv;
}

__global__ __launch_bounds__(256) void gcn_gather(
    const float* __restrict__ xw, const int* __restrict__ rowptr,
    const int* __restrict__ adj, const float* __restrict__ rs,
    const float* __restrict__ bias, float* __restrict__ out, int n) {
  const int r = (blockIdx.x * blockDim.x + threadIdx.x) >> 6;
  const int lane = threadIdx.x & 63;
  if (r >= n) return;
  const int lo = rowptr[r], hi = rowptr[r + 1];
  const float rd = rs[r];
  float2 acc = make_float2(0.f, 0.f);
  for (int base = lo; base < hi; base += 64) {
    const int mm = min(64, hi - base);
    int aj = 0;
    float rj = 0.f;
    if (base + lane < hi) {
      aj = adj[base + lane];
      rj = rs[aj];
    }
    for (int j = 0; j < mm; j++) {
      const int s = __shfl(aj, j);
      const float w = __shfl(rj, j);
      const float2 v = ((const float2*)xw)[(size_t)s * 64 + lane];
      acc.x = fmaf(w, v.x, acc.x);
      acc.y = fmaf(w, v.y, acc.y);
    }
  }
  const float2 self = ((const float2*)xw)[(size_t)r * 64 + lane];
  const float2 bb = ((const float2*)bias)[lane];
  float2 o;
  o.x = fmaf(rd, acc.x, fmaf(rd * rd, self.x, bb.x));
  o.y = fmaf(rd, acc.y, fmaf(rd * rd, self.y, bb.y));
  ((float2*)out)[(size_t)r * 64 + lane] = o;
}

// ---------- barlow: split-K gram + fused colstats ----------
__global__ __launch_bounds__(256) void gram_partial(
    const float* __restrict__ Z1, const float* __restrict__ Z2, int n,
    float* __restrict__ part, float* sum1, float* ssq1, float* sum2, float* ssq2) {
  __shared__ float4 s1[256], s2[256];
  const int t = threadIdx.x;
  const int ti = t >> 4, tj = t & 15;
  const int rpb = (n + GPARTS - 1) / GPARTS;
  const int lo = blockIdx.x * rpb, hi = min(lo + rpb, n);
  float acc[8][8];
#pragma unroll
  for (int i = 0; i < 8; i++)
#pragma unroll
    for (int j = 0; j < 8; j++) acc[i][j] = 0.f;
  float cs = 0.f, cq = 0.f;
  const float* s1f = (const float*)s1;
  const float* s2f = (const float*)s2;
  const int c = t & 127;
  const bool low = t < 128;
  for (int rb = lo; rb < hi; rb += 8) {
    const int nr = min(8, hi - rb);
    __syncthreads();
    if (t < nr * 32) {
      const int rr = rb + (t >> 5);
      s1[t] = ((const float4*)Z1)[(size_t)rr * 32 + (t & 31)];
      s2[t] = ((const float4*)Z2)[(size_t)rr * 32 + (t & 31)];
    }
    __syncthreads();
    for (int r = 0; r < nr; r++) {
      const float4 a0 = s1[r * 32 + ti * 2], a1 = s1[r * 32 + ti * 2 + 1];
      const float4 b0 = s2[r * 32 + tj * 2], b1 = s2[r * 32 + tj * 2 + 1];
      const float av[8] = {a0.x, a0.y, a0.z, a0.w, a1.x, a1.y, a1.z, a1.w};
      const float bv[8] = {b0.x, b0.y, b0.z, b0.w, b1.x, b1.y, b1.z, b1.w};
#pragma unroll
      for (int i = 0; i < 8; i++)
#pragma unroll
        for (int j = 0; j < 8; j++) acc[i][j] = fmaf(av[i], bv[j], acc[i][j]);
      const float v = low ? s1f[r * 128 + c] : s2f[r * 128 + c];
      cs += v;
      cq = fmaf(v, v, cq);
    }
  }
  float4* P = (float4*)(part + (size_t)blockIdx.x * 16384);
#pragma unroll
  for (int i = 0; i < 8; i++) {
    P[(ti * 8 + i) * 32 + tj * 2] = make_float4(acc[i][0], acc[i][1], acc[i][2], acc[i][3]);
    P[(ti * 8 + i) * 32 + tj * 2 + 1] = make_float4(acc[i][4], acc[i][5], acc[i][6], acc[i][7]);
  }
  if (low) {
    atomicAdd(&sum1[c], cs);
    atomicAdd(&ssq1[c], cq);
  } else {
    atomicAdd(&sum2[c], cs);
    atomicAdd(&ssq2[c], cq);
  }
}

__global__ __launch_bounds__(256) void gram_reduce(const float* __restrict__ part,
                                                   float* __restrict__ G) {
  const int e = blockIdx.x * 256 + threadIdx.x;  // grid 64
  float s = 0.f;
  for (int p = 0; p < GPARTS; p++) s += part[(size_t)p * 16384 + e];
  G[e] = s;
}

__global__ __launch_bounds__(256) void barlow_fin(
    const float* __restrict__ G, const float* __restrict__ sum1,
    const float* __restrict__ ssq1, const float* __restrict__ sum2,
    const float* __restrict__ ssq2, float n, float* out) {
  __shared__ float s1s[128], m1s[128], s2s[128], m2s[128];
  __shared__ float red[256];
  const int t = threadIdx.x;
  if (t < 128) {
    const float inv_n = 1.f / n;
    const float bnf = (n - 1.f) * inv_n + 1e-5f;
    float mu = sum1[t] * inv_n;
    float vu = (ssq1[t] * inv_n - mu * mu) * n / (n - 1.f);
    s1s[t] = rsqrtf(vu * bnf);
    m1s[t] = mu;
    mu = sum2[t] * inv_n;
    vu = (ssq2[t] * inv_n - mu * mu) * n / (n - 1.f);
    s2s[t] = rsqrtf(vu * bnf);
    m2s[t] = mu;
  }
  __syncthreads();
  float on = 0.f, off = 0.f;
  for (int idx = t; idx < 16384; idx += 256) {
    const int i = idx >> 7, j = idx & 127;
    const float c = s1s[i] * s2s[j] * (G[idx] - n * m1s[i] * m2s[j]) * (1.f / 32.f);
    if (i == j) {
      const float dd = c - 1.f;
      on += dd * dd;
    } else {
      off += c * c;
    }
  }
  red[t] = on + 0.005f * off;
  __syncthreads();
  for (int s = 128; s; s >>= 1) {
    if (t < s) red[t] += red[t + s];
    __syncthreads();
  }
  if (t == 0) atomicAdd(out, red[0]);
}

// ---------- epilogue ----------
__global__ __launch_bounds__(256) void ln_gelu_res(
    const float* __restrict__ conv, const float* __restrict__ resid,
    const float* __restrict__ g, const float* __restrict__ b, float* out, int rows) {
  const int w = (blockIdx.x * blockDim.x + threadIdx.x) >> 6;
  const int lane = threadIdx.x & 63;
  if (w >= rows) return;
  const float2 v = ((const float2*)conv)[(size_t)w * 64 + lane];
  const float m = wave_sum(v.x + v.y) * (1.f / 128.f);
  const float q = wave_sum(fmaf(v.x, v.x, v.y * v.y)) * (1.f / 128.f);
  const float rstd = rsqrtf(q - m * m + 1e-5f);
  const float2 gg = ((const float2*)g)[lane];
  const float2 bb = ((const float2*)b)[lane];
  const float2 rr = ((const float2*)resid)[(size_t)w * 64 + lane];
  float y0 = fmaf(gg.x, (v.x - m) * rstd, bb.x);
  float y1 = fmaf(gg.y, (v.y - m) * rstd, bb.y);
  y0 = 0.5f * y0 * (1.f + erff(y0 * 0.7071067811865476f));
  y1 = 0.5f * y1 * (1.f + erff(y1 * 0.7071067811865476f));
  float2 o;
  o.x = y0 + rr.x;
  o.y = y1 + rr.y;
  ((float2*)out)[(size_t)w * 64 + lane] = o;
}

__global__ __launch_bounds__(128) void seg_pool(const float* __restrict__ Z,
                                                const int* __restrict__ bidx, int n,
                                                float* pool) {
  const int c = threadIdx.x;
  const int r0 = blockIdx.x * 128;
  const int re = min(r0 + 128, n);
  if (r0 >= n) return;
  float acc = 0.f;
  int cur = bidx[r0];
  for (int r = r0; r < re; r++) {
    const int bb = bidx[r];
    if (bb != cur) {
      atomicAdd(&pool[cur * 128 + c], acc);
      acc = 0.f;
      cur = bb;
    }
    acc += Z[(size_t)r * 128 + c];
  }
  atomicAdd(&pool[cur * 128 + c], acc);
}

__global__ __launch_bounds__(128) void graph_gemm(
    const float* __restrict__ zg, const float* __restrict__ eg,
    const int* __restrict__ cnz, const int* __restrict__ cne,
    const float* __restrict__ Wf, const float* __restrict__ bf, float* out) {
  __shared__ float cat[256];
  const int g = blockIdx.x, t = threadIdx.x;
  cat[t] = zg[g * 128 + t] / fmaxf((float)cnz[g], 1.f);
  cat[128 + t] = eg[g * 128 + t] / fmaxf((float)cne[g], 1.f);
  __syncthreads();
  float acc = bf[t];
#pragma unroll 8
  for (int k = 0; k < 256; k++) acc = fmaf(cat[k], Wf[k * 128 + t], acc);
  out[g * 128 + t] = acc;
}

extern "C" void kernel_launch(void* const* d_in, const int* in_sizes, int n_in,
                              void* d_out, int out_size, void* d_ws, size_t ws_size,
                              hipStream_t stream) {
  const float* x = (const float*)d_in[0];
  const float* hf = (const float*)d_in[1];
  const float* coord = (const float*)d_in[2];
  const int* ni = (const int*)d_in[3];
  const int* ei = (const int*)d_in[4];
  const int* nb = (const int*)d_in[5];
  const int* hb = (const int*)d_in[6];
  const int* xx = (const int*)d_in[7];
  const int* ee = (const int*)d_in[8];
  const float* Wv = (const float*)d_in[10];
  const float* bv = (const float*)d_in[11];
  const float* We = (const float*)d_in[12];
  const float* be = (const float*)d_in[13];
  const float* Wx = (const float*)d_in[14];
  const float* bx = (const float*)d_in[15];
  const float* Weg = (const float*)d_in[16];
  const float* beg = (const float*)d_in[17];
  const float* lng = (const float*)d_in[18];
  const float* lnb = (const float*)d_in[19];
  const float* Wf = (const float*)d_in[20];
  const float* bf = (const float*)d_in[21];

  const int N = in_sizes[0] / 128;
  const int M = in_sizes[1] / 128;
  const int NNZ = in_sizes[3];
  const int EG = in_sizes[7] / 2;
  const int EE = in_sizes[8] / 2;

  float* ws = (float*)d_ws;
  size_t o = 0;
  float* xw = ws + o;     o += (size_t)N * 128;  // } these three (56MB) are dead by
  float* ew = ws + o;     o += (size_t)M * 128;  // } gram time -> reused as partials
  float* xw2 = ws + o;    o += (size_t)N * 128;
  float* ew2 = ws + o;    o += (size_t)M * 128;
  float* z_conv = ws + o; o += (size_t)N * 128;
  float* e_conv = ws + o; o += (size_t)M * 128;
  float* ecoord = ws + o; o += (size_t)M * 3;
  float* rs_gx = ws + o;  o += N;
  float* rs_ge = ws + o;  o += M;
  float* G1 = ws + o;     o += 16384;
  float* G2 = ws + o;     o += 16384;
  const size_t fz0 = o;  // zeroed float block
  float* st = ws + o;     o += 1024;
  float* zg = ws + o;     o += NB * 128;
  float* eg = ws + o;     o += NB * 128;
  const size_t fz1 = o;
  int* wsi = (int*)(ws + o);
  size_t oi = 0;
  int* cnt_n = wsi + oi;  oi += N;  // becomes cursor after exscan
  int* cnt_e = wsi + oi;  oi += M;
  int* cnt_gx = wsi + oi; oi += N;
  int* cnt_ge = wsi + oi; oi += M;
  const size_t iz1 = oi;
  int* rp_n = wsi + oi;   oi += N + 1;
  int* rp_e = wsi + oi;   oi += M + 1;
  int* rp_gx = wsi + oi;  oi += N + 1;
  int* rp_ge = wsi + oi;  oi += M + 1;
  int* adj_n = wsi + oi;  oi += NNZ;
  int* adj_e = wsi + oi;  oi += NNZ;
  int* adj_gx = wsi + oi; oi += EG;
  int* adj_ge = wsi + oi; oi += EE;
  int* cbn = wsi + oi;    oi += NB;
  int* cbe = wsi + oi;    oi += NB;

  float* gpart = xw;  // GPARTS*16384 floats = 33.6MB, aliases dead xw/ew/xw2

  float* outz = (float*)d_out;           // temporarily z_imp
  float* oute = outz + (size_t)N * 128;  // temporarily e_imp
  float* outc = oute + (size_t)M * 128;
  float* outg = outc + (size_t)N * 3;
  float* outbt = outg + NB * 128;

  hipMemsetAsync(ws + fz0, 0, (fz1 - fz0) * 4, stream);
  hipMemsetAsync(wsi, 0, iz1 * 4, stream);
  hipMemsetAsync(outbt, 0, 4, stream);

  // dense projections
  gemm128<<<(N + 63) / 64, 256, 0, stream>>>(x, Wv, bv, xw, N);
  gemm128<<<(M + 63) / 64, 256, 0, stream>>>(hf, We, be, ew, M);
  gemm128<<<(N + 63) / 64, 256, 0, stream>>>(x, Wx, nullptr, xw2, N);
  gemm128<<<(M + 63) / 64, 256, 0, stream>>>(hf, Weg, nullptr, ew2, M);

  // CSR build
  const int tot = NNZ + EG + EE;
  count_all<<<(tot + 255) / 256, 256, 0, stream>>>(ni, ei, NNZ, xx, EG, ee, EE,
                                                   cnt_n, cnt_e, cnt_gx, cnt_ge);
  exscan4<<<4, 1024, 0, stream>>>(cnt_n, rp_n, nullptr, N, cnt_e, rp_e, nullptr, M,
                                  cnt_gx, rp_gx, rs_gx, N, cnt_ge, rp_ge, rs_ge, M);
  fill_all<<<(tot + 255) / 256, 256, 0, stream>>>(ni, ei, NNZ, xx, EG, ee, EE, cnt_n,
                                                  cnt_e, cnt_gx, cnt_ge, adj_n, adj_e,
                                                  adj_gx, adj_ge);
  batch_counts<<<1, 64, 0, stream>>>(nb, N, cbn, NB);
  batch_counts<<<1, 64, 0, stream>>>(hb, M, cbe, NB);

  // hypergraph conv (gather form) + coord update
  hedge_gather<<<(M + 3) / 4, 256, 0, stream>>>(xw, coord, rp_e, adj_e, e_conv, ecoord, M);
  node_gather<<<(N + 3) / 4, 256, 0, stream>>>(ew, xw, coord, ecoord, rp_n, adj_n,
                                               z_conv, outc, N);

  // GCN branches into d_out z/e regions (z_imp/e_imp)
  gcn_gather<<<(N + 3) / 4, 256, 0, stream>>>(xw2, rp_gx, adj_gx, rs_gx, bx, outz, N);
  gcn_gather<<<(M + 3) / 4, 256, 0, stream>>>(ew2, rp_ge, adj_ge, rs_ge, beg, oute, M);

  // barlow-twins: split-K gram with fused column stats (xw/ew/xw2 now dead)
  gram_partial<<<GPARTS, 256, 0, stream>>>(outz, z_conv, N, gpart, st + 0, st + 128,
                                           st + 256, st + 384);
  gram_reduce<<<64, 256, 0, stream>>>(gpart, G1);
  gram_partial<<<GPARTS, 256, 0, stream>>>(oute, e_conv, M, gpart, st + 512, st + 640,
                                           st + 768, st + 896);
  gram_reduce<<<64, 256, 0, stream>>>(gpart, G2);
  barlow_fin<<<1, 256, 0, stream>>>(G1, st + 0, st + 128, st + 256, st + 384, (float)N, outbt);
  barlow_fin<<<1, 256, 0, stream>>>(G2, st + 512, st + 640, st + 768, st + 896, (float)M, outbt);

  // final z/e (overwrite z_imp/e_imp AFTER gram consumed them)
  ln_gelu_res<<<(N + 3) / 4, 256, 0, stream>>>(z_conv, x, lng, lnb, outz, N);
  ln_gelu_res<<<(M + 3) / 4, 256, 0, stream>>>(e_conv, hf, lng, lnb, oute, M);

  // pooling + output linear
  seg_pool<<<(N + 127) / 128, 128, 0, stream>>>(outz, nb, N, zg);
  seg_pool<<<(M + 127) / 128, 128, 0, stream>>>(oute, hb, M, eg);
  graph_gemm<<<NB, 128, 0, stream>>>(zg, eg, cbn, cbe, Wf, bf, outg);
}

// Round 4
// 905.168 us; speedup vs baseline: 3.0312x; 1.0612x over previous
//
#include <hip/hip_runtime.h>
#include <hip/hip_bf16.h>

#define NB 32      // num_graphs
#define GPN 512    // split-K parts for gram (N side)
#define GPM 128    // split-K parts for gram (M side)

__device__ __forceinline__ float wave_sum(float v) {
#pragma unroll
  for (int off = 32; off; off >>= 1) v += __shfl_xor(v, off);
  return v;
}
__device__ __forceinline__ int wave_sum_i(int v) {
#pragma unroll
  for (int off = 32; off; off >>= 1) v += __shfl_xor(v, off);
  return v;
}

// ---- fused dual GEMM: out1 = X@W1 + b1, out2 = X@W2 (shared X staging) ----
__global__ __launch_bounds__(256) void gemm128x2(const float* __restrict__ X,
                                                 const float* __restrict__ W1,
                                                 const float* __restrict__ b1,
                                                 float* __restrict__ out1,
                                                 const float* __restrict__ W2,
                                                 float* __restrict__ out2, int rows) {
  __shared__ float xs[8][128];
  const int t = threadIdx.x;
  const int row = t >> 5, c4 = t & 31;
  const float4* W1v = (const float4*)W1;
  const float4* W2v = (const float4*)W2;
  const float4 b4 = ((const float4*)b1)[c4];
  const int r0 = blockIdx.x * 64;
  for (int rb = 0; rb < 64; rb += 8) {
    const int rr = r0 + rb + row;
    __syncthreads();
    if (rr < rows) ((float4*)xs[row])[c4] = ((const float4*)X)[(size_t)rr * 32 + c4];
    __syncthreads();
    if (rr < rows) {
      float4 a1 = b4;
      float4 a2 = make_float4(0.f, 0.f, 0.f, 0.f);
#pragma unroll 8
      for (int k = 0; k < 128; k++) {
        const float xv = xs[row][k];
        const float4 w1 = W1v[k * 32 + c4];
        const float4 w2 = W2v[k * 32 + c4];
        a1.x = fmaf(xv, w1.x, a1.x);
        a1.y = fmaf(xv, w1.y, a1.y);
        a1.z = fmaf(xv, w1.z, a1.z);
        a1.w = fmaf(xv, w1.w, a1.w);
        a2.x = fmaf(xv, w2.x, a2.x);
        a2.y = fmaf(xv, w2.y, a2.y);
        a2.z = fmaf(xv, w2.z, a2.z);
        a2.w = fmaf(xv, w2.w, a2.w);
      }
      ((float4*)out1)[(size_t)rr * 32 + c4] = a1;
      ((float4*)out2)[(size_t)rr * 32 + c4] = a2;
    }
  }
}

// ---------- CSR build ----------
__global__ void count_all(const int* __restrict__ ni, const int* __restrict__ ei,
                          int nnz, const int* __restrict__ xx, int eg,
                          const int* __restrict__ ee, int eeN, int* cn, int* ce,
                          int* cgx, int* cge) {
  int i = blockIdx.x * blockDim.x + threadIdx.x;
  if (i < nnz) {
    atomicAdd(&cn[ni[i]], 1);
    atomicAdd(&ce[ei[i]], 1);
  } else if (i < nnz + eg) {
    atomicAdd(&cgx[xx[eg + (i - nnz)]], 1);
  } else if (i < nnz + eg + eeN) {
    atomicAdd(&cge[ee[eeN + (i - nnz - eg)]], 1);
  }
}

// ---- multi-block segmented exclusive scan over the 4 count arrays ----
// phase A: per-block totals (4096 elems/block, 16/thread)
__global__ __launch_bounds__(256) void scan_partial(
    const int* __restrict__ c0, int n0, const int* __restrict__ c1, int n1,
    const int* __restrict__ c2, int n2, const int* __restrict__ c3, int n3,
    int nb0, int nb1, int nb2, int nb3, int* __restrict__ bsums) {
  const int gb = blockIdx.x;
  const int* cnt;
  int lb, n;
  if (gb < nb0) { cnt = c0; lb = gb; n = n0; }
  else if (gb < nb0 + nb1) { cnt = c1; lb = gb - nb0; n = n1; }
  else if (gb < nb0 + nb1 + nb2) { cnt = c2; lb = gb - nb0 - nb1; n = n2; }
  else { cnt = c3; lb = gb - nb0 - nb1 - nb2; n = n3; }
  const int t = threadIdx.x;
  const int base = lb * 4096 + t * 16;
  int s = 0;
#pragma unroll
  for (int i = 0; i < 16; i++) {
    const int idx = base + i;
    if (idx < n) s += cnt[idx];
  }
  const int wsum = wave_sum_i(s);
  __shared__ int wsm[4];
  if ((t & 63) == 0) wsm[t >> 6] = wsum;
  __syncthreads();
  if (t == 0) bsums[gb] = wsm[0] + wsm[1] + wsm[2] + wsm[3];
}

// phase B: serial scan of per-block sums (tiny), segmented per array
__global__ void scan_bsums(const int* __restrict__ bsums, int nb0, int nb1, int nb2,
                           int nb3, int* __restrict__ bbase, int* __restrict__ totals) {
  if (threadIdx.x) return;
  int segs[4] = {nb0, nb1, nb2, nb3};
  int gb = 0;
  for (int a = 0; a < 4; a++) {
    int run = 0;
    for (int i = 0; i < segs[a]; i++) {
      bbase[gb] = run;
      run += bsums[gb];
      gb++;
    }
    totals[a] = run;
  }
}

// phase C: write rowptr + cursor (in place over cnt) + optional rsqrt(1+deg)
__global__ __launch_bounds__(256) void scan_final(
    int* __restrict__ c0, int* rp0, float* rs0, int n0,
    int* __restrict__ c1, int* rp1, float* rs1, int n1,
    int* __restrict__ c2, int* rp2, float* rs2, int n2,
    int* __restrict__ c3, int* rp3, float* rs3, int n3,
    int nb0, int nb1, int nb2, int nb3, const int* __restrict__ bbase,
    const int* __restrict__ totals) {
  const int gb = blockIdx.x;
  int* cnt;
  int* rp;
  float* rs;
  int lb, n, a;
  if (gb < nb0) { cnt = c0; rp = rp0; rs = rs0; lb = gb; n = n0; a = 0; }
  else if (gb < nb0 + nb1) { cnt = c1; rp = rp1; rs = rs1; lb = gb - nb0; n = n1; a = 1; }
  else if (gb < nb0 + nb1 + nb2) { cnt = c2; rp = rp2; rs = rs2; lb = gb - nb0 - nb1; n = n2; a = 2; }
  else { cnt = c3; rp = rp3; rs = rs3; lb = gb - nb0 - nb1 - nb2; n = n3; a = 3; }
  const int t = threadIdx.x;
  const int base = lb * 4096 + t * 16;
  int vals[16];
  int s = 0;
#pragma unroll
  for (int i = 0; i < 16; i++) {
    const int idx = base + i;
    vals[i] = (idx < n) ? cnt[idx] : 0;
    s += vals[i];
  }
  __shared__ int tsum[256];
  tsum[t] = s;
  __syncthreads();
  for (int off = 1; off < 256; off <<= 1) {
    const int v = (t >= off) ? tsum[t - off] : 0;
    __syncthreads();
    tsum[t] += v;
    __syncthreads();
  }
  int run = bbase[gb] + (t ? tsum[t - 1] : 0);
#pragma unroll
  for (int i = 0; i < 16; i++) {
    const int idx = base + i;
    if (idx < n) {
      rp[idx] = run;
      cnt[idx] = run;  // cursor for fill
      if (rs) rs[idx] = rsqrtf(1.f + (float)vals[i]);
      run += vals[i];
    }
  }
  if (t == 0 && lb == 0) rp[n] = totals[a];
}

__global__ void fill_all(const int* __restrict__ ni, const int* __restrict__ ei,
                         int nnz, const int* __restrict__ xx, int eg,
                         const int* __restrict__ ee, int eeN, int* cur_n, int* cur_e,
                         int* cur_gx, int* cur_ge, int* adj_n, int* adj_e,
                         int* adj_gx, int* adj_ge) {
  int i = blockIdx.x * blockDim.x + threadIdx.x;
  if (i < nnz) {
    const int n = ni[i], e = ei[i];
    adj_n[atomicAdd(&cur_n[n], 1)] = e;
    adj_e[atomicAdd(&cur_e[e], 1)] = n;
  } else if (i < nnz + eg) {
    const int j = i - nnz;
    adj_gx[atomicAdd(&cur_gx[xx[eg + j]], 1)] = xx[j];
  } else if (i < nnz + eg + eeN) {
    const int j = i - nnz - eg;
    adj_ge[atomicAdd(&cur_ge[ee[eeN + j]], 1)] = ee[j];
  }
}

__global__ void batch_counts2(const int* __restrict__ nbi, int n, int* cbn,
                              const int* __restrict__ hbi, int m, int* cbe) {
  const int* idx = blockIdx.x ? hbi : nbi;
  const int nn = blockIdx.x ? m : n;
  int* out = blockIdx.x ? cbe : cbn;
  int b = threadIdx.x;
  if (b >= NB) return;
  int lo = 0, hi = nn;
  while (lo < hi) { int mid = (lo + hi) >> 1; if (idx[mid] < b) lo = mid + 1; else hi = mid; }
  const int l = lo;
  lo = 0; hi = nn;
  while (lo < hi) { int mid = (lo + hi) >> 1; if (idx[mid] < b + 1) lo = mid + 1; else hi = mid; }
  out[b] = lo - l;
}

// ---------- gathers ----------
__global__ __launch_bounds__(256) void hedge_gather(
    const float* __restrict__ xw, const float* __restrict__ coord,
    const int* __restrict__ rowptr, const int* __restrict__ adj,
    float* __restrict__ e_conv, float* __restrict__ ecoord, int m) {
  const int e = (blockIdx.x * blockDim.x + threadIdx.x) >> 6;
  const int lane = threadIdx.x & 63;
  if (e >= m) return;
  const int lo = rowptr[e], hi = rowptr[e + 1];
  float2 acc = make_float2(0.f, 0.f);
  float cacc = 0.f;
  for (int base = lo; base < hi; base += 64) {
    const int mm = min(64, hi - base);
    int aj = (base + lane < hi) ? adj[base + lane] : 0;
    for (int j = 0; j < mm; j++) {
      const int nidx = __shfl(aj, j);
      const float2 v = ((const float2*)xw)[(size_t)nidx * 64 + lane];
      acc.x += v.x;
      acc.y += v.y;
      if (lane < 3) cacc += coord[nidx * 3 + lane];
    }
  }
  const float inv = 1.f / fmaxf((float)(hi - lo), 1.f);
  ((float2*)e_conv)[(size_t)e * 64 + lane] = make_float2(acc.x * inv, acc.y * inv);
  if (lane < 3) ecoord[e * 3 + lane] = cacc * inv;
}

__global__ __launch_bounds__(256) void node_gather(
    const float* __restrict__ ew, const float* __restrict__ xw,
    const float* __restrict__ coord, const float* __restrict__ ecoord,
    const int* __restrict__ rowptr, const int* __restrict__ adj,
    float* __restrict__ z_conv, float* __restrict__ outc, int n) {
  const int r = (blockIdx.x * blockDim.x + threadIdx.x) >> 6;
  const int lane = threadIdx.x & 63;
  if (r >= n) return;
  const int lo = rowptr[r], hi = rowptr[r + 1];
  const float2 a = ((const float2*)xw)[(size_t)r * 64 + lane];
  const float myc = (lane < 3) ? coord[r * 3 + lane] : 0.f;
  float2 acc = make_float2(0.f, 0.f);
  float cacc = 0.f;
  for (int base = lo; base < hi; base += 64) {
    const int mm = min(64, hi - base);
    int aj = (base + lane < hi) ? adj[base + lane] : 0;
    for (int j = 0; j < mm; j++) {
      const int e = __shfl(aj, j);
      const float2 b = ((const float2*)ew)[(size_t)e * 64 + lane];
      acc.x += b.x;
      acc.y += b.y;
      const float dot = wave_sum(fmaf(a.x, b.x, a.y * b.y));
      const float ph = tanhf(dot * 0.08838834764831845f);  // 1/sqrt(128)
      if (lane < 3) cacc = fmaf(myc - ecoord[e * 3 + lane], ph, cacc);
    }
  }
  const float inv = 1.f / fmaxf((float)(hi - lo), 1.f);
  ((float2*)z_conv)[(size_t)r * 64 + lane] = make_float2(acc.x * inv, acc.y * inv);
  if (lane < 3) outc[r * 3 + lane] = myc + cacc * inv;
}

// merged GCN for both graphs: blocks [0,nbA) -> A side, rest -> B side
__global__ __launch_bounds__(256) void gcn_gather2(
    const float* __restrict__ xwA, const int* __restrict__ rpA,
    const int* __restrict__ adjA, const float* __restrict__ rsA,
    const float* __restrict__ biasA, float* __restrict__ outA, int nA, int nbA,
    const float* __restrict__ xwB, const int* __restrict__ rpB,
    const int* __restrict__ adjB, const float* __restrict__ rsB,
    const float* __restrict__ biasB, float* __restrict__ outB, int nB) {
  const bool A = blockIdx.x < nbA;
  const int lb = A ? blockIdx.x : blockIdx.x - nbA;
  const float* xw = A ? xwA : xwB;
  const int* rowptr = A ? rpA : rpB;
  const int* adj = A ? adjA : adjB;
  const float* rs = A ? rsA : rsB;
  const float* bias = A ? biasA : biasB;
  float* out = A ? outA : outB;
  const int n = A ? nA : nB;
  const int r = (lb * 256 + (int)threadIdx.x) >> 6;
  const int lane = threadIdx.x & 63;
  if (r >= n) return;
  const int lo = rowptr[r], hi = rowptr[r + 1];
  const float rd = rs[r];
  float2 acc = make_float2(0.f, 0.f);
  for (int base = lo; base < hi; base += 64) {
    const int mm = min(64, hi - base);
    int aj = 0;
    float rj = 0.f;
    if (base + lane < hi) {
      aj = adj[base + lane];
      rj = rs[aj];
    }
    for (int j = 0; j < mm; j++) {
      const int s = __shfl(aj, j);
      const float w = __shfl(rj, j);
      const float2 v = ((const float2*)xw)[(size_t)s * 64 + lane];
      acc.x = fmaf(w, v.x, acc.x);
      acc.y = fmaf(w, v.y, acc.y);
    }
  }
  const float2 self = ((const float2*)xw)[(size_t)r * 64 + lane];
  const float2 bb = ((const float2*)bias)[lane];
  float2 o;
  o.x = fmaf(rd, acc.x, fmaf(rd * rd, self.x, bb.x));
  o.y = fmaf(rd, acc.y, fmaf(rd * rd, self.y, bb.y));
  ((float2*)out)[(size_t)r * 64 + lane] = o;
}

// ---------- barlow: split-K gram + fused colstats, both pairs in one launch ----------
__global__ __launch_bounds__(256) void gram_partial2(
    const float* __restrict__ Z1a, const float* __restrict__ Z2a, int na,
    float* __restrict__ parta, const float* __restrict__ Z1b,
    const float* __restrict__ Z2b, int nbm, float* __restrict__ partb,
    float* __restrict__ st, int nblkA) {
  const bool A = (int)blockIdx.x < nblkA;
  const int pid = A ? blockIdx.x : blockIdx.x - nblkA;
  const float* Z1 = A ? Z1a : Z1b;
  const float* Z2 = A ? Z2a : Z2b;
  const int n = A ? na : nbm;
  const int gparts = A ? GPN : GPM;
  float* part = (A ? parta : partb) + (size_t)pid * 16384;
  float* sum1 = st + (A ? 0 : 512);
  float* ssq1 = sum1 + 128;
  float* sum2 = sum1 + 256;
  float* ssq2 = sum1 + 384;
  __shared__ float4 s1[256], s2[256];
  const int t = threadIdx.x;
  const int ti = t >> 4, tj = t & 15;
  const int rpb = (n + gparts - 1) / gparts;
  const int lo = pid * rpb, hi = min(lo + rpb, n);
  float acc[8][8];
#pragma unroll
  for (int i = 0; i < 8; i++)
#pragma unroll
    for (int j = 0; j < 8; j++) acc[i][j] = 0.f;
  float cs = 0.f, cq = 0.f;
  const float* s1f = (const float*)s1;
  const float* s2f = (const float*)s2;
  const int c = t & 127;
  const bool low = t < 128;
  for (int rb = lo; rb < hi; rb += 8) {
    const int nr = min(8, hi - rb);
    __syncthreads();
    if (t < nr * 32) {
      const int rr = rb + (t >> 5);
      s1[t] = ((const float4*)Z1)[(size_t)rr * 32 + (t & 31)];
      s2[t] = ((const float4*)Z2)[(size_t)rr * 32 + (t & 31)];
    }
    __syncthreads();
    for (int r = 0; r < nr; r++) {
      const float4 a0 = s1[r * 32 + ti * 2], a1 = s1[r * 32 + ti * 2 + 1];
      const float4 b0 = s2[r * 32 + tj * 2], b1 = s2[r * 32 + tj * 2 + 1];
      const float av[8] = {a0.x, a0.y, a0.z, a0.w, a1.x, a1.y, a1.z, a1.w};
      const float bv[8] = {b0.x, b0.y, b0.z, b0.w, b1.x, b1.y, b1.z, b1.w};
#pragma unroll
      for (int i = 0; i < 8; i++)
#pragma unroll
        for (int j = 0; j < 8; j++) acc[i][j] = fmaf(av[i], bv[j], acc[i][j]);
      const float v = low ? s1f[r * 128 + c] : s2f[r * 128 + c];
      cs += v;
      cq = fmaf(v, v, cq);
    }
  }
  float4* P = (float4*)part;
#pragma unroll
  for (int i = 0; i < 8; i++) {
    P[(ti * 8 + i) * 32 + tj * 2] = make_float4(acc[i][0], acc[i][1], acc[i][2], acc[i][3]);
    P[(ti * 8 + i) * 32 + tj * 2 + 1] = make_float4(acc[i][4], acc[i][5], acc[i][6], acc[i][7]);
  }
  if (low) {
    atomicAdd(&sum1[c], cs);
    atomicAdd(&ssq1[c], cq);
  } else {
    atomicAdd(&sum2[c], cs);
    atomicAdd(&ssq2[c], cq);
  }
}

__global__ __launch_bounds__(256) void gram_reduce2(const float* __restrict__ parta,
                                                    float* __restrict__ G1,
                                                    const float* __restrict__ partb,
                                                    float* __restrict__ G2) {
  const int gb = blockIdx.x;  // grid 128
  const bool A = gb < 64;
  const float* part = A ? parta : partb;
  float* G = A ? G1 : G2;
  const int gp = A ? GPN : GPM;
  const int e = (A ? gb : gb - 64) * 256 + threadIdx.x;
  float s = 0.f;
  for (int p = 0; p < gp; p++) s += part[(size_t)p * 16384 + e];
  G[e] = s;
}

__global__ __launch_bounds__(256) void barlow_fin2(const float* __restrict__ G1,
                                                   const float* __restrict__ G2,
                                                   const float* __restrict__ st,
                                                   float nA, float nB, float* out) {
  const bool A = blockIdx.x == 0;
  const float* G = A ? G1 : G2;
  const float* sum1 = st + (A ? 0 : 512);
  const float* ssq1 = sum1 + 128;
  const float* sum2 = sum1 + 256;
  const float* ssq2 = sum1 + 384;
  const float n = A ? nA : nB;
  __shared__ float s1s[128], m1s[128], s2s[128], m2s[128];
  __shared__ float red[256];
  const int t = threadIdx.x;
  if (t < 128) {
    const float inv_n = 1.f / n;
    const float bnf = (n - 1.f) * inv_n + 1e-5f;
    float mu = sum1[t] * inv_n;
    float vu = (ssq1[t] * inv_n - mu * mu) * n / (n - 1.f);
    s1s[t] = rsqrtf(vu * bnf);
    m1s[t] = mu;
    mu = sum2[t] * inv_n;
    vu = (ssq2[t] * inv_n - mu * mu) * n / (n - 1.f);
    s2s[t] = rsqrtf(vu * bnf);
    m2s[t] = mu;
  }
  __syncthreads();
  float on = 0.f, off = 0.f;
  for (int idx = t; idx < 16384; idx += 256) {
    const int i = idx >> 7, j = idx & 127;
    const float c = s1s[i] * s2s[j] * (G[idx] - n * m1s[i] * m2s[j]) * (1.f / 32.f);
    if (i == j) {
      const float dd = c - 1.f;
      on += dd * dd;
    } else {
      off += c * c;
    }
  }
  red[t] = on + 0.005f * off;
  __syncthreads();
  for (int s = 128; s; s >>= 1) {
    if (t < s) red[t] += red[t + s];
    __syncthreads();
  }
  if (t == 0) atomicAdd(out, red[0]);
}

// ---------- epilogue (z and e sides in one launch) ----------
__global__ __launch_bounds__(256) void ln_gelu_res2(
    const float* __restrict__ convA, const float* __restrict__ residA,
    float* __restrict__ outA, int nA, int nbA, const float* __restrict__ convB,
    const float* __restrict__ residB, float* __restrict__ outB, int nB,
    const float* __restrict__ g, const float* __restrict__ b) {
  const bool A = (int)blockIdx.x < nbA;
  const int lb = A ? blockIdx.x : blockIdx.x - nbA;
  const float* conv = A ? convA : convB;
  const float* resid = A ? residA : residB;
  float* out = A ? outA : outB;
  const int rows = A ? nA : nB;
  const int w = (lb * 256 + (int)threadIdx.x) >> 6;
  const int lane = threadIdx.x & 63;
  if (w >= rows) return;
  const float2 v = ((const float2*)conv)[(size_t)w * 64 + lane];
  const float m = wave_sum(v.x + v.y) * (1.f / 128.f);
  const float q = wave_sum(fmaf(v.x, v.x, v.y * v.y)) * (1.f / 128.f);
  const float rstd = rsqrtf(q - m * m + 1e-5f);
  const float2 gg = ((const float2*)g)[lane];
  const float2 bb = ((const float2*)b)[lane];
  const float2 rr = ((const float2*)resid)[(size_t)w * 64 + lane];
  float y0 = fmaf(gg.x, (v.x - m) * rstd, bb.x);
  float y1 = fmaf(gg.y, (v.y - m) * rstd, bb.y);
  y0 = 0.5f * y0 * (1.f + erff(y0 * 0.7071067811865476f));
  y1 = 0.5f * y1 * (1.f + erff(y1 * 0.7071067811865476f));
  float2 o;
  o.x = y0 + rr.x;
  o.y = y1 + rr.y;
  ((float2*)out)[(size_t)w * 64 + lane] = o;
}

__global__ __launch_bounds__(128) void seg_pool2(const float* __restrict__ ZA,
                                                 const int* __restrict__ bidxA, int nA,
                                                 int nbA, float* poolA,
                                                 const float* __restrict__ ZB,
                                                 const int* __restrict__ bidxB, int nB,
                                                 float* poolB) {
  const bool A = (int)blockIdx.x < nbA;
  const int lb = A ? blockIdx.x : blockIdx.x - nbA;
  const float* Z = A ? ZA : ZB;
  const int* bidx = A ? bidxA : bidxB;
  const int n = A ? nA : nB;
  float* pool = A ? poolA : poolB;
  const int c = threadIdx.x;
  const int r0 = lb * 128;
  const int re = min(r0 + 128, n);
  if (r0 >= n) return;
  float acc = 0.f;
  int cur = bidx[r0];
  for (int r = r0; r < re; r++) {
    const int bb = bidx[r];
    if (bb != cur) {
      atomicAdd(&pool[cur * 128 + c], acc);
      acc = 0.f;
      cur = bb;
    }
    acc += Z[(size_t)r * 128 + c];
  }
  atomicAdd(&pool[cur * 128 + c], acc);
}

__global__ __launch_bounds__(128) void graph_gemm(
    const float* __restrict__ zg, const float* __restrict__ eg,
    const int* __restrict__ cnz, const int* __restrict__ cne,
    const float* __restrict__ Wf, const float* __restrict__ bf, float* out) {
  __shared__ float cat[256];
  const int g = blockIdx.x, t = threadIdx.x;
  cat[t] = zg[g * 128 + t] / fmaxf((float)cnz[g], 1.f);
  cat[128 + t] = eg[g * 128 + t] / fmaxf((float)cne[g], 1.f);
  __syncthreads();
  float acc = bf[t];
#pragma unroll 8
  for (int k = 0; k < 256; k++) acc = fmaf(cat[k], Wf[k * 128 + t], acc);
  out[g * 128 + t] = acc;
}

extern "C" void kernel_launch(void* const* d_in, const int* in_sizes, int n_in,
                              void* d_out, int out_size, void* d_ws, size_t ws_size,
                              hipStream_t stream) {
  const float* x = (const float*)d_in[0];
  const float* hf = (const float*)d_in[1];
  const float* coord = (const float*)d_in[2];
  const int* ni = (const int*)d_in[3];
  const int* ei = (const int*)d_in[4];
  const int* nb = (const int*)d_in[5];
  const int* hb = (const int*)d_in[6];
  const int* xx = (const int*)d_in[7];
  const int* ee = (const int*)d_in[8];
  const float* Wv = (const float*)d_in[10];
  const float* bv = (const float*)d_in[11];
  const float* We = (const float*)d_in[12];
  const float* be = (const float*)d_in[13];
  const float* Wx = (const float*)d_in[14];
  const float* bx = (const float*)d_in[15];
  const float* Weg = (const float*)d_in[16];
  const float* beg = (const float*)d_in[17];
  const float* lng = (const float*)d_in[18];
  const float* lnb = (const float*)d_in[19];
  const float* Wf = (const float*)d_in[20];
  const float* bf = (const float*)d_in[21];

  const int N = in_sizes[0] / 128;
  const int M = in_sizes[1] / 128;
  const int NNZ = in_sizes[3];
  const int EG = in_sizes[7] / 2;
  const int EE = in_sizes[8] / 2;

  float* ws = (float*)d_ws;
  size_t o = 0;
  float* xw = ws + o;     o += (size_t)N * 128;  // dead by gram time -> gpart alias
  float* ew = ws + o;     o += (size_t)M * 128;
  float* xw2 = ws + o;    o += (size_t)N * 128;
  float* ew2 = ws + o;    o += (size_t)M * 128;
  float* z_conv = ws + o; o += (size_t)N * 128;
  float* e_conv = ws + o; o += (size_t)M * 128;
  float* ecoord = ws + o; o += (size_t)M * 3;
  float* rs_gx = ws + o;  o += N;
  float* rs_ge = ws + o;  o += M;
  float* G1 = ws + o;     o += 16384;
  float* G2 = ws + o;     o += 16384;
  const size_t fz0 = o;  // zeroed float block
  float* st = ws + o;     o += 1024;
  float* zg = ws + o;     o += NB * 128;
  float* eg = ws + o;     o += NB * 128;
  const size_t fz1 = o;
  int* wsi = (int*)(ws + o);
  size_t oi = 0;
  int* cnt_n = wsi + oi;  oi += N;  // becomes cursor after scan
  int* cnt_e = wsi + oi;  oi += M;
  int* cnt_gx = wsi + oi; oi += N;
  int* cnt_ge = wsi + oi; oi += M;
  const size_t iz1 = oi;
  int* rp_n = wsi + oi;   oi += N + 1;
  int* rp_e = wsi + oi;   oi += M + 1;
  int* rp_gx = wsi + oi;  oi += N + 1;
  int* rp_ge = wsi + oi;  oi += M + 1;
  int* adj_n = wsi + oi;  oi += NNZ;
  int* adj_e = wsi + oi;  oi += NNZ;
  int* adj_gx = wsi + oi; oi += EG;
  int* adj_ge = wsi + oi; oi += EE;
  int* cbn = wsi + oi;    oi += NB;
  int* cbe = wsi + oi;    oi += NB;
  int* bsums = wsi + oi;  oi += 64;
  int* bbase = wsi + oi;  oi += 64;
  int* totals = wsi + oi; oi += 4;

  float* gpartA = xw;                              // GPN*16384 floats = 33.6MB
  float* gpartB = xw + (size_t)GPN * 16384;        // GPM*16384 floats = 8.4MB (fits in 61MB of dead bufs)

  float* outz = (float*)d_out;           // temporarily z_imp
  float* oute = outz + (size_t)N * 128;  // temporarily e_imp
  float* outc = oute + (size_t)M * 128;
  float* outg = outc + (size_t)N * 3;
  float* outbt = outg + NB * 128;

  hipMemsetAsync(ws + fz0, 0, (fz1 - fz0) * 4, stream);
  hipMemsetAsync(wsi, 0, iz1 * 4, stream);
  hipMemsetAsync(outbt, 0, 4, stream);

  // dense projections (fused pairs sharing the input)
  gemm128x2<<<(N + 63) / 64, 256, 0, stream>>>(x, Wv, bv, xw, Wx, xw2, N);
  gemm128x2<<<(M + 63) / 64, 256, 0, stream>>>(hf, We, be, ew, Weg, ew2, M);

  // CSR build
  const int tot = NNZ + EG + EE;
  count_all<<<(tot + 255) / 256, 256, 0, stream>>>(ni, ei, NNZ, xx, EG, ee, EE,
                                                   cnt_n, cnt_e, cnt_gx, cnt_ge);
  const int nb0 = (N + 4095) >> 12, nb1 = (M + 4095) >> 12;
  const int sgrid = 2 * nb0 + 2 * nb1;
  scan_partial<<<sgrid, 256, 0, stream>>>(cnt_n, N, cnt_e, M, cnt_gx, N, cnt_ge, M,
                                          nb0, nb1, nb0, nb1, bsums);
  scan_bsums<<<1, 64, 0, stream>>>(bsums, nb0, nb1, nb0, nb1, bbase, totals);
  scan_final<<<sgrid, 256, 0, stream>>>(
      cnt_n, rp_n, nullptr, N, cnt_e, rp_e, nullptr, M, cnt_gx, rp_gx, rs_gx, N,
      cnt_ge, rp_ge, rs_ge, M, nb0, nb1, nb0, nb1, bbase, totals);
  fill_all<<<(tot + 255) / 256, 256, 0, stream>>>(ni, ei, NNZ, xx, EG, ee, EE, cnt_n,
                                                  cnt_e, cnt_gx, cnt_ge, adj_n, adj_e,
                                                  adj_gx, adj_ge);
  batch_counts2<<<2, 64, 0, stream>>>(nb, N, cbn, hb, M, cbe);

  // hypergraph conv (gather form) + coord update
  hedge_gather<<<(M + 3) / 4, 256, 0, stream>>>(xw, coord, rp_e, adj_e, e_conv, ecoord, M);
  node_gather<<<(N + 3) / 4, 256, 0, stream>>>(ew, xw, coord, ecoord, rp_n, adj_n,
                                               z_conv, outc, N);

  // GCN branches into d_out z/e regions (z_imp/e_imp)
  const int gcnA = (N + 3) / 4;
  gcn_gather2<<<gcnA + (M + 3) / 4, 256, 0, stream>>>(
      xw2, rp_gx, adj_gx, rs_gx, bx, outz, N, gcnA, ew2, rp_ge, adj_ge, rs_ge, beg,
      oute, M);

  // barlow-twins: split-K gram with fused column stats (xw..ew2 now dead)
  gram_partial2<<<GPN + GPM, 256, 0, stream>>>(outz, z_conv, N, gpartA, oute, e_conv,
                                               M, gpartB, st, GPN);
  gram_reduce2<<<128, 256, 0, stream>>>(gpartA, G1, gpartB, G2);
  barlow_fin2<<<2, 256, 0, stream>>>(G1, G2, st, (float)N, (float)M, outbt);

  // final z/e (overwrite z_imp/e_imp AFTER gram consumed them)
  const int lnA = (N + 3) / 4;
  ln_gelu_res2<<<lnA + (M + 3) / 4, 256, 0, stream>>>(z_conv, x, outz, N, lnA, e_conv,
                                                      hf, oute, M, lng, lnb);

  // pooling + output linear
  const int spA = (N + 127) / 128;
  seg_pool2<<<spA + (M + 127) / 128, 128, 0, stream>>>(outz, nb, N, spA, zg, oute, hb,
                                                       M, eg);
  graph_gemm<<<NB, 128, 0, stream>>>(zg, eg, cbn, cbe, Wf, bf, outg);
}

// Round 5
// 620.917 us; speedup vs baseline: 4.4188x; 1.4578x over previous
//
#include <hip/hip_runtime.h>
#include <hip/hip_bf16.h>

#define NB 32      // num_graphs
#define GPN 512    // split-K parts for gram (N side)
#define GPM 128    // split-K parts for gram (M side)

__device__ __forceinline__ float wave_sum(float v) {
#pragma unroll
  for (int off = 32; off; off >>= 1) v += __shfl_xor(v, off);
  return v;
}
__device__ __forceinline__ int wave_sum_i(int v) {
#pragma unroll
  for (int off = 32; off; off >>= 1) v += __shfl_xor(v, off);
  return v;
}

// ---- fused dual GEMM: out1 = X@W1 + b1, out2 = X@W2 ----
// 64 rows of X staged in LDS; one K sweep per block; thread = 4 cols x 8 rows x 2 mats.
__global__ __launch_bounds__(256) void gemm128x2(const float* __restrict__ X,
                                                 const float* __restrict__ W1,
                                                 const float* __restrict__ b1,
                                                 float* __restrict__ out1,
                                                 const float* __restrict__ W2,
                                                 float* __restrict__ out2, int rows) {
  __shared__ float xs[64][132];  // pad 132: 16B-aligned rows, distinct banks per row
  const int t = threadIdx.x;
  const int c4 = t & 31;   // col group (4 cols)
  const int rg = t >> 5;   // row group (8 rows)
  const int r0 = blockIdx.x * 64;
#pragma unroll
  for (int i = 0; i < 8; i++) {
    const int idx = t + i * 256;
    const int row = idx >> 5, cc = idx & 31;
    const int gr = r0 + row;
    float4 v = make_float4(0.f, 0.f, 0.f, 0.f);
    if (gr < rows) v = ((const float4*)X)[(size_t)gr * 32 + cc];
    *(float4*)&xs[row][cc * 4] = v;
  }
  __syncthreads();
  const float4* W1v = (const float4*)W1;
  const float4* W2v = (const float4*)W2;
  const float4 b4 = ((const float4*)b1)[c4];
  float4 acc1[8], acc2[8];
#pragma unroll
  for (int i = 0; i < 8; i++) {
    acc1[i] = b4;
    acc2[i] = make_float4(0.f, 0.f, 0.f, 0.f);
  }
  const int rbase = rg * 8;
#pragma unroll 2
  for (int k = 0; k < 128; k++) {
    const float4 w1 = W1v[k * 32 + c4];
    const float4 w2 = W2v[k * 32 + c4];
#pragma unroll
    for (int i = 0; i < 8; i++) {
      const float xv = xs[rbase + i][k];
      acc1[i].x = fmaf(xv, w1.x, acc1[i].x);
      acc1[i].y = fmaf(xv, w1.y, acc1[i].y);
      acc1[i].z = fmaf(xv, w1.z, acc1[i].z);
      acc1[i].w = fmaf(xv, w1.w, acc1[i].w);
      acc2[i].x = fmaf(xv, w2.x, acc2[i].x);
      acc2[i].y = fmaf(xv, w2.y, acc2[i].y);
      acc2[i].z = fmaf(xv, w2.z, acc2[i].z);
      acc2[i].w = fmaf(xv, w2.w, acc2[i].w);
    }
  }
#pragma unroll
  for (int i = 0; i < 8; i++) {
    const int gr = r0 + rbase + i;
    if (gr < rows) {
      ((float4*)out1)[(size_t)gr * 32 + c4] = acc1[i];
      ((float4*)out2)[(size_t)gr * 32 + c4] = acc2[i];
    }
  }
}

// ---------- CSR build ----------
__global__ void count_all(const int* __restrict__ ni, const int* __restrict__ ei,
                          int nnz, const int* __restrict__ xx, int eg,
                          const int* __restrict__ ee, int eeN, int* cn, int* ce,
                          int* cgx, int* cge) {
  int i = blockIdx.x * blockDim.x + threadIdx.x;
  if (i < nnz) {
    atomicAdd(&cn[ni[i]], 1);
    atomicAdd(&ce[ei[i]], 1);
  } else if (i < nnz + eg) {
    atomicAdd(&cgx[xx[eg + (i - nnz)]], 1);
  } else if (i < nnz + eg + eeN) {
    atomicAdd(&cge[ee[eeN + (i - nnz - eg)]], 1);
  }
}

// ---- multi-block segmented exclusive scan over the 4 count arrays ----
__global__ __launch_bounds__(256) void scan_partial(
    const int* __restrict__ c0, int n0, const int* __restrict__ c1, int n1,
    const int* __restrict__ c2, int n2, const int* __restrict__ c3, int n3,
    int nb0, int nb1, int nb2, int nb3, int* __restrict__ bsums) {
  const int gb = blockIdx.x;
  const int* cnt;
  int lb, n;
  if (gb < nb0) { cnt = c0; lb = gb; n = n0; }
  else if (gb < nb0 + nb1) { cnt = c1; lb = gb - nb0; n = n1; }
  else if (gb < nb0 + nb1 + nb2) { cnt = c2; lb = gb - nb0 - nb1; n = n2; }
  else { cnt = c3; lb = gb - nb0 - nb1 - nb2; n = n3; }
  const int t = threadIdx.x;
  const int base = lb * 4096 + t * 16;
  int s = 0;
#pragma unroll
  for (int i = 0; i < 16; i++) {
    const int idx = base + i;
    if (idx < n) s += cnt[idx];
  }
  const int wsum = wave_sum_i(s);
  __shared__ int wsm[4];
  if ((t & 63) == 0) wsm[t >> 6] = wsum;
  __syncthreads();
  if (t == 0) bsums[gb] = wsm[0] + wsm[1] + wsm[2] + wsm[3];
}

__global__ void scan_bsums(const int* __restrict__ bsums, int nb0, int nb1, int nb2,
                           int nb3, int* __restrict__ bbase, int* __restrict__ totals) {
  if (threadIdx.x) return;
  int segs[4] = {nb0, nb1, nb2, nb3};
  int gb = 0;
  for (int a = 0; a < 4; a++) {
    int run = 0;
    for (int i = 0; i < segs[a]; i++) {
      bbase[gb] = run;
      run += bsums[gb];
      gb++;
    }
    totals[a] = run;
  }
}

__global__ __launch_bounds__(256) void scan_final(
    int* __restrict__ c0, int* rp0, float* rs0, int n0,
    int* __restrict__ c1, int* rp1, float* rs1, int n1,
    int* __restrict__ c2, int* rp2, float* rs2, int n2,
    int* __restrict__ c3, int* rp3, float* rs3, int n3,
    int nb0, int nb1, int nb2, int nb3, const int* __restrict__ bbase,
    const int* __restrict__ totals) {
  const int gb = blockIdx.x;
  int* cnt;
  int* rp;
  float* rs;
  int lb, n, a;
  if (gb < nb0) { cnt = c0; rp = rp0; rs = rs0; lb = gb; n = n0; a = 0; }
  else if (gb < nb0 + nb1) { cnt = c1; rp = rp1; rs = rs1; lb = gb - nb0; n = n1; a = 1; }
  else if (gb < nb0 + nb1 + nb2) { cnt = c2; rp = rp2; rs = rs2; lb = gb - nb0 - nb1; n = n2; a = 2; }
  else { cnt = c3; rp = rp3; rs = rs3; lb = gb - nb0 - nb1 - nb2; n = n3; a = 3; }
  const int t = threadIdx.x;
  const int base = lb * 4096 + t * 16;
  int vals[16];
  int s = 0;
#pragma unroll
  for (int i = 0; i < 16; i++) {
    const int idx = base + i;
    vals[i] = (idx < n) ? cnt[idx] : 0;
    s += vals[i];
  }
  __shared__ int tsum[256];
  tsum[t] = s;
  __syncthreads();
  for (int off = 1; off < 256; off <<= 1) {
    const int v = (t >= off) ? tsum[t - off] : 0;
    __syncthreads();
    tsum[t] += v;
    __syncthreads();
  }
  int run = bbase[gb] + (t ? tsum[t - 1] : 0);
#pragma unroll
  for (int i = 0; i < 16; i++) {
    const int idx = base + i;
    if (idx < n) {
      rp[idx] = run;
      cnt[idx] = run;  // cursor for fill
      if (rs) rs[idx] = rsqrtf(1.f + (float)vals[i]);
      run += vals[i];
    }
  }
  if (t == 0 && lb == 0) rp[n] = totals[a];
}

__global__ void fill_all(const int* __restrict__ ni, const int* __restrict__ ei,
                         int nnz, const int* __restrict__ xx, int eg,
                         const int* __restrict__ ee, int eeN, int* cur_n, int* cur_e,
                         int* cur_gx, int* cur_ge, int* adj_n, int* adj_e,
                         int* adj_gx, int* adj_ge) {
  int i = blockIdx.x * blockDim.x + threadIdx.x;
  if (i < nnz) {
    const int n = ni[i], e = ei[i];
    adj_n[atomicAdd(&cur_n[n], 1)] = e;
    adj_e[atomicAdd(&cur_e[e], 1)] = n;
  } else if (i < nnz + eg) {
    const int j = i - nnz;
    adj_gx[atomicAdd(&cur_gx[xx[eg + j]], 1)] = xx[j];
  } else if (i < nnz + eg + eeN) {
    const int j = i - nnz - eg;
    adj_ge[atomicAdd(&cur_ge[ee[eeN + j]], 1)] = ee[j];
  }
}

__global__ void batch_counts2(const int* __restrict__ nbi, int n, int* cbn,
                              const int* __restrict__ hbi, int m, int* cbe) {
  const int* idx = blockIdx.x ? hbi : nbi;
  const int nn = blockIdx.x ? m : n;
  int* out = blockIdx.x ? cbe : cbn;
  int b = threadIdx.x;
  if (b >= NB) return;
  int lo = 0, hi = nn;
  while (lo < hi) { int mid = (lo + hi) >> 1; if (idx[mid] < b) lo = mid + 1; else hi = mid; }
  const int l = lo;
  lo = 0; hi = nn;
  while (lo < hi) { int mid = (lo + hi) >> 1; if (idx[mid] < b + 1) lo = mid + 1; else hi = mid; }
  out[b] = lo - l;
}

// ---------- gathers ----------
__global__ __launch_bounds__(256) void hedge_gather(
    const float* __restrict__ xw, const float* __restrict__ coord,
    const int* __restrict__ rowptr, const int* __restrict__ adj,
    float* __restrict__ e_conv, float* __restrict__ ecoord, int m) {
  const int e = (blockIdx.x * blockDim.x + threadIdx.x) >> 6;
  const int lane = threadIdx.x & 63;
  if (e >= m) return;
  const int lo = rowptr[e], hi = rowptr[e + 1];
  float2 acc = make_float2(0.f, 0.f);
  float cacc = 0.f;
  for (int base = lo; base < hi; base += 64) {
    const int mm = min(64, hi - base);
    int aj = (base + lane < hi) ? adj[base + lane] : 0;
    for (int j = 0; j < mm; j++) {
      const int nidx = __shfl(aj, j);
      const float2 v = ((const float2*)xw)[(size_t)nidx * 64 + lane];
      acc.x += v.x;
      acc.y += v.y;
      if (lane < 3) cacc += coord[nidx * 3 + lane];
    }
  }
  const float inv = 1.f / fmaxf((float)(hi - lo), 1.f);
  ((float2*)e_conv)[(size_t)e * 64 + lane] = make_float2(acc.x * inv, acc.y * inv);
  if (lane < 3) ecoord[e * 3 + lane] = cacc * inv;
}

__global__ __launch_bounds__(256) void node_gather(
    const float* __restrict__ ew, const float* __restrict__ xw,
    const float* __restrict__ coord, const float* __restrict__ ecoord,
    const int* __restrict__ rowptr, const int* __restrict__ adj,
    float* __restrict__ z_conv, float* __restrict__ outc, int n) {
  const int r = (blockIdx.x * blockDim.x + threadIdx.x) >> 6;
  const int lane = threadIdx.x & 63;
  if (r >= n) return;
  const int lo = rowptr[r], hi = rowptr[r + 1];
  const float2 a = ((const float2*)xw)[(size_t)r * 64 + lane];
  const float myc = (lane < 3) ? coord[r * 3 + lane] : 0.f;
  float2 acc = make_float2(0.f, 0.f);
  float cacc = 0.f;
  for (int base = lo; base < hi; base += 64) {
    const int mm = min(64, hi - base);
    int aj = (base + lane < hi) ? adj[base + lane] : 0;
    for (int j = 0; j < mm; j++) {
      const int e = __shfl(aj, j);
      const float2 b = ((const float2*)ew)[(size_t)e * 64 + lane];
      acc.x += b.x;
      acc.y += b.y;
      const float dot = wave_sum(fmaf(a.x, b.x, a.y * b.y));
      const float ph = tanhf(dot * 0.08838834764831845f);  // 1/sqrt(128)
      if (lane < 3) cacc = fmaf(myc - ecoord[e * 3 + lane], ph, cacc);
    }
  }
  const float inv = 1.f / fmaxf((float)(hi - lo), 1.f);
  ((float2*)z_conv)[(size_t)r * 64 + lane] = make_float2(acc.x * inv, acc.y * inv);
  if (lane < 3) outc[r * 3 + lane] = myc + cacc * inv;
}

// merged GCN for both graphs
__global__ __launch_bounds__(256) void gcn_gather2(
    const float* __restrict__ xwA, const int* __restrict__ rpA,
    const int* __restrict__ adjA, const float* __restrict__ rsA,
    const float* __restrict__ biasA, float* __restrict__ outA, int nA, int nbA,
    const float* __restrict__ xwB, const int* __restrict__ rpB,
    const int* __restrict__ adjB, const float* __restrict__ rsB,
    const float* __restrict__ biasB, float* __restrict__ outB, int nB) {
  const bool A = blockIdx.x < nbA;
  const int lb = A ? blockIdx.x : blockIdx.x - nbA;
  const float* xw = A ? xwA : xwB;
  const int* rowptr = A ? rpA : rpB;
  const int* adj = A ? adjA : adjB;
  const float* rs = A ? rsA : rsB;
  const float* bias = A ? biasA : biasB;
  float* out = A ? outA : outB;
  const int n = A ? nA : nB;
  const int r = (lb * 256 + (int)threadIdx.x) >> 6;
  const int lane = threadIdx.x & 63;
  if (r >= n) return;
  const int lo = rowptr[r], hi = rowptr[r + 1];
  const float rd = rs[r];
  float2 acc = make_float2(0.f, 0.f);
  for (int base = lo; base < hi; base += 64) {
    const int mm = min(64, hi - base);
    int aj = 0;
    float rj = 0.f;
    if (base + lane < hi) {
      aj = adj[base + lane];
      rj = rs[aj];
    }
    for (int j = 0; j < mm; j++) {
      const int s = __shfl(aj, j);
      const float w = __shfl(rj, j);
      const float2 v = ((const float2*)xw)[(size_t)s * 64 + lane];
      acc.x = fmaf(w, v.x, acc.x);
      acc.y = fmaf(w, v.y, acc.y);
    }
  }
  const float2 self = ((const float2*)xw)[(size_t)r * 64 + lane];
  const float2 bb = ((const float2*)bias)[lane];
  float2 o;
  o.x = fmaf(rd, acc.x, fmaf(rd * rd, self.x, bb.x));
  o.y = fmaf(rd, acc.y, fmaf(rd * rd, self.y, bb.y));
  ((float2*)out)[(size_t)r * 64 + lane] = o;
}

// ---------- barlow: split-K gram + fused colstats ----------
__global__ __launch_bounds__(256) void gram_partial2(
    const float* __restrict__ Z1a, const float* __restrict__ Z2a, int na,
    float* __restrict__ parta, const float* __restrict__ Z1b,
    const float* __restrict__ Z2b, int nbm, float* __restrict__ partb,
    float* __restrict__ st, int nblkA) {
  const bool A = (int)blockIdx.x < nblkA;
  const int pid = A ? blockIdx.x : blockIdx.x - nblkA;
  const float* Z1 = A ? Z1a : Z1b;
  const float* Z2 = A ? Z2a : Z2b;
  const int n = A ? na : nbm;
  const int gparts = A ? GPN : GPM;
  float* part = (A ? parta : partb) + (size_t)pid * 16384;
  float* sum1 = st + (A ? 0 : 512);
  float* ssq1 = sum1 + 128;
  float* sum2 = sum1 + 256;
  float* ssq2 = sum1 + 384;
  __shared__ float4 s1[256], s2[256];
  const int t = threadIdx.x;
  const int ti = t >> 4, tj = t & 15;
  const int rpb = (n + gparts - 1) / gparts;
  const int lo = pid * rpb, hi = min(lo + rpb, n);
  float acc[8][8];
#pragma unroll
  for (int i = 0; i < 8; i++)
#pragma unroll
    for (int j = 0; j < 8; j++) acc[i][j] = 0.f;
  float cs = 0.f, cq = 0.f;
  const float* s1f = (const float*)s1;
  const float* s2f = (const float*)s2;
  const int c = t & 127;
  const bool low = t < 128;
  for (int rb = lo; rb < hi; rb += 8) {
    const int nr = min(8, hi - rb);
    __syncthreads();
    if (t < nr * 32) {
      const int rr = rb + (t >> 5);
      s1[t] = ((const float4*)Z1)[(size_t)rr * 32 + (t & 31)];
      s2[t] = ((const float4*)Z2)[(size_t)rr * 32 + (t & 31)];
    }
    __syncthreads();
    for (int r = 0; r < nr; r++) {
      const float4 a0 = s1[r * 32 + ti * 2], a1 = s1[r * 32 + ti * 2 + 1];
      const float4 b0 = s2[r * 32 + tj * 2], b1 = s2[r * 32 + tj * 2 + 1];
      const float av[8] = {a0.x, a0.y, a0.z, a0.w, a1.x, a1.y, a1.z, a1.w};
      const float bv[8] = {b0.x, b0.y, b0.z, b0.w, b1.x, b1.y, b1.z, b1.w};
#pragma unroll
      for (int i = 0; i < 8; i++)
#pragma unroll
        for (int j = 0; j < 8; j++) acc[i][j] = fmaf(av[i], bv[j], acc[i][j]);
      const float v = low ? s1f[r * 128 + c] : s2f[r * 128 + c];
      cs += v;
      cq = fmaf(v, v, cq);
    }
  }
  float4* P = (float4*)part;
#pragma unroll
  for (int i = 0; i < 8; i++) {
    P[(ti * 8 + i) * 32 + tj * 2] = make_float4(acc[i][0], acc[i][1], acc[i][2], acc[i][3]);
    P[(ti * 8 + i) * 32 + tj * 2 + 1] = make_float4(acc[i][4], acc[i][5], acc[i][6], acc[i][7]);
  }
  if (low) {
    atomicAdd(&sum1[c], cs);
    atomicAdd(&ssq1[c], cq);
  } else {
    atomicAdd(&sum2[c], cs);
    atomicAdd(&ssq2[c], cq);
  }
}

__global__ __launch_bounds__(256) void gram_reduce2(const float* __restrict__ parta,
                                                    float* __restrict__ G1,
                                                    const float* __restrict__ partb,
                                                    float* __restrict__ G2) {
  const int gb = blockIdx.x;  // grid 128
  const bool A = gb < 64;
  const float* part = A ? parta : partb;
  float* G = A ? G1 : G2;
  const int gp = A ? GPN : GPM;
  const int e = (A ? gb : gb - 64) * 256 + threadIdx.x;
  float s = 0.f;
  for (int p = 0; p < gp; p++) s += part[(size_t)p * 16384 + e];
  G[e] = s;
}

__global__ __launch_bounds__(256) void barlow_fin2(const float* __restrict__ G1,
                                                   const float* __restrict__ G2,
                                                   const float* __restrict__ st,
                                                   float nA, float nB, float* out) {
  const bool A = blockIdx.x == 0;
  const float* G = A ? G1 : G2;
  const float* sum1 = st + (A ? 0 : 512);
  const float* ssq1 = sum1 + 128;
  const float* sum2 = sum1 + 256;
  const float* ssq2 = sum1 + 384;
  const float n = A ? nA : nB;
  __shared__ float s1s[128], m1s[128], s2s[128], m2s[128];
  __shared__ float red[256];
  const int t = threadIdx.x;
  if (t < 128) {
    const float inv_n = 1.f / n;
    const float bnf = (n - 1.f) * inv_n + 1e-5f;
    float mu = sum1[t] * inv_n;
    float vu = (ssq1[t] * inv_n - mu * mu) * n / (n - 1.f);
    s1s[t] = rsqrtf(vu * bnf);
    m1s[t] = mu;
    mu = sum2[t] * inv_n;
    vu = (ssq2[t] * inv_n - mu * mu) * n / (n - 1.f);
    s2s[t] = rsqrtf(vu * bnf);
    m2s[t] = mu;
  }
  __syncthreads();
  float on = 0.f, off = 0.f;
  for (int idx = t; idx < 16384; idx += 256) {
    const int i = idx >> 7, j = idx & 127;
    const float c = s1s[i] * s2s[j] * (G[idx] - n * m1s[i] * m2s[j]) * (1.f / 32.f);
    if (i == j) {
      const float dd = c - 1.f;
      on += dd * dd;
    } else {
      off += c * c;
    }
  }
  red[t] = on + 0.005f * off;
  __syncthreads();
  for (int s = 128; s; s >>= 1) {
    if (t < s) red[t] += red[t + s];
    __syncthreads();
  }
  if (t == 0) atomicAdd(out, red[0]);
}

// ---------- epilogue ----------
__global__ __launch_bounds__(256) void ln_gelu_res2(
    const float* __restrict__ convA, const float* __restrict__ residA,
    float* __restrict__ outA, int nA, int nbA, const float* __restrict__ convB,
    const float* __restrict__ residB, float* __restrict__ outB, int nB,
    const float* __restrict__ g, const float* __restrict__ b) {
  const bool A = (int)blockIdx.x < nbA;
  const int lb = A ? blockIdx.x : blockIdx.x - nbA;
  const float* conv = A ? convA : convB;
  const float* resid = A ? residA : residB;
  float* out = A ? outA : outB;
  const int rows = A ? nA : nB;
  const int w = (lb * 256 + (int)threadIdx.x) >> 6;
  const int lane = threadIdx.x & 63;
  if (w >= rows) return;
  const float2 v = ((const float2*)conv)[(size_t)w * 64 + lane];
  const float m = wave_sum(v.x + v.y) * (1.f / 128.f);
  const float q = wave_sum(fmaf(v.x, v.x, v.y * v.y)) * (1.f / 128.f);
  const float rstd = rsqrtf(q - m * m + 1e-5f);
  const float2 gg = ((const float2*)g)[lane];
  const float2 bb = ((const float2*)b)[lane];
  const float2 rr = ((const float2*)resid)[(size_t)w * 64 + lane];
  float y0 = fmaf(gg.x, (v.x - m) * rstd, bb.x);
  float y1 = fmaf(gg.y, (v.y - m) * rstd, bb.y);
  y0 = 0.5f * y0 * (1.f + erff(y0 * 0.7071067811865476f));
  y1 = 0.5f * y1 * (1.f + erff(y1 * 0.7071067811865476f));
  float2 o;
  o.x = y0 + rr.x;
  o.y = y1 + rr.y;
  ((float2*)out)[(size_t)w * 64 + lane] = o;
}

__global__ __launch_bounds__(128) void seg_pool2(const float* __restrict__ ZA,
                                                 const int* __restrict__ bidxA, int nA,
                                                 int nbA, float* poolA,
                                                 const float* __restrict__ ZB,
                                                 const int* __restrict__ bidxB, int nB,
                                                 float* poolB) {
  const bool A = (int)blockIdx.x < nbA;
  const int lb = A ? blockIdx.x : blockIdx.x - nbA;
  const float* Z = A ? ZA : ZB;
  const int* bidx = A ? bidxA : bidxB;
  const int n = A ? nA : nB;
  float* pool = A ? poolA : poolB;
  const int c = threadIdx.x;
  const int r0 = lb * 128;
  const int re = min(r0 + 128, n);
  if (r0 >= n) return;
  float acc = 0.f;
  int cur = bidx[r0];
  for (int r = r0; r < re; r++) {
    const int bb = bidx[r];
    if (bb != cur) {
      atomicAdd(&pool[cur * 128 + c], acc);
      acc = 0.f;
      cur = bb;
    }
    acc += Z[(size_t)r * 128 + c];
  }
  atomicAdd(&pool[cur * 128 + c], acc);
}

__global__ __launch_bounds__(128) void graph_gemm(
    const float* __restrict__ zg, const float* __restrict__ eg,
    const int* __restrict__ cnz, const int* __restrict__ cne,
    const float* __restrict__ Wf, const float* __restrict__ bf, float* out) {
  __shared__ float cat[256];
  const int g = blockIdx.x, t = threadIdx.x;
  cat[t] = zg[g * 128 + t] / fmaxf((float)cnz[g], 1.f);
  cat[128 + t] = eg[g * 128 + t] / fmaxf((float)cne[g], 1.f);
  __syncthreads();
  float acc = bf[t];
#pragma unroll 8
  for (int k = 0; k < 256; k++) acc = fmaf(cat[k], Wf[k * 128 + t], acc);
  out[g * 128 + t] = acc;
}

extern "C" void kernel_launch(void* const* d_in, const int* in_sizes, int n_in,
                              void* d_out, int out_size, void* d_ws, size_t ws_size,
                              hipStream_t stream) {
  const float* x = (const float*)d_in[0];
  const float* hf = (const float*)d_in[1];
  const float* coord = (const float*)d_in[2];
  const int* ni = (const int*)d_in[3];
  const int* ei = (const int*)d_in[4];
  const int* nb = (const int*)d_in[5];
  const int* hb = (const int*)d_in[6];
  const int* xx = (const int*)d_in[7];
  const int* ee = (const int*)d_in[8];
  const float* Wv = (const float*)d_in[10];
  const float* bv = (const float*)d_in[11];
  const float* We = (const float*)d_in[12];
  const float* be = (const float*)d_in[13];
  const float* Wx = (const float*)d_in[14];
  const float* bx = (const float*)d_in[15];
  const float* Weg = (const float*)d_in[16];
  const float* beg = (const float*)d_in[17];
  const float* lng = (const float*)d_in[18];
  const float* lnb = (const float*)d_in[19];
  const float* Wf = (const float*)d_in[20];
  const float* bf = (const float*)d_in[21];

  const int N = in_sizes[0] / 128;
  const int M = in_sizes[1] / 128;
  const int NNZ = in_sizes[3];
  const int EG = in_sizes[7] / 2;
  const int EE = in_sizes[8] / 2;

  float* ws = (float*)d_ws;
  size_t o = 0;
  float* xw = ws + o;     o += (size_t)N * 128;  // dead by gram time -> gpart alias
  float* ew = ws + o;     o += (size_t)M * 128;
  float* xw2 = ws + o;    o += (size_t)N * 128;
  float* ew2 = ws + o;    o += (size_t)M * 128;
  float* z_conv = ws + o; o += (size_t)N * 128;
  float* e_conv = ws + o; o += (size_t)M * 128;
  float* ecoord = ws + o; o += (size_t)M * 3;
  float* rs_gx = ws + o;  o += N;
  float* rs_ge = ws + o;  o += M;
  float* G1 = ws + o;     o += 16384;
  float* G2 = ws + o;     o += 16384;
  const size_t fz0 = o;  // zeroed float block
  float* st = ws + o;     o += 1024;
  float* zg = ws + o;     o += NB * 128;
  float* eg = ws + o;     o += NB * 128;
  const size_t fz1 = o;
  int* wsi = (int*)(ws + o);
  size_t oi = 0;
  int* cnt_n = wsi + oi;  oi += N;  // becomes cursor after scan
  int* cnt_e = wsi + oi;  oi += M;
  int* cnt_gx = wsi + oi; oi += N;
  int* cnt_ge = wsi + oi; oi += M;
  const size_t iz1 = oi;
  int* rp_n = wsi + oi;   oi += N + 1;
  int* rp_e = wsi + oi;   oi += M + 1;
  int* rp_gx = wsi + oi;  oi += N + 1;
  int* rp_ge = wsi + oi;  oi += M + 1;
  int* adj_n = wsi + oi;  oi += NNZ;
  int* adj_e = wsi + oi;  oi += NNZ;
  int* adj_gx = wsi + oi; oi += EG;
  int* adj_ge = wsi + oi; oi += EE;
  int* cbn = wsi + oi;    oi += NB;
  int* cbe = wsi + oi;    oi += NB;
  int* bsums = wsi + oi;  oi += 64;
  int* bbase = wsi + oi;  oi += 64;
  int* totals = wsi + oi; oi += 4;

  float* gpartA = xw;                        // GPN*16384 floats
  float* gpartB = xw + (size_t)GPN * 16384;  // GPM*16384 floats (dead xw/ew/xw2)

  float* outz = (float*)d_out;           // temporarily z_imp
  float* oute = outz + (size_t)N * 128;  // temporarily e_imp
  float* outc = oute + (size_t)M * 128;
  float* outg = outc + (size_t)N * 3;
  float* outbt = outg + NB * 128;

  hipMemsetAsync(ws + fz0, 0, (fz1 - fz0) * 4, stream);
  hipMemsetAsync(wsi, 0, iz1 * 4, stream);
  hipMemsetAsync(outbt, 0, 4, stream);

  // dense projections (fused pairs sharing the input)
  gemm128x2<<<(N + 63) / 64, 256, 0, stream>>>(x, Wv, bv, xw, Wx, xw2, N);
  gemm128x2<<<(M + 63) / 64, 256, 0, stream>>>(hf, We, be, ew, Weg, ew2, M);

  // CSR build
  const int tot = NNZ + EG + EE;
  count_all<<<(tot + 255) / 256, 256, 0, stream>>>(ni, ei, NNZ, xx, EG, ee, EE,
                                                   cnt_n, cnt_e, cnt_gx, cnt_ge);
  const int nb0 = (N + 4095) >> 12, nb1 = (M + 4095) >> 12;
  const int sgrid = 2 * nb0 + 2 * nb1;
  scan_partial<<<sgrid, 256, 0, stream>>>(cnt_n, N, cnt_e, M, cnt_gx, N, cnt_ge, M,
                                          nb0, nb1, nb0, nb1, bsums);
  scan_bsums<<<1, 64, 0, stream>>>(bsums, nb0, nb1, nb0, nb1, bbase, totals);
  scan_final<<<sgrid, 256, 0, stream>>>(
      cnt_n, rp_n, nullptr, N, cnt_e, rp_e, nullptr, M, cnt_gx, rp_gx, rs_gx, N,
      cnt_ge, rp_ge, rs_ge, M, nb0, nb1, nb0, nb1, bbase, totals);
  fill_all<<<(tot + 255) / 256, 256, 0, stream>>>(ni, ei, NNZ, xx, EG, ee, EE, cnt_n,
                                                  cnt_e, cnt_gx, cnt_ge, adj_n, adj_e,
                                                  adj_gx, adj_ge);
  batch_counts2<<<2, 64, 0, stream>>>(nb, N, cbn, hb, M, cbe);

  // hypergraph conv (gather form) + coord update
  hedge_gather<<<(M + 3) / 4, 256, 0, stream>>>(xw, coord, rp_e, adj_e, e_conv, ecoord, M);
  node_gather<<<(N + 3) / 4, 256, 0, stream>>>(ew, xw, coord, ecoord, rp_n, adj_n,
                                               z_conv, outc, N);

  // GCN branches into d_out z/e regions (z_imp/e_imp)
  const int gcnA = (N + 3) / 4;
  gcn_gather2<<<gcnA + (M + 3) / 4, 256, 0, stream>>>(
      xw2, rp_gx, adj_gx, rs_gx, bx, outz, N, gcnA, ew2, rp_ge, adj_ge, rs_ge, beg,
      oute, M);

  // barlow-twins: split-K gram with fused column stats (xw..ew2 now dead)
  gram_partial2<<<GPN + GPM, 256, 0, stream>>>(outz, z_conv, N, gpartA, oute, e_conv,
                                               M, gpartB, st, GPN);
  gram_reduce2<<<128, 256, 0, stream>>>(gpartA, G1, gpartB, G2);
  barlow_fin2<<<2, 256, 0, stream>>>(G1, G2, st, (float)N, (float)M, outbt);

  // final z/e (overwrite z_imp/e_imp AFTER gram consumed them)
  const int lnA = (N + 3) / 4;
  ln_gelu_res2<<<lnA + (M + 3) / 4, 256, 0, stream>>>(z_conv, x, outz, N, lnA, e_conv,
                                                      hf, oute, M, lng, lnb);

  // pooling + output linear
  const int spA = (N + 127) / 128;
  seg_pool2<<<spA + (M + 127) / 128, 128, 0, stream>>>(outz, nb, N, spA, zg, oute, hb,
                                                       M, eg);
  graph_gemm<<<NB, 128, 0, stream>>>(zg, eg, cbn, cbe, Wf, bf, outg);
}

// Round 6
// 521.430 us; speedup vs baseline: 5.2619x; 1.1908x over previous
//
#include <hip/hip_runtime.h>
#include <hip/hip_bf16.h>

#define NB 32       // num_graphs
#define GPN 512     // split-K parts for gram (N side)
#define GPM 128     // split-K parts for gram (M side)
#define RGRP 16     // partials reduced per block in gram_reduce2

__device__ __forceinline__ float wave_sum(float v) {
#pragma unroll
  for (int off = 32; off; off >>= 1) v += __shfl_xor(v, off);
  return v;
}
__device__ __forceinline__ int wave_sum_i(int v) {
#pragma unroll
  for (int off = 32; off; off >>= 1) v += __shfl_xor(v, off);
  return v;
}

// ---- fused dual GEMM: out1 = X@W1 + b1, out2 = X@W2 ----
__global__ __launch_bounds__(256) void gemm128x2(const float* __restrict__ X,
                                                 const float* __restrict__ W1,
                                                 const float* __restrict__ b1,
                                                 float* __restrict__ out1,
                                                 const float* __restrict__ W2,
                                                 float* __restrict__ out2, int rows) {
  __shared__ float xs[64][132];
  const int t = threadIdx.x;
  const int c4 = t & 31;
  const int rg = t >> 5;
  const int r0 = blockIdx.x * 64;
#pragma unroll
  for (int i = 0; i < 8; i++) {
    const int idx = t + i * 256;
    const int row = idx >> 5, cc = idx & 31;
    const int gr = r0 + row;
    float4 v = make_float4(0.f, 0.f, 0.f, 0.f);
    if (gr < rows) v = ((const float4*)X)[(size_t)gr * 32 + cc];
    *(float4*)&xs[row][cc * 4] = v;
  }
  __syncthreads();
  const float4* W1v = (const float4*)W1;
  const float4* W2v = (const float4*)W2;
  const float4 b4 = ((const float4*)b1)[c4];
  float4 acc1[8], acc2[8];
#pragma unroll
  for (int i = 0; i < 8; i++) {
    acc1[i] = b4;
    acc2[i] = make_float4(0.f, 0.f, 0.f, 0.f);
  }
  const int rbase = rg * 8;
#pragma unroll 2
  for (int k = 0; k < 128; k++) {
    const float4 w1 = W1v[k * 32 + c4];
    const float4 w2 = W2v[k * 32 + c4];
#pragma unroll
    for (int i = 0; i < 8; i++) {
      const float xv = xs[rbase + i][k];
      acc1[i].x = fmaf(xv, w1.x, acc1[i].x);
      acc1[i].y = fmaf(xv, w1.y, acc1[i].y);
      acc1[i].z = fmaf(xv, w1.z, acc1[i].z);
      acc1[i].w = fmaf(xv, w1.w, acc1[i].w);
      acc2[i].x = fmaf(xv, w2.x, acc2[i].x);
      acc2[i].y = fmaf(xv, w2.y, acc2[i].y);
      acc2[i].z = fmaf(xv, w2.z, acc2[i].z);
      acc2[i].w = fmaf(xv, w2.w, acc2[i].w);
    }
  }
#pragma unroll
  for (int i = 0; i < 8; i++) {
    const int gr = r0 + rbase + i;
    if (gr < rows) {
      ((float4*)out1)[(size_t)gr * 32 + c4] = acc1[i];
      ((float4*)out2)[(size_t)gr * 32 + c4] = acc2[i];
    }
  }
}

// ---------- CSR build ----------
__global__ void count_all(const int* __restrict__ ni, const int* __restrict__ ei,
                          int nnz, const int* __restrict__ xx, int eg,
                          const int* __restrict__ ee, int eeN, int* cn, int* ce,
                          int* cgx, int* cge) {
  int i = blockIdx.x * blockDim.x + threadIdx.x;
  if (i < nnz) {
    atomicAdd(&cn[ni[i]], 1);
    atomicAdd(&ce[ei[i]], 1);
  } else if (i < nnz + eg) {
    atomicAdd(&cgx[xx[eg + (i - nnz)]], 1);
  } else if (i < nnz + eg + eeN) {
    atomicAdd(&cge[ee[eeN + (i - nnz - eg)]], 1);
  }
}

__global__ __launch_bounds__(256) void scan_partial(
    const int* __restrict__ c0, int n0, const int* __restrict__ c1, int n1,
    const int* __restrict__ c2, int n2, const int* __restrict__ c3, int n3,
    int nb0, int nb1, int nb2, int nb3, int* __restrict__ bsums) {
  const int gb = blockIdx.x;
  const int* cnt;
  int lb, n;
  if (gb < nb0) { cnt = c0; lb = gb; n = n0; }
  else if (gb < nb0 + nb1) { cnt = c1; lb = gb - nb0; n = n1; }
  else if (gb < nb0 + nb1 + nb2) { cnt = c2; lb = gb - nb0 - nb1; n = n2; }
  else { cnt = c3; lb = gb - nb0 - nb1 - nb2; n = n3; }
  const int t = threadIdx.x;
  const int base = lb * 4096 + t * 16;
  int s = 0;
#pragma unroll
  for (int i = 0; i < 16; i++) {
    const int idx = base + i;
    if (idx < n) s += cnt[idx];
  }
  const int wsum = wave_sum_i(s);
  __shared__ int wsm[4];
  if ((t & 63) == 0) wsm[t >> 6] = wsum;
  __syncthreads();
  if (t == 0) bsums[gb] = wsm[0] + wsm[1] + wsm[2] + wsm[3];
}

__global__ void scan_bsums(const int* __restrict__ bsums, int nb0, int nb1, int nb2,
                           int nb3, int* __restrict__ bbase, int* __restrict__ totals) {
  if (threadIdx.x) return;
  int segs[4] = {nb0, nb1, nb2, nb3};
  int gb = 0;
  for (int a = 0; a < 4; a++) {
    int run = 0;
    for (int i = 0; i < segs[a]; i++) {
      bbase[gb] = run;
      run += bsums[gb];
      gb++;
    }
    totals[a] = run;
  }
}

__global__ __launch_bounds__(256) void scan_final(
    int* __restrict__ c0, int* rp0, float* rs0, int n0,
    int* __restrict__ c1, int* rp1, float* rs1, int n1,
    int* __restrict__ c2, int* rp2, float* rs2, int n2,
    int* __restrict__ c3, int* rp3, float* rs3, int n3,
    int nb0, int nb1, int nb2, int nb3, const int* __restrict__ bbase,
    const int* __restrict__ totals) {
  const int gb = blockIdx.x;
  int* cnt;
  int* rp;
  float* rs;
  int lb, n, a;
  if (gb < nb0) { cnt = c0; rp = rp0; rs = rs0; lb = gb; n = n0; a = 0; }
  else if (gb < nb0 + nb1) { cnt = c1; rp = rp1; rs = rs1; lb = gb - nb0; n = n1; a = 1; }
  else if (gb < nb0 + nb1 + nb2) { cnt = c2; rp = rp2; rs = rs2; lb = gb - nb0 - nb1; n = n2; a = 2; }
  else { cnt = c3; rp = rp3; rs = rs3; lb = gb - nb0 - nb1 - nb2; n = n3; a = 3; }
  const int t = threadIdx.x;
  const int base = lb * 4096 + t * 16;
  int vals[16];
  int s = 0;
#pragma unroll
  for (int i = 0; i < 16; i++) {
    const int idx = base + i;
    vals[i] = (idx < n) ? cnt[idx] : 0;
    s += vals[i];
  }
  __shared__ int tsum[256];
  tsum[t] = s;
  __syncthreads();
  for (int off = 1; off < 256; off <<= 1) {
    const int v = (t >= off) ? tsum[t - off] : 0;
    __syncthreads();
    tsum[t] += v;
    __syncthreads();
  }
  int run = bbase[gb] + (t ? tsum[t - 1] : 0);
#pragma unroll
  for (int i = 0; i < 16; i++) {
    const int idx = base + i;
    if (idx < n) {
      rp[idx] = run;
      cnt[idx] = run;  // cursor for fill
      if (rs) rs[idx] = rsqrtf(1.f + (float)vals[i]);
      run += vals[i];
    }
  }
  if (t == 0 && lb == 0) rp[n] = totals[a];
}

__global__ void fill_all(const int* __restrict__ ni, const int* __restrict__ ei,
                         int nnz, const int* __restrict__ xx, int eg,
                         const int* __restrict__ ee, int eeN, int* cur_n, int* cur_e,
                         int* cur_gx, int* cur_ge, int* adj_n, int* adj_e,
                         int* adj_gx, int* adj_ge) {
  int i = blockIdx.x * blockDim.x + threadIdx.x;
  if (i < nnz) {
    const int n = ni[i], e = ei[i];
    adj_n[atomicAdd(&cur_n[n], 1)] = e;
    adj_e[atomicAdd(&cur_e[e], 1)] = n;
  } else if (i < nnz + eg) {
    const int j = i - nnz;
    adj_gx[atomicAdd(&cur_gx[xx[eg + j]], 1)] = xx[j];
  } else if (i < nnz + eg + eeN) {
    const int j = i - nnz - eg;
    adj_ge[atomicAdd(&cur_ge[ee[eeN + j]], 1)] = ee[j];
  }
}

__global__ void batch_counts2(const int* __restrict__ nbi, int n, int* cbn,
                              const int* __restrict__ hbi, int m, int* cbe) {
  const int* idx = blockIdx.x ? hbi : nbi;
  const int nn = blockIdx.x ? m : n;
  int* out = blockIdx.x ? cbe : cbn;
  int b = threadIdx.x;
  if (b >= NB) return;
  int lo = 0, hi = nn;
  while (lo < hi) { int mid = (lo + hi) >> 1; if (idx[mid] < b) lo = mid + 1; else hi = mid; }
  const int l = lo;
  lo = 0; hi = nn;
  while (lo < hi) { int mid = (lo + hi) >> 1; if (idx[mid] < b + 1) lo = mid + 1; else hi = mid; }
  out[b] = lo - l;
}

// ---------- gathers ----------
__global__ __launch_bounds__(256) void hedge_gather(
    const float* __restrict__ xw, const float* __restrict__ coord,
    const int* __restrict__ rowptr, const int* __restrict__ adj,
    float* __restrict__ e_conv, float* __restrict__ ecoord, int m) {
  const int e = (blockIdx.x * blockDim.x + threadIdx.x) >> 6;
  const int lane = threadIdx.x & 63;
  if (e >= m) return;
  const int lo = rowptr[e], hi = rowptr[e + 1];
  float2 acc = make_float2(0.f, 0.f);
  float cacc = 0.f;
  for (int base = lo; base < hi; base += 64) {
    const int mm = min(64, hi - base);
    int aj = (base + lane < hi) ? adj[base + lane] : 0;
    for (int j = 0; j < mm; j++) {
      const int nidx = __shfl(aj, j);
      const float2 v = ((const float2*)xw)[(size_t)nidx * 64 + lane];
      acc.x += v.x;
      acc.y += v.y;
      if (lane < 3) cacc += coord[nidx * 3 + lane];
    }
  }
  const float inv = 1.f / fmaxf((float)(hi - lo), 1.f);
  ((float2*)e_conv)[(size_t)e * 64 + lane] = make_float2(acc.x * inv, acc.y * inv);
  if (lane < 3) ecoord[e * 3 + lane] = cacc * inv;
}

__global__ __launch_bounds__(256) void node_gather(
    const float* __restrict__ ew, const float* __restrict__ xw,
    const float* __restrict__ coord, const float* __restrict__ ecoord,
    const int* __restrict__ rowptr, const int* __restrict__ adj,
    float* __restrict__ z_conv, float* __restrict__ outc, int n) {
  const int r = (blockIdx.x * blockDim.x + threadIdx.x) >> 6;
  const int lane = threadIdx.x & 63;
  if (r >= n) return;
  const int lo = rowptr[r], hi = rowptr[r + 1];
  const float2 a = ((const float2*)xw)[(size_t)r * 64 + lane];
  const float myc = (lane < 3) ? coord[r * 3 + lane] : 0.f;
  float2 acc = make_float2(0.f, 0.f);
  float cacc = 0.f;
  for (int base = lo; base < hi; base += 64) {
    const int mm = min(64, hi - base);
    int aj = (base + lane < hi) ? adj[base + lane] : 0;
    for (int j = 0; j < mm; j++) {
      const int e = __shfl(aj, j);
      const float2 b = ((const float2*)ew)[(size_t)e * 64 + lane];
      acc.x += b.x;
      acc.y += b.y;
      const float dot = wave_sum(fmaf(a.x, b.x, a.y * b.y));
      const float ph = tanhf(dot * 0.08838834764831845f);  // 1/sqrt(128)
      if (lane < 3) cacc = fmaf(myc - ecoord[e * 3 + lane], ph, cacc);
    }
  }
  const float inv = 1.f / fmaxf((float)(hi - lo), 1.f);
  ((float2*)z_conv)[(size_t)r * 64 + lane] = make_float2(acc.x * inv, acc.y * inv);
  if (lane < 3) outc[r * 3 + lane] = myc + cacc * inv;
}

__global__ __launch_bounds__(256) void gcn_gather2(
    const float* __restrict__ xwA, const int* __restrict__ rpA,
    const int* __restrict__ adjA, const float* __restrict__ rsA,
    const float* __restrict__ biasA, float* __restrict__ outA, int nA, int nbA,
    const float* __restrict__ xwB, const int* __restrict__ rpB,
    const int* __restrict__ adjB, const float* __restrict__ rsB,
    const float* __restrict__ biasB, float* __restrict__ outB, int nB) {
  const bool A = blockIdx.x < nbA;
  const int lb = A ? blockIdx.x : blockIdx.x - nbA;
  const float* xw = A ? xwA : xwB;
  const int* rowptr = A ? rpA : rpB;
  const int* adj = A ? adjA : adjB;
  const float* rs = A ? rsA : rsB;
  const float* bias = A ? biasA : biasB;
  float* out = A ? outA : outB;
  const int n = A ? nA : nB;
  const int r = (lb * 256 + (int)threadIdx.x) >> 6;
  const int lane = threadIdx.x & 63;
  if (r >= n) return;
  const int lo = rowptr[r], hi = rowptr[r + 1];
  const float rd = rs[r];
  float2 acc = make_float2(0.f, 0.f);
  for (int base = lo; base < hi; base += 64) {
    const int mm = min(64, hi - base);
    int aj = 0;
    float rj = 0.f;
    if (base + lane < hi) {
      aj = adj[base + lane];
      rj = rs[aj];
    }
    for (int j = 0; j < mm; j++) {
      const int s = __shfl(aj, j);
      const float w = __shfl(rj, j);
      const float2 v = ((const float2*)xw)[(size_t)s * 64 + lane];
      acc.x = fmaf(w, v.x, acc.x);
      acc.y = fmaf(w, v.y, acc.y);
    }
  }
  const float2 self = ((const float2*)xw)[(size_t)r * 64 + lane];
  const float2 bb = ((const float2*)bias)[lane];
  float2 o;
  o.x = fmaf(rd, acc.x, fmaf(rd * rd, self.x, bb.x));
  o.y = fmaf(rd, acc.y, fmaf(rd * rd, self.y, bb.y));
  ((float2*)out)[(size_t)r * 64 + lane] = o;
}

// ---------- barlow: split-K gram + fused colstats ----------
__global__ __launch_bounds__(256) void gram_partial2(
    const float* __restrict__ Z1a, const float* __restrict__ Z2a, int na,
    float* __restrict__ parta, const float* __restrict__ Z1b,
    const float* __restrict__ Z2b, int nbm, float* __restrict__ partb,
    float* __restrict__ st, int nblkA) {
  const bool A = (int)blockIdx.x < nblkA;
  const int pid = A ? blockIdx.x : blockIdx.x - nblkA;
  const float* Z1 = A ? Z1a : Z1b;
  const float* Z2 = A ? Z2a : Z2b;
  const int n = A ? na : nbm;
  const int gparts = A ? GPN : GPM;
  float* part = (A ? parta : partb) + (size_t)pid * 16384;
  float* sum1 = st + (A ? 0 : 512);
  float* ssq1 = sum1 + 128;
  float* sum2 = sum1 + 256;
  float* ssq2 = sum1 + 384;
  __shared__ float4 s1[256], s2[256];
  const int t = threadIdx.x;
  const int ti = t >> 4, tj = t & 15;
  const int rpb = (n + gparts - 1) / gparts;
  const int lo = pid * rpb, hi = min(lo + rpb, n);
  float acc[8][8];
#pragma unroll
  for (int i = 0; i < 8; i++)
#pragma unroll
    for (int j = 0; j < 8; j++) acc[i][j] = 0.f;
  float cs = 0.f, cq = 0.f;
  const float* s1f = (const float*)s1;
  const float* s2f = (const float*)s2;
  const int c = t & 127;
  const bool low = t < 128;
  for (int rb = lo; rb < hi; rb += 8) {
    const int nr = min(8, hi - rb);
    __syncthreads();
    if (t < nr * 32) {
      const int rr = rb + (t >> 5);
      s1[t] = ((const float4*)Z1)[(size_t)rr * 32 + (t & 31)];
      s2[t] = ((const float4*)Z2)[(size_t)rr * 32 + (t & 31)];
    }
    __syncthreads();
    for (int r = 0; r < nr; r++) {
      const float4 a0 = s1[r * 32 + ti * 2], a1 = s1[r * 32 + ti * 2 + 1];
      const float4 b0 = s2[r * 32 + tj * 2], b1 = s2[r * 32 + tj * 2 + 1];
      const float av[8] = {a0.x, a0.y, a0.z, a0.w, a1.x, a1.y, a1.z, a1.w};
      const float bv[8] = {b0.x, b0.y, b0.z, b0.w, b1.x, b1.y, b1.z, b1.w};
#pragma unroll
      for (int i = 0; i < 8; i++)
#pragma unroll
        for (int j = 0; j < 8; j++) acc[i][j] = fmaf(av[i], bv[j], acc[i][j]);
      const float v = low ? s1f[r * 128 + c] : s2f[r * 128 + c];
      cs += v;
      cq = fmaf(v, v, cq);
    }
  }
  float4* P = (float4*)part;
#pragma unroll
  for (int i = 0; i < 8; i++) {
    P[(ti * 8 + i) * 32 + tj * 2] = make_float4(acc[i][0], acc[i][1], acc[i][2], acc[i][3]);
    P[(ti * 8 + i) * 32 + tj * 2 + 1] = make_float4(acc[i][4], acc[i][5], acc[i][6], acc[i][7]);
  }
  if (low) {
    atomicAdd(&sum1[c], cs);
    atomicAdd(&ssq1[c], cq);
  } else {
    atomicAdd(&sum2[c], cs);
    atomicAdd(&ssq2[c], cq);
  }
}

// hierarchical reduce: block = (group of RGRP partials) x (1024-elem slice), atomicAdd into G
__global__ __launch_bounds__(256) void gram_reduce2(const float* __restrict__ parta,
                                                    float* __restrict__ G1,
                                                    const float* __restrict__ partb,
                                                    float* __restrict__ G2) {
  const int nga = GPN / RGRP;            // 32 groups (A)
  const int slice = blockIdx.x & 15;     // 16 slices x 1024 elems
  const int grp = blockIdx.x >> 4;
  const bool A = grp < nga;
  const float* part = A ? parta : partb;
  float* G = A ? G1 : G2;
  const int g0 = (A ? grp : grp - nga) * RGRP;
  const int e = slice * 1024 + threadIdx.x * 4;
  float4 s = make_float4(0.f, 0.f, 0.f, 0.f);
#pragma unroll 4
  for (int p = 0; p < RGRP; p++) {
    const float4 v = *(const float4*)&part[(size_t)(g0 + p) * 16384 + e];
    s.x += v.x;
    s.y += v.y;
    s.z += v.z;
    s.w += v.w;
  }
  atomicAdd(&G[e], s.x);
  atomicAdd(&G[e + 1], s.y);
  atomicAdd(&G[e + 2], s.z);
  atomicAdd(&G[e + 3], s.w);
}

__global__ __launch_bounds__(256) void barlow_fin2(const float* __restrict__ G1,
                                                   const float* __restrict__ G2,
                                                   const float* __restrict__ st,
                                                   float nA, float nB, float* out) {
  const bool A = blockIdx.x == 0;
  const float* G = A ? G1 : G2;
  const float* sum1 = st + (A ? 0 : 512);
  const float* ssq1 = sum1 + 128;
  const float* sum2 = sum1 + 256;
  const float* ssq2 = sum1 + 384;
  const float n = A ? nA : nB;
  __shared__ float s1s[128], m1s[128], s2s[128], m2s[128];
  __shared__ float red[256];
  const int t = threadIdx.x;
  if (t < 128) {
    const float inv_n = 1.f / n;
    const float bnf = (n - 1.f) * inv_n + 1e-5f;
    float mu = sum1[t] * inv_n;
    float vu = (ssq1[t] * inv_n - mu * mu) * n / (n - 1.f);
    s1s[t] = rsqrtf(vu * bnf);
    m1s[t] = mu;
    mu = sum2[t] * inv_n;
    vu = (ssq2[t] * inv_n - mu * mu) * n / (n - 1.f);
    s2s[t] = rsqrtf(vu * bnf);
    m2s[t] = mu;
  }
  __syncthreads();
  float on = 0.f, off = 0.f;
  for (int idx = t; idx < 16384; idx += 256) {
    const int i = idx >> 7, j = idx & 127;
    const float c = s1s[i] * s2s[j] * (G[idx] - n * m1s[i] * m2s[j]) * (1.f / 32.f);
    if (i == j) {
      const float dd = c - 1.f;
      on += dd * dd;
    } else {
      off += c * c;
    }
  }
  red[t] = on + 0.005f * off;
  __syncthreads();
  for (int s = 128; s; s >>= 1) {
    if (t < s) red[t] += red[t + s];
    __syncthreads();
  }
  if (t == 0) atomicAdd(out, red[0]);
}

// ---------- epilogue ----------
__global__ __launch_bounds__(256) void ln_gelu_res2(
    const float* __restrict__ convA, const float* __restrict__ residA,
    float* __restrict__ outA, int nA, int nbA, const float* __restrict__ convB,
    const float* __restrict__ residB, float* __restrict__ outB, int nB,
    const float* __restrict__ g, const float* __restrict__ b) {
  const bool A = (int)blockIdx.x < nbA;
  const int lb = A ? blockIdx.x : blockIdx.x - nbA;
  const float* conv = A ? convA : convB;
  const float* resid = A ? residA : residB;
  float* out = A ? outA : outB;
  const int rows = A ? nA : nB;
  const int w = (lb * 256 + (int)threadIdx.x) >> 6;
  const int lane = threadIdx.x & 63;
  if (w >= rows) return;
  const float2 v = ((const float2*)conv)[(size_t)w * 64 + lane];
  const float m = wave_sum(v.x + v.y) * (1.f / 128.f);
  const float q = wave_sum(fmaf(v.x, v.x, v.y * v.y)) * (1.f / 128.f);
  const float rstd = rsqrtf(q - m * m + 1e-5f);
  const float2 gg = ((const float2*)g)[lane];
  const float2 bb = ((const float2*)b)[lane];
  const float2 rr = ((const float2*)resid)[(size_t)w * 64 + lane];
  float y0 = fmaf(gg.x, (v.x - m) * rstd, bb.x);
  float y1 = fmaf(gg.y, (v.y - m) * rstd, bb.y);
  y0 = 0.5f * y0 * (1.f + erff(y0 * 0.7071067811865476f));
  y1 = 0.5f * y1 * (1.f + erff(y1 * 0.7071067811865476f));
  float2 o;
  o.x = y0 + rr.x;
  o.y = y1 + rr.y;
  ((float2*)out)[(size_t)w * 64 + lane] = o;
}

__global__ __launch_bounds__(128) void seg_pool2(const float* __restrict__ ZA,
                                                 const int* __restrict__ bidxA, int nA,
                                                 int nbA, float* poolA,
                                                 const float* __restrict__ ZB,
                                                 const int* __restrict__ bidxB, int nB,
                                                 float* poolB) {
  const bool A = (int)blockIdx.x < nbA;
  const int lb = A ? blockIdx.x : blockIdx.x - nbA;
  const float* Z = A ? ZA : ZB;
  const int* bidx = A ? bidxA : bidxB;
  const int n = A ? nA : nB;
  float* pool = A ? poolA : poolB;
  const int c = threadIdx.x;
  const int r0 = lb * 128;
  const int re = min(r0 + 128, n);
  if (r0 >= n) return;
  float acc = 0.f;
  int cur = bidx[r0];
  for (int r = r0; r < re; r++) {
    const int bb = bidx[r];
    if (bb != cur) {
      atomicAdd(&pool[cur * 128 + c], acc);
      acc = 0.f;
      cur = bb;
    }
    acc += Z[(size_t)r * 128 + c];
  }
  atomicAdd(&pool[cur * 128 + c], acc);
}

__global__ __launch_bounds__(128) void graph_gemm(
    const float* __restrict__ zg, const float* __restrict__ eg,
    const int* __restrict__ cnz, const int* __restrict__ cne,
    const float* __restrict__ Wf, const float* __restrict__ bf, float* out) {
  __shared__ float cat[256];
  const int g = blockIdx.x, t = threadIdx.x;
  cat[t] = zg[g * 128 + t] / fmaxf((float)cnz[g], 1.f);
  cat[128 + t] = eg[g * 128 + t] / fmaxf((float)cne[g], 1.f);
  __syncthreads();
  float acc = bf[t];
#pragma unroll 8
  for (int k = 0; k < 256; k++) acc = fmaf(cat[k], Wf[k * 128 + t], acc);
  out[g * 128 + t] = acc;
}

extern "C" void kernel_launch(void* const* d_in, const int* in_sizes, int n_in,
                              void* d_out, int out_size, void* d_ws, size_t ws_size,
                              hipStream_t stream) {
  const float* x = (const float*)d_in[0];
  const float* hf = (const float*)d_in[1];
  const float* coord = (const float*)d_in[2];
  const int* ni = (const int*)d_in[3];
  const int* ei = (const int*)d_in[4];
  const int* nb = (const int*)d_in[5];
  const int* hb = (const int*)d_in[6];
  const int* xx = (const int*)d_in[7];
  const int* ee = (const int*)d_in[8];
  const float* Wv = (const float*)d_in[10];
  const float* bv = (const float*)d_in[11];
  const float* We = (const float*)d_in[12];
  const float* be = (const float*)d_in[13];
  const float* Wx = (const float*)d_in[14];
  const float* bx = (const float*)d_in[15];
  const float* Weg = (const float*)d_in[16];
  const float* beg = (const float*)d_in[17];
  const float* lng = (const float*)d_in[18];
  const float* lnb = (const float*)d_in[19];
  const float* Wf = (const float*)d_in[20];
  const float* bf = (const float*)d_in[21];

  const int N = in_sizes[0] / 128;
  const int M = in_sizes[1] / 128;
  const int NNZ = in_sizes[3];
  const int EG = in_sizes[7] / 2;
  const int EE = in_sizes[8] / 2;

  float* ws = (float*)d_ws;
  size_t o = 0;
  float* xw = ws + o;     o += (size_t)N * 128;  // dead by gram time -> gpart alias
  float* ew = ws + o;     o += (size_t)M * 128;
  float* xw2 = ws + o;    o += (size_t)N * 128;
  float* ew2 = ws + o;    o += (size_t)M * 128;
  float* z_conv = ws + o; o += (size_t)N * 128;
  float* e_conv = ws + o; o += (size_t)M * 128;
  float* ecoord = ws + o; o += (size_t)M * 3;
  float* rs_gx = ws + o;  o += N;
  float* rs_ge = ws + o;  o += M;
  const size_t fz0 = o;  // zeroed float block
  float* G1 = ws + o;     o += 16384;  // accumulated by gram_reduce2 -> must be zeroed
  float* G2 = ws + o;     o += 16384;
  float* st = ws + o;     o += 1024;
  float* zg = ws + o;     o += NB * 128;
  float* eg = ws + o;     o += NB * 128;
  const size_t fz1 = o;
  int* wsi = (int*)(ws + o);
  size_t oi = 0;
  int* cnt_n = wsi + oi;  oi += N;  // becomes cursor after scan
  int* cnt_e = wsi + oi;  oi += M;
  int* cnt_gx = wsi + oi; oi += N;
  int* cnt_ge = wsi + oi; oi += M;
  const size_t iz1 = oi;
  int* rp_n = wsi + oi;   oi += N + 1;
  int* rp_e = wsi + oi;   oi += M + 1;
  int* rp_gx = wsi + oi;  oi += N + 1;
  int* rp_ge = wsi + oi;  oi += M + 1;
  int* adj_n = wsi + oi;  oi += NNZ;
  int* adj_e = wsi + oi;  oi += NNZ;
  int* adj_gx = wsi + oi; oi += EG;
  int* adj_ge = wsi + oi; oi += EE;
  int* cbn = wsi + oi;    oi += NB;
  int* cbe = wsi + oi;    oi += NB;
  int* bsums = wsi + oi;  oi += 64;
  int* bbase = wsi + oi;  oi += 64;
  int* totals = wsi + oi; oi += 4;

  float* gpartA = xw;                        // GPN*16384 floats
  float* gpartB = xw + (size_t)GPN * 16384;  // GPM*16384 floats (dead xw/ew/xw2)

  float* outz = (float*)d_out;           // temporarily z_imp
  float* oute = outz + (size_t)N * 128;  // temporarily e_imp
  float* outc = oute + (size_t)M * 128;
  float* outg = outc + (size_t)N * 3;
  float* outbt = outg + NB * 128;

  hipMemsetAsync(ws + fz0, 0, (fz1 - fz0) * 4, stream);
  hipMemsetAsync(wsi, 0, iz1 * 4, stream);
  hipMemsetAsync(outbt, 0, 4, stream);

  // dense projections (fused pairs sharing the input)
  gemm128x2<<<(N + 63) / 64, 256, 0, stream>>>(x, Wv, bv, xw, Wx, xw2, N);
  gemm128x2<<<(M + 63) / 64, 256, 0, stream>>>(hf, We, be, ew, Weg, ew2, M);

  // CSR build
  const int tot = NNZ + EG + EE;
  count_all<<<(tot + 255) / 256, 256, 0, stream>>>(ni, ei, NNZ, xx, EG, ee, EE,
                                                   cnt_n, cnt_e, cnt_gx, cnt_ge);
  const int nb0 = (N + 4095) >> 12, nb1 = (M + 4095) >> 12;
  const int sgrid = 2 * nb0 + 2 * nb1;
  scan_partial<<<sgrid, 256, 0, stream>>>(cnt_n, N, cnt_e, M, cnt_gx, N, cnt_ge, M,
                                          nb0, nb1, nb0, nb1, bsums);
  scan_bsums<<<1, 64, 0, stream>>>(bsums, nb0, nb1, nb0, nb1, bbase, totals);
  scan_final<<<sgrid, 256, 0, stream>>>(
      cnt_n, rp_n, nullptr, N, cnt_e, rp_e, nullptr, M, cnt_gx, rp_gx, rs_gx, N,
      cnt_ge, rp_ge, rs_ge, M, nb0, nb1, nb0, nb1, bbase, totals);
  fill_all<<<(tot + 255) / 256, 256, 0, stream>>>(ni, ei, NNZ, xx, EG, ee, EE, cnt_n,
                                                  cnt_e, cnt_gx, cnt_ge, adj_n, adj_e,
                                                  adj_gx, adj_ge);
  batch_counts2<<<2, 64, 0, stream>>>(nb, N, cbn, hb, M, cbe);

  // hypergraph conv (gather form) + coord update
  hedge_gather<<<(M + 3) / 4, 256, 0, stream>>>(xw, coord, rp_e, adj_e, e_conv, ecoord, M);
  node_gather<<<(N + 3) / 4, 256, 0, stream>>>(ew, xw, coord, ecoord, rp_n, adj_n,
                                               z_conv, outc, N);

  // GCN branches into d_out z/e regions (z_imp/e_imp)
  const int gcnA = (N + 3) / 4;
  gcn_gather2<<<gcnA + (M + 3) / 4, 256, 0, stream>>>(
      xw2, rp_gx, adj_gx, rs_gx, bx, outz, N, gcnA, ew2, rp_ge, adj_ge, rs_ge, beg,
      oute, M);

  // barlow-twins: split-K gram with fused column stats (xw..ew2 now dead)
  gram_partial2<<<GPN + GPM, 256, 0, stream>>>(outz, z_conv, N, gpartA, oute, e_conv,
                                               M, gpartB, st, GPN);
  gram_reduce2<<<(GPN / RGRP + GPM / RGRP) * 16, 256, 0, stream>>>(gpartA, G1, gpartB, G2);
  barlow_fin2<<<2, 256, 0, stream>>>(G1, G2, st, (float)N, (float)M, outbt);

  // final z/e (overwrite z_imp/e_imp AFTER gram consumed them)
  const int lnA = (N + 3) / 4;
  ln_gelu_res2<<<lnA + (M + 3) / 4, 256, 0, stream>>>(z_conv, x, outz, N, lnA, e_conv,
                                                      hf, oute, M, lng, lnb);

  // pooling + output linear
  const int spA = (N + 127) / 128;
  seg_pool2<<<spA + (M + 127) / 128, 128, 0, stream>>>(outz, nb, N, spA, zg, oute, hb,
                                                       M, eg);
  graph_gemm<<<NB, 128, 0, stream>>>(zg, eg, cbn, cbe, Wf, bf, outg);
}

// Round 7
// 380.985 us; speedup vs baseline: 7.2017x; 1.3686x over previous
//
#include <hip/hip_runtime.h>
#include <hip/hip_bf16.h>

#define NB 32       // num_graphs
#define GPN 512     // split-K parts for gram (N side)
#define GPM 128     // split-K parts for gram (M side)
#define RGRP 16     // partials reduced per block in gram reduce

__device__ __forceinline__ float wave_sum(float v) {
#pragma unroll
  for (int off = 32; off; off >>= 1) v += __shfl_xor(v, off);
  return v;
}
__device__ __forceinline__ int wave_sum_i(int v) {
#pragma unroll
  for (int off = 32; off; off >>= 1) v += __shfl_xor(v, off);
  return v;
}

// ---- dual GEMM body: out1 = X@W1 + b1, out2 = X@W2 (64-row LDS tile, 1 K sweep) ----
__device__ __forceinline__ void gemm_body(const float* __restrict__ X,
                                          const float* __restrict__ W1,
                                          const float* __restrict__ b1,
                                          float* __restrict__ out1,
                                          const float* __restrict__ W2,
                                          float* __restrict__ out2, int rows, int blk,
                                          float (*xs)[132]) {
  const int t = threadIdx.x;
  const int c4 = t & 31;
  const int rg = t >> 5;
  const int r0 = blk * 64;
#pragma unroll
  for (int i = 0; i < 8; i++) {
    const int idx = t + i * 256;
    const int row = idx >> 5, cc = idx & 31;
    const int gr = r0 + row;
    float4 v = make_float4(0.f, 0.f, 0.f, 0.f);
    if (gr < rows) v = ((const float4*)X)[(size_t)gr * 32 + cc];
    *(float4*)&xs[row][cc * 4] = v;
  }
  __syncthreads();
  const float4* W1v = (const float4*)W1;
  const float4* W2v = (const float4*)W2;
  const float4 b4 = ((const float4*)b1)[c4];
  float4 acc1[8], acc2[8];
#pragma unroll
  for (int i = 0; i < 8; i++) {
    acc1[i] = b4;
    acc2[i] = make_float4(0.f, 0.f, 0.f, 0.f);
  }
  const int rbase = rg * 8;
#pragma unroll 2
  for (int k = 0; k < 128; k++) {
    const float4 w1 = W1v[k * 32 + c4];
    const float4 w2 = W2v[k * 32 + c4];
#pragma unroll
    for (int i = 0; i < 8; i++) {
      const float xv = xs[rbase + i][k];
      acc1[i].x = fmaf(xv, w1.x, acc1[i].x);
      acc1[i].y = fmaf(xv, w1.y, acc1[i].y);
      acc1[i].z = fmaf(xv, w1.z, acc1[i].z);
      acc1[i].w = fmaf(xv, w1.w, acc1[i].w);
      acc2[i].x = fmaf(xv, w2.x, acc2[i].x);
      acc2[i].y = fmaf(xv, w2.y, acc2[i].y);
      acc2[i].z = fmaf(xv, w2.z, acc2[i].z);
      acc2[i].w = fmaf(xv, w2.w, acc2[i].w);
    }
  }
#pragma unroll
  for (int i = 0; i < 8; i++) {
    const int gr = r0 + rbase + i;
    if (gr < rows) {
      ((float4*)out1)[(size_t)gr * 32 + c4] = acc1[i];
      ((float4*)out2)[(size_t)gr * 32 + c4] = acc2[i];
    }
  }
}

// ---- stage 1: both GEMM pairs + count/rank + COO ecoord-sum, one launch ----
__global__ __launch_bounds__(256) void fused_stage1(
    const float* __restrict__ x, const float* __restrict__ Wv,
    const float* __restrict__ bv, float* __restrict__ xw,
    const float* __restrict__ Wx, float* __restrict__ xw2, int N, int nbGN,
    const float* __restrict__ hf, const float* __restrict__ We,
    const float* __restrict__ be, float* __restrict__ ew,
    const float* __restrict__ Weg, float* __restrict__ ew2, int M, int nbGM,
    const int* __restrict__ ni, const int* __restrict__ ei, int nnz,
    const int* __restrict__ xx, int eg, const int* __restrict__ ee, int eeN,
    int* cnt_n, int* cnt_e, int* cnt_gx, int* cnt_ge, int* rank_pn, int* rank_pe,
    int* rank_g, int* rank_h, const float* __restrict__ coord, float* ec) {
  __shared__ float xs[64][132];
  const int b = blockIdx.x;
  if (b < nbGN) {
    gemm_body(x, Wv, bv, xw, Wx, xw2, N, b, xs);
    return;
  }
  if (b < nbGN + nbGM) {
    gemm_body(hf, We, be, ew, Weg, ew2, M, b - nbGN, xs);
    return;
  }
  const int cb = b - nbGN - nbGM;
  int i = cb * 1024 + (int)threadIdx.x;
#pragma unroll
  for (int k = 0; k < 4; k++, i += 256) {
    if (i < nnz) {
      const int n = ni[i], e = ei[i];
      rank_pn[i] = atomicAdd(&cnt_n[n], 1);
      rank_pe[i] = atomicAdd(&cnt_e[e], 1);
      atomicAdd(&ec[e * 3 + 0], coord[n * 3 + 0]);
      atomicAdd(&ec[e * 3 + 1], coord[n * 3 + 1]);
      atomicAdd(&ec[e * 3 + 2], coord[n * 3 + 2]);
    } else if (i < nnz + eg) {
      const int j = i - nnz;
      rank_g[j] = atomicAdd(&cnt_gx[xx[eg + j]], 1);
    } else if (i < nnz + eg + eeN) {
      const int j = i - nnz - eg;
      rank_h[j] = atomicAdd(&cnt_ge[ee[eeN + j]], 1);
    }
  }
}

// ---- multi-block segmented exclusive scan over the 4 count arrays ----
__global__ __launch_bounds__(256) void scan_partial(
    const int* __restrict__ c0, int n0, const int* __restrict__ c1, int n1,
    const int* __restrict__ c2, int n2, const int* __restrict__ c3, int n3,
    int nb0, int nb1, int nb2, int nb3, int* __restrict__ bsums) {
  const int gb = blockIdx.x;
  const int* cnt;
  int lb, n;
  if (gb < nb0) { cnt = c0; lb = gb; n = n0; }
  else if (gb < nb0 + nb1) { cnt = c1; lb = gb - nb0; n = n1; }
  else if (gb < nb0 + nb1 + nb2) { cnt = c2; lb = gb - nb0 - nb1; n = n2; }
  else { cnt = c3; lb = gb - nb0 - nb1 - nb2; n = n3; }
  const int t = threadIdx.x;
  const int base = lb * 4096 + t * 16;
  int s = 0;
#pragma unroll
  for (int i = 0; i < 16; i++) {
    const int idx = base + i;
    if (idx < n) s += cnt[idx];
  }
  const int wsum = wave_sum_i(s);
  __shared__ int wsm[4];
  if ((t & 63) == 0) wsm[t >> 6] = wsum;
  __syncthreads();
  if (t == 0) bsums[gb] = wsm[0] + wsm[1] + wsm[2] + wsm[3];
}

__global__ void scan_bsums(const int* __restrict__ bsums, int nb0, int nb1, int nb2,
                           int nb3, int* __restrict__ bbase, int* __restrict__ totals) {
  if (threadIdx.x) return;
  int segs[4] = {nb0, nb1, nb2, nb3};
  int gb = 0;
  for (int a = 0; a < 4; a++) {
    int run = 0;
    for (int i = 0; i < segs[a]; i++) {
      bbase[gb] = run;
      run += bsums[gb];
      gb++;
    }
    totals[a] = run;
  }
}

// rowptr + optional rsqrt(1+deg) + optional ecoord divide (array 1)
__global__ __launch_bounds__(256) void scan_final(
    int* __restrict__ c0, int* rp0, float* rs0, float* ecd0, int n0,
    int* __restrict__ c1, int* rp1, float* rs1, float* ecd1, int n1,
    int* __restrict__ c2, int* rp2, float* rs2, float* ecd2, int n2,
    int* __restrict__ c3, int* rp3, float* rs3, float* ecd3, int n3,
    int nb0, int nb1, int nb2, int nb3, const int* __restrict__ bbase,
    const int* __restrict__ totals) {
  const int gb = blockIdx.x;
  int* cnt;
  int* rp;
  float* rs;
  float* ecd;
  int lb, n, a;
  if (gb < nb0) { cnt = c0; rp = rp0; rs = rs0; ecd = ecd0; lb = gb; n = n0; a = 0; }
  else if (gb < nb0 + nb1) { cnt = c1; rp = rp1; rs = rs1; ecd = ecd1; lb = gb - nb0; n = n1; a = 1; }
  else if (gb < nb0 + nb1 + nb2) { cnt = c2; rp = rp2; rs = rs2; ecd = ecd2; lb = gb - nb0 - nb1; n = n2; a = 2; }
  else { cnt = c3; rp = rp3; rs = rs3; ecd = ecd3; lb = gb - nb0 - nb1 - nb2; n = n3; a = 3; }
  const int t = threadIdx.x;
  const int base = lb * 4096 + t * 16;
  int vals[16];
  int s = 0;
#pragma unroll
  for (int i = 0; i < 16; i++) {
    const int idx = base + i;
    vals[i] = (idx < n) ? cnt[idx] : 0;
    s += vals[i];
  }
  __shared__ int tsum[256];
  tsum[t] = s;
  __syncthreads();
  for (int off = 1; off < 256; off <<= 1) {
    const int v = (t >= off) ? tsum[t - off] : 0;
    __syncthreads();
    tsum[t] += v;
    __syncthreads();
  }
  int run = bbase[gb] + (t ? tsum[t - 1] : 0);
#pragma unroll
  for (int i = 0; i < 16; i++) {
    const int idx = base + i;
    if (idx < n) {
      rp[idx] = run;
      if (rs) rs[idx] = rsqrtf(1.f + (float)vals[i]);
      if (ecd) {
        const float inv = 1.f / fmaxf((float)vals[i], 1.f);
        ecd[idx * 3 + 0] *= inv;
        ecd[idx * 3 + 1] *= inv;
        ecd[idx * 3 + 2] *= inv;
      }
      run += vals[i];
    }
  }
  if (t == 0 && lb == 0) rp[n] = totals[a];
}

// ---- fill (atomic-free, ranks precomputed) + batch_counts, one launch ----
__global__ __launch_bounds__(256) void fused_fill(
    const int* __restrict__ ni, const int* __restrict__ ei, int nnz,
    const int* __restrict__ xx, int eg, const int* __restrict__ ee, int eeN,
    const int* __restrict__ rp_n, const int* __restrict__ rp_e,
    const int* __restrict__ rp_gx, const int* __restrict__ rp_ge,
    const int* __restrict__ rank_pn, const int* __restrict__ rank_pe,
    const int* __restrict__ rank_g, const int* __restrict__ rank_h, int* adj_n,
    int* adj_e, int* adj_gx, int* adj_ge, int nbFill, const int* __restrict__ nbi,
    int n, int* cbn, const int* __restrict__ hbi, int m, int* cbe) {
  const int b = blockIdx.x;
  const int t = threadIdx.x;
  if (b < nbFill) {
    int i = b * 1024 + t;
#pragma unroll
    for (int k = 0; k < 4; k++, i += 256) {
      if (i < nnz) {
        const int n0 = ni[i], e0 = ei[i];
        adj_n[rp_n[n0] + rank_pn[i]] = e0;
        adj_e[rp_e[e0] + rank_pe[i]] = n0;
      } else if (i < nnz + eg) {
        const int j = i - nnz;
        adj_gx[rp_gx[xx[eg + j]] + rank_g[j]] = xx[j];
      } else if (i < nnz + eg + eeN) {
        const int j = i - nnz - eg;
        adj_ge[rp_ge[ee[eeN + j]] + rank_h[j]] = ee[j];
      }
    }
    return;
  }
  // batch counts via binary search on sorted batch index
  const bool B = (b - nbFill) != 0;
  const int* idx = B ? hbi : nbi;
  const int nn = B ? m : n;
  int* out = B ? cbe : cbn;
  const int g = t;
  if (g >= NB) return;
  int lo = 0, hi = nn;
  while (lo < hi) { int mid = (lo + hi) >> 1; if (idx[mid] < g) lo = mid + 1; else hi = mid; }
  const int l = lo;
  lo = 0; hi = nn;
  while (lo < hi) { int mid = (lo + hi) >> 1; if (idx[mid] < g + 1) lo = mid + 1; else hi = mid; }
  out[g] = lo - l;
}

// ---- GCN gather body ----
__device__ __forceinline__ void gcn_body(const float* __restrict__ xw,
                                         const int* __restrict__ rowptr,
                                         const int* __restrict__ adj,
                                         const float* __restrict__ rs,
                                         const float* __restrict__ bias,
                                         float* __restrict__ out, int n, int lb) {
  const int r = (lb * 256 + (int)threadIdx.x) >> 6;
  const int lane = threadIdx.x & 63;
  if (r >= n) return;
  const int lo = rowptr[r], hi = rowptr[r + 1];
  const float rd = rs[r];
  float2 acc = make_float2(0.f, 0.f);
  for (int base = lo; base < hi; base += 64) {
    const int mm = min(64, hi - base);
    int aj = 0;
    float rj = 0.f;
    if (base + lane < hi) {
      aj = adj[base + lane];
      rj = rs[aj];
    }
    for (int j = 0; j < mm; j++) {
      const int s = __shfl(aj, j);
      const float w = __shfl(rj, j);
      const float2 v = ((const float2*)xw)[(size_t)s * 64 + lane];
      acc.x = fmaf(w, v.x, acc.x);
      acc.y = fmaf(w, v.y, acc.y);
    }
  }
  const float2 self = ((const float2*)xw)[(size_t)r * 64 + lane];
  const float2 bb = ((const float2*)bias)[lane];
  float2 o;
  o.x = fmaf(rd, acc.x, fmaf(rd * rd, self.x, bb.x));
  o.y = fmaf(rd, acc.y, fmaf(rd * rd, self.y, bb.y));
  ((float2*)out)[(size_t)r * 64 + lane] = o;
}

// ---- all four gathers in one launch ----
__global__ __launch_bounds__(256) void fused_gathers(
    // node path
    const float* __restrict__ ew, const float* __restrict__ xw,
    const float* __restrict__ coord, const float* __restrict__ ecoord,
    const int* __restrict__ rp_n, const int* __restrict__ adj_n,
    float* __restrict__ z_conv, float* __restrict__ outc, int N, int nbNode,
    // gcn N
    const float* __restrict__ xw2, const int* __restrict__ rp_gx,
    const int* __restrict__ adj_gx, const float* __restrict__ rs_gx,
    const float* __restrict__ bx, float* __restrict__ outz, int nbGcnN,
    // gcn M
    const float* __restrict__ ew2, const int* __restrict__ rp_ge,
    const int* __restrict__ adj_ge, const float* __restrict__ rs_ge,
    const float* __restrict__ beg, float* __restrict__ oute, int M, int nbGcnM,
    // hedge (e_conv only)
    const int* __restrict__ rp_e, const int* __restrict__ adj_e,
    float* __restrict__ e_conv) {
  const int b = blockIdx.x;
  const int t = threadIdx.x;
  const int lane = t & 63;
  if (b < nbNode) {
    const int r = (b * 256 + t) >> 6;
    if (r >= N) return;
    const int lo = rp_n[r], hi = rp_n[r + 1];
    const float2 a = ((const float2*)xw)[(size_t)r * 64 + lane];
    const float myc = (lane < 3) ? coord[r * 3 + lane] : 0.f;
    float2 acc = make_float2(0.f, 0.f);
    float cacc = 0.f;
    for (int base = lo; base < hi; base += 64) {
      const int mm = min(64, hi - base);
      int aj = (base + lane < hi) ? adj_n[base + lane] : 0;
      for (int j = 0; j < mm; j++) {
        const int e = __shfl(aj, j);
        const float2 bb = ((const float2*)ew)[(size_t)e * 64 + lane];
        acc.x += bb.x;
        acc.y += bb.y;
        const float dot = wave_sum(fmaf(a.x, bb.x, a.y * bb.y));
        const float ph = tanhf(dot * 0.08838834764831845f);  // 1/sqrt(128)
        if (lane < 3) cacc = fmaf(myc - ecoord[e * 3 + lane], ph, cacc);
      }
    }
    const float inv = 1.f / fmaxf((float)(hi - lo), 1.f);
    ((float2*)z_conv)[(size_t)r * 64 + lane] = make_float2(acc.x * inv, acc.y * inv);
    if (lane < 3) outc[r * 3 + lane] = myc + cacc * inv;
    return;
  }
  if (b < nbNode + nbGcnN) {
    gcn_body(xw2, rp_gx, adj_gx, rs_gx, bx, outz, N, b - nbNode);
    return;
  }
  if (b < nbNode + nbGcnN + nbGcnM) {
    gcn_body(ew2, rp_ge, adj_ge, rs_ge, beg, oute, M, b - nbNode - nbGcnN);
    return;
  }
  // hedge path
  const int lb = b - nbNode - nbGcnN - nbGcnM;
  const int e = (lb * 256 + t) >> 6;
  if (e >= M) return;
  const int lo = rp_e[e], hi = rp_e[e + 1];
  float2 acc = make_float2(0.f, 0.f);
  for (int base = lo; base < hi; base += 64) {
    const int mm = min(64, hi - base);
    int aj = (base + lane < hi) ? adj_e[base + lane] : 0;
    for (int j = 0; j < mm; j++) {
      const int nidx = __shfl(aj, j);
      const float2 v = ((const float2*)xw)[(size_t)nidx * 64 + lane];
      acc.x += v.x;
      acc.y += v.y;
    }
  }
  const float inv = 1.f / fmaxf((float)(hi - lo), 1.f);
  ((float2*)e_conv)[(size_t)e * 64 + lane] = make_float2(acc.x * inv, acc.y * inv);
}

// ---------- barlow: split-K gram + fused colstats ----------
__global__ __launch_bounds__(256) void gram_partial2(
    const float* __restrict__ Z1a, const float* __restrict__ Z2a, int na,
    float* __restrict__ parta, const float* __restrict__ Z1b,
    const float* __restrict__ Z2b, int nbm, float* __restrict__ partb,
    float* __restrict__ st, int nblkA) {
  const bool A = (int)blockIdx.x < nblkA;
  const int pid = A ? blockIdx.x : blockIdx.x - nblkA;
  const float* Z1 = A ? Z1a : Z1b;
  const float* Z2 = A ? Z2a : Z2b;
  const int n = A ? na : nbm;
  const int gparts = A ? GPN : GPM;
  float* part = (A ? parta : partb) + (size_t)pid * 16384;
  float* sum1 = st + (A ? 0 : 512);
  float* ssq1 = sum1 + 128;
  float* sum2 = sum1 + 256;
  float* ssq2 = sum1 + 384;
  __shared__ float4 s1[256], s2[256];
  const int t = threadIdx.x;
  const int ti = t >> 4, tj = t & 15;
  const int rpb = (n + gparts - 1) / gparts;
  const int lo = pid * rpb, hi = min(lo + rpb, n);
  float acc[8][8];
#pragma unroll
  for (int i = 0; i < 8; i++)
#pragma unroll
    for (int j = 0; j < 8; j++) acc[i][j] = 0.f;
  float cs = 0.f, cq = 0.f;
  const float* s1f = (const float*)s1;
  const float* s2f = (const float*)s2;
  const int c = t & 127;
  const bool low = t < 128;
  for (int rb = lo; rb < hi; rb += 8) {
    const int nr = min(8, hi - rb);
    __syncthreads();
    if (t < nr * 32) {
      const int rr = rb + (t >> 5);
      s1[t] = ((const float4*)Z1)[(size_t)rr * 32 + (t & 31)];
      s2[t] = ((const float4*)Z2)[(size_t)rr * 32 + (t & 31)];
    }
    __syncthreads();
    for (int r = 0; r < nr; r++) {
      const float4 a0 = s1[r * 32 + ti * 2], a1 = s1[r * 32 + ti * 2 + 1];
      const float4 b0 = s2[r * 32 + tj * 2], b1 = s2[r * 32 + tj * 2 + 1];
      const float av[8] = {a0.x, a0.y, a0.z, a0.w, a1.x, a1.y, a1.z, a1.w};
      const float bv[8] = {b0.x, b0.y, b0.z, b0.w, b1.x, b1.y, b1.z, b1.w};
#pragma unroll
      for (int i = 0; i < 8; i++)
#pragma unroll
        for (int j = 0; j < 8; j++) acc[i][j] = fmaf(av[i], bv[j], acc[i][j]);
      const float v = low ? s1f[r * 128 + c] : s2f[r * 128 + c];
      cs += v;
      cq = fmaf(v, v, cq);
    }
  }
  float4* P = (float4*)part;
#pragma unroll
  for (int i = 0; i < 8; i++) {
    P[(ti * 8 + i) * 32 + tj * 2] = make_float4(acc[i][0], acc[i][1], acc[i][2], acc[i][3]);
    P[(ti * 8 + i) * 32 + tj * 2 + 1] = make_float4(acc[i][4], acc[i][5], acc[i][6], acc[i][7]);
  }
  if (low) {
    atomicAdd(&sum1[c], cs);
    atomicAdd(&ssq1[c], cq);
  } else {
    atomicAdd(&sum2[c], cs);
    atomicAdd(&ssq2[c], cq);
  }
}

// ---- gram hierarchical reduce + layernorm/gelu/residual, one launch ----
__global__ __launch_bounds__(256) void fused_reduce_ln(
    const float* __restrict__ parta, float* __restrict__ G1,
    const float* __restrict__ partb, float* __restrict__ G2,
    const float* __restrict__ convA, const float* __restrict__ residA,
    float* __restrict__ outA, int nA, int lnA, const float* __restrict__ convB,
    const float* __restrict__ residB, float* __restrict__ outB, int nBm,
    const float* __restrict__ g, const float* __restrict__ bvec) {
  const int b = blockIdx.x;
  const int t = threadIdx.x;
  const int NRED = (GPN / RGRP + GPM / RGRP) * 16;  // 640
  if (b < NRED) {
    const int nga = GPN / RGRP;
    const int slice = b & 15;
    const int grp = b >> 4;
    const bool A = grp < nga;
    const float* part = A ? parta : partb;
    float* G = A ? G1 : G2;
    const int g0 = (A ? grp : grp - nga) * RGRP;
    const int e = slice * 1024 + t * 4;
    float4 s = make_float4(0.f, 0.f, 0.f, 0.f);
#pragma unroll 4
    for (int p = 0; p < RGRP; p++) {
      const float4 v = *(const float4*)&part[(size_t)(g0 + p) * 16384 + e];
      s.x += v.x;
      s.y += v.y;
      s.z += v.z;
      s.w += v.w;
    }
    atomicAdd(&G[e], s.x);
    atomicAdd(&G[e + 1], s.y);
    atomicAdd(&G[e + 2], s.z);
    atomicAdd(&G[e + 3], s.w);
    return;
  }
  const int b2 = b - NRED;
  const bool A = b2 < lnA;
  const int lb = A ? b2 : b2 - lnA;
  const float* conv = A ? convA : convB;
  const float* resid = A ? residA : residB;
  float* out = A ? outA : outB;
  const int rows = A ? nA : nBm;
  const int w = (lb * 256 + t) >> 6;
  const int lane = t & 63;
  if (w >= rows) return;
  const float2 v = ((const float2*)conv)[(size_t)w * 64 + lane];
  const float m = wave_sum(v.x + v.y) * (1.f / 128.f);
  const float q = wave_sum(fmaf(v.x, v.x, v.y * v.y)) * (1.f / 128.f);
  const float rstd = rsqrtf(q - m * m + 1e-5f);
  const float2 gg = ((const float2*)g)[lane];
  const float2 bb = ((const float2*)bvec)[lane];
  const float2 rr = ((const float2*)resid)[(size_t)w * 64 + lane];
  float y0 = fmaf(gg.x, (v.x - m) * rstd, bb.x);
  float y1 = fmaf(gg.y, (v.y - m) * rstd, bb.y);
  y0 = 0.5f * y0 * (1.f + erff(y0 * 0.7071067811865476f));
  y1 = 0.5f * y1 * (1.f + erff(y1 * 0.7071067811865476f));
  float2 o;
  o.x = y0 + rr.x;
  o.y = y1 + rr.y;
  ((float2*)out)[(size_t)w * 64 + lane] = o;
}

// ---- barlow finalize + segment pooling, one launch ----
__global__ __launch_bounds__(256) void fused_fin_pool(
    const float* __restrict__ G1, const float* __restrict__ G2,
    const float* __restrict__ st, float nA, float nB, float* outbt,
    const float* __restrict__ ZA, const int* __restrict__ bidxA, int n, int spA,
    float* poolA, const float* __restrict__ ZB, const int* __restrict__ bidxB, int m,
    float* poolB) {
  __shared__ float s1s[128], m1s[128], s2s[128], m2s[128];
  __shared__ float red[256];
  const int b = blockIdx.x;
  const int t = threadIdx.x;
  if (b < 2) {
    const bool A = b == 0;
    const float* G = A ? G1 : G2;
    const float* sum1 = st + (A ? 0 : 512);
    const float* ssq1 = sum1 + 128;
    const float* sum2 = sum1 + 256;
    const float* ssq2 = sum1 + 384;
    const float nn = A ? nA : nB;
    if (t < 128) {
      const float inv_n = 1.f / nn;
      const float bnf = (nn - 1.f) * inv_n + 1e-5f;
      float mu = sum1[t] * inv_n;
      float vu = (ssq1[t] * inv_n - mu * mu) * nn / (nn - 1.f);
      s1s[t] = rsqrtf(vu * bnf);
      m1s[t] = mu;
      mu = sum2[t] * inv_n;
      vu = (ssq2[t] * inv_n - mu * mu) * nn / (nn - 1.f);
      s2s[t] = rsqrtf(vu * bnf);
      m2s[t] = mu;
    }
    __syncthreads();
    float on = 0.f, off = 0.f;
    for (int idx = t; idx < 16384; idx += 256) {
      const int i = idx >> 7, j = idx & 127;
      const float c = s1s[i] * s2s[j] * (G[idx] - nn * m1s[i] * m2s[j]) * (1.f / 32.f);
      if (i == j) {
        const float dd = c - 1.f;
        on += dd * dd;
      } else {
        off += c * c;
      }
    }
    red[t] = on + 0.005f * off;
    __syncthreads();
    for (int s = 128; s; s >>= 1) {
      if (t < s) red[t] += red[t + s];
      __syncthreads();
    }
    if (t == 0) atomicAdd(outbt, red[0]);
    return;
  }
  // pool path: 128 rows per block, 256 threads = 2 row-halves x 128 cols
  const int pb = b - 2;
  const bool A = pb < spA;
  const int lb = A ? pb : pb - spA;
  const float* Z = A ? ZA : ZB;
  const int* bidx = A ? bidxA : bidxB;
  const int n2 = A ? n : m;
  float* pool = A ? poolA : poolB;
  const int c = t & 127;
  const int h = t >> 7;
  const int r0 = lb * 128 + h * 64;
  const int re = min(lb * 128 + (h + 1) * 64, n2);
  if (r0 >= n2) return;
  float acc = 0.f;
  int cur = bidx[r0];
  for (int r = r0; r < re; r++) {
    const int bb = bidx[r];
    if (bb != cur) {
      atomicAdd(&pool[cur * 128 + c], acc);
      acc = 0.f;
      cur = bb;
    }
    acc += Z[(size_t)r * 128 + c];
  }
  atomicAdd(&pool[cur * 128 + c], acc);
}

__global__ __launch_bounds__(128) void graph_gemm(
    const float* __restrict__ zg, const float* __restrict__ eg,
    const int* __restrict__ cnz, const int* __restrict__ cne,
    const float* __restrict__ Wf, const float* __restrict__ bf, float* out) {
  __shared__ float cat[256];
  const int g = blockIdx.x, t = threadIdx.x;
  cat[t] = zg[g * 128 + t] / fmaxf((float)cnz[g], 1.f);
  cat[128 + t] = eg[g * 128 + t] / fmaxf((float)cne[g], 1.f);
  __syncthreads();
  float acc = bf[t];
#pragma unroll 8
  for (int k = 0; k < 256; k++) acc = fmaf(cat[k], Wf[k * 128 + t], acc);
  out[g * 128 + t] = acc;
}

extern "C" void kernel_launch(void* const* d_in, const int* in_sizes, int n_in,
                              void* d_out, int out_size, void* d_ws, size_t ws_size,
                              hipStream_t stream) {
  const float* x = (const float*)d_in[0];
  const float* hf = (const float*)d_in[1];
  const float* coord = (const float*)d_in[2];
  const int* ni = (const int*)d_in[3];
  const int* ei = (const int*)d_in[4];
  const int* nb = (const int*)d_in[5];
  const int* hb = (const int*)d_in[6];
  const int* xx = (const int*)d_in[7];
  const int* ee = (const int*)d_in[8];
  const float* Wv = (const float*)d_in[10];
  const float* bv = (const float*)d_in[11];
  const float* We = (const float*)d_in[12];
  const float* be = (const float*)d_in[13];
  const float* Wx = (const float*)d_in[14];
  const float* bx = (const float*)d_in[15];
  const float* Weg = (const float*)d_in[16];
  const float* beg = (const float*)d_in[17];
  const float* lng = (const float*)d_in[18];
  const float* lnb = (const float*)d_in[19];
  const float* Wf = (const float*)d_in[20];
  const float* bf = (const float*)d_in[21];

  const int N = in_sizes[0] / 128;
  const int M = in_sizes[1] / 128;
  const int NNZ = in_sizes[3];
  const int EG = in_sizes[7] / 2;
  const int EE = in_sizes[8] / 2;

  float* ws = (float*)d_ws;
  size_t o = 0;
  float* xw = ws + o;     o += (size_t)N * 128;  // dead by gram time -> gpart alias
  float* ew = ws + o;     o += (size_t)M * 128;
  float* xw2 = ws + o;    o += (size_t)N * 128;
  float* ew2 = ws + o;    o += (size_t)M * 128;
  float* z_conv = ws + o; o += (size_t)N * 128;
  float* e_conv = ws + o; o += (size_t)M * 128;
  float* rs_gx = ws + o;  o += N;
  float* rs_ge = ws + o;  o += M;
  const size_t fz0 = o;  // zeroed float block
  float* ecoord = ws + o; o += (size_t)M * 3;  // accumulated by atomics in stage1
  float* G1 = ws + o;     o += 16384;          // accumulated by fused_reduce_ln
  float* G2 = ws + o;     o += 16384;
  float* st = ws + o;     o += 1024;
  float* zg = ws + o;     o += NB * 128;
  float* eg_p = ws + o;   o += NB * 128;
  const size_t fz1 = o;
  int* wsi = (int*)(ws + o);
  size_t oi = 0;
  int* cnt_n = wsi + oi;  oi += N;  // zeroed: counts after stage1
  int* cnt_e = wsi + oi;  oi += M;
  int* cnt_gx = wsi + oi; oi += N;
  int* cnt_ge = wsi + oi; oi += M;
  const size_t iz1 = oi;
  int* rp_n = wsi + oi;   oi += N + 1;
  int* rp_e = wsi + oi;   oi += M + 1;
  int* rp_gx = wsi + oi;  oi += N + 1;
  int* rp_ge = wsi + oi;  oi += M + 1;
  int* adj_n = wsi + oi;  oi += NNZ;
  int* adj_e = wsi + oi;  oi += NNZ;
  int* adj_gx = wsi + oi; oi += EG;
  int* adj_ge = wsi + oi; oi += EE;
  int* rank_pn = wsi + oi; oi += NNZ;
  int* rank_pe = wsi + oi; oi += NNZ;
  int* rank_g = wsi + oi;  oi += EG;
  int* rank_h = wsi + oi;  oi += EE;
  int* cbn = wsi + oi;    oi += NB;
  int* cbe = wsi + oi;    oi += NB;
  int* bsums = wsi + oi;  oi += 64;
  int* bbase = wsi + oi;  oi += 64;
  int* totals = wsi + oi; oi += 4;

  float* gpartA = xw;                        // GPN*16384 floats
  float* gpartB = xw + (size_t)GPN * 16384;  // GPM*16384 floats (dead xw/ew/xw2)

  float* outz = (float*)d_out;           // temporarily z_imp
  float* oute = outz + (size_t)N * 128;  // temporarily e_imp
  float* outc = oute + (size_t)M * 128;
  float* outg = outc + (size_t)N * 3;
  float* outbt = outg + NB * 128;

  hipMemsetAsync(ws + fz0, 0, (fz1 - fz0) * 4, stream);
  hipMemsetAsync(wsi, 0, iz1 * 4, stream);
  hipMemsetAsync(outbt, 0, 4, stream);

  // stage 1: GEMMs || count/rank || ecoord COO sum
  const int nbGN = (N + 63) / 64, nbGM = (M + 63) / 64;
  const int tot = NNZ + EG + EE;
  const int nbCnt = (tot + 1023) >> 10;
  fused_stage1<<<nbGN + nbGM + nbCnt, 256, 0, stream>>>(
      x, Wv, bv, xw, Wx, xw2, N, nbGN, hf, We, be, ew, Weg, ew2, M, nbGM, ni, ei, NNZ,
      xx, EG, ee, EE, cnt_n, cnt_e, cnt_gx, cnt_ge, rank_pn, rank_pe, rank_g, rank_h,
      coord, ecoord);

  // scans (+ ecoord divide folded into array-1 pass)
  const int nb0 = (N + 4095) >> 12, nb1 = (M + 4095) >> 12;
  const int sgrid = 2 * nb0 + 2 * nb1;
  scan_partial<<<sgrid, 256, 0, stream>>>(cnt_n, N, cnt_e, M, cnt_gx, N, cnt_ge, M,
                                          nb0, nb1, nb0, nb1, bsums);
  scan_bsums<<<1, 64, 0, stream>>>(bsums, nb0, nb1, nb0, nb1, bbase, totals);
  scan_final<<<sgrid, 256, 0, stream>>>(
      cnt_n, rp_n, nullptr, nullptr, N, cnt_e, rp_e, nullptr, ecoord, M, cnt_gx,
      rp_gx, rs_gx, nullptr, N, cnt_ge, rp_ge, rs_ge, nullptr, M, nb0, nb1, nb0, nb1,
      bbase, totals);

  // fill (atomic-free) || batch counts
  const int nbFill = (tot + 1023) >> 10;
  fused_fill<<<nbFill + 2, 256, 0, stream>>>(
      ni, ei, NNZ, xx, EG, ee, EE, rp_n, rp_e, rp_gx, rp_ge, rank_pn, rank_pe, rank_g,
      rank_h, adj_n, adj_e, adj_gx, adj_ge, nbFill, nb, N, cbn, hb, M, cbe);

  // all gathers in one launch
  const int nbNode = (N + 3) / 4, nbGcnN = (N + 3) / 4, nbGcnM = (M + 3) / 4,
            nbHedge = (M + 3) / 4;
  fused_gathers<<<nbNode + nbGcnN + nbGcnM + nbHedge, 256, 0, stream>>>(
      ew, xw, coord, ecoord, rp_n, adj_n, z_conv, outc, N, nbNode, xw2, rp_gx, adj_gx,
      rs_gx, bx, outz, nbGcnN, ew2, rp_ge, adj_ge, rs_ge, beg, oute, M, nbGcnM, rp_e,
      adj_e, e_conv);

  // barlow gram partials (xw..ew2 dead now)
  gram_partial2<<<GPN + GPM, 256, 0, stream>>>(outz, z_conv, N, gpartA, oute, e_conv,
                                               M, gpartB, st, GPN);

  // gram reduce || layernorm+gelu+residual (ln overwrites outz/oute AFTER partials read them)
  const int lnA = (N + 3) / 4;
  fused_reduce_ln<<<(GPN / RGRP + GPM / RGRP) * 16 + lnA + (M + 3) / 4, 256, 0,
                    stream>>>(gpartA, G1, gpartB, G2, z_conv, x, outz, N, lnA, e_conv,
                              hf, oute, M, lng, lnb);

  // barlow finalize || segment pooling
  const int spA = (N + 127) / 128, spB = (M + 127) / 128;
  fused_fin_pool<<<2 + spA + spB, 256, 0, stream>>>(G1, G2, st, (float)N, (float)M,
                                                    outbt, outz, nb, N, spA, zg, oute,
                                                    hb, M, eg_p);

  graph_gemm<<<NB, 128, 0, stream>>>(zg, eg_p, cbn, cbe, Wf, bf, outg);
}

// Round 8
// 372.750 us; speedup vs baseline: 7.3608x; 1.0221x over previous
//
#include <hip/hip_runtime.h>
#include <hip/hip_bf16.h>

#define NB 32       // num_graphs
#define GPN 512     // split-K parts for gram (N side)
#define GPM 128     // split-K parts for gram (M side)
#define RGRP 16     // partials reduced per block in gram reduce

__device__ __forceinline__ float wave_sum(float v) {
#pragma unroll
  for (int off = 32; off; off >>= 1) v += __shfl_xor(v, off);
  return v;
}
__device__ __forceinline__ int wave_sum_i(int v) {
#pragma unroll
  for (int off = 32; off; off >>= 1) v += __shfl_xor(v, off);
  return v;
}

__device__ __forceinline__ float bf2f(unsigned short u) {
  return __uint_as_float(((unsigned int)u) << 16);
}
__device__ __forceinline__ unsigned short f2bf(float f) {  // RNE
  unsigned int v = __float_as_uint(f);
  return (unsigned short)((v + 0x7FFFu + ((v >> 16) & 1u)) >> 16);
}

// ---- dual GEMM body: out1 = X@W1 + b1 (f32), out2 = X@W2 (bf16) ----
__device__ __forceinline__ void gemm_body(const float* __restrict__ X,
                                          const float* __restrict__ W1,
                                          const float* __restrict__ b1,
                                          float* __restrict__ out1,
                                          const float* __restrict__ W2,
                                          unsigned short* __restrict__ out2, int rows,
                                          int blk, float (*xs)[132]) {
  const int t = threadIdx.x;
  const int c4 = t & 31;
  const int rg = t >> 5;
  const int r0 = blk * 64;
#pragma unroll
  for (int i = 0; i < 8; i++) {
    const int idx = t + i * 256;
    const int row = idx >> 5, cc = idx & 31;
    const int gr = r0 + row;
    float4 v = make_float4(0.f, 0.f, 0.f, 0.f);
    if (gr < rows) v = ((const float4*)X)[(size_t)gr * 32 + cc];
    *(float4*)&xs[row][cc * 4] = v;
  }
  __syncthreads();
  const float4* W1v = (const float4*)W1;
  const float4* W2v = (const float4*)W2;
  const float4 b4 = ((const float4*)b1)[c4];
  float4 acc1[8], acc2[8];
#pragma unroll
  for (int i = 0; i < 8; i++) {
    acc1[i] = b4;
    acc2[i] = make_float4(0.f, 0.f, 0.f, 0.f);
  }
  const int rbase = rg * 8;
#pragma unroll 2
  for (int k = 0; k < 128; k++) {
    const float4 w1 = W1v[k * 32 + c4];
    const float4 w2 = W2v[k * 32 + c4];
#pragma unroll
    for (int i = 0; i < 8; i++) {
      const float xv = xs[rbase + i][k];
      acc1[i].x = fmaf(xv, w1.x, acc1[i].x);
      acc1[i].y = fmaf(xv, w1.y, acc1[i].y);
      acc1[i].z = fmaf(xv, w1.z, acc1[i].z);
      acc1[i].w = fmaf(xv, w1.w, acc1[i].w);
      acc2[i].x = fmaf(xv, w2.x, acc2[i].x);
      acc2[i].y = fmaf(xv, w2.y, acc2[i].y);
      acc2[i].z = fmaf(xv, w2.z, acc2[i].z);
      acc2[i].w = fmaf(xv, w2.w, acc2[i].w);
    }
  }
#pragma unroll
  for (int i = 0; i < 8; i++) {
    const int gr = r0 + rbase + i;
    if (gr < rows) {
      ((float4*)out1)[(size_t)gr * 32 + c4] = acc1[i];
      ushort4 o;
      o.x = f2bf(acc2[i].x);
      o.y = f2bf(acc2[i].y);
      o.z = f2bf(acc2[i].z);
      o.w = f2bf(acc2[i].w);
      ((ushort4*)out2)[(size_t)gr * 32 + c4] = o;
    }
  }
}

// ---- stage 1: both GEMM pairs + count/rank + COO ecoord-sum, one launch ----
__global__ __launch_bounds__(256) void fused_stage1(
    const float* __restrict__ x, const float* __restrict__ Wv,
    const float* __restrict__ bv, float* __restrict__ xw,
    const float* __restrict__ Wx, unsigned short* __restrict__ xw2, int N, int nbGN,
    const float* __restrict__ hf, const float* __restrict__ We,
    const float* __restrict__ be, float* __restrict__ ew,
    const float* __restrict__ Weg, unsigned short* __restrict__ ew2, int M, int nbGM,
    const int* __restrict__ ni, const int* __restrict__ ei, int nnz,
    const int* __restrict__ xx, int eg, const int* __restrict__ ee, int eeN,
    int* cnt_n, int* cnt_e, int* cnt_gx, int* cnt_ge, int* rank_pn, int* rank_pe,
    int* rank_g, int* rank_h, const float* __restrict__ coord, float* ec) {
  __shared__ float xs[64][132];
  const int b = blockIdx.x;
  if (b < nbGN) {
    gemm_body(x, Wv, bv, xw, Wx, xw2, N, b, xs);
    return;
  }
  if (b < nbGN + nbGM) {
    gemm_body(hf, We, be, ew, Weg, ew2, M, b - nbGN, xs);
    return;
  }
  const int cb = b - nbGN - nbGM;
  int i = cb * 1024 + (int)threadIdx.x;
#pragma unroll
  for (int k = 0; k < 4; k++, i += 256) {
    if (i < nnz) {
      const int n = ni[i], e = ei[i];
      rank_pn[i] = atomicAdd(&cnt_n[n], 1);
      rank_pe[i] = atomicAdd(&cnt_e[e], 1);
      atomicAdd(&ec[e * 3 + 0], coord[n * 3 + 0]);
      atomicAdd(&ec[e * 3 + 1], coord[n * 3 + 1]);
      atomicAdd(&ec[e * 3 + 2], coord[n * 3 + 2]);
    } else if (i < nnz + eg) {
      const int j = i - nnz;
      rank_g[j] = atomicAdd(&cnt_gx[xx[eg + j]], 1);
    } else if (i < nnz + eg + eeN) {
      const int j = i - nnz - eg;
      rank_h[j] = atomicAdd(&cnt_ge[ee[eeN + j]], 1);
    }
  }
}

// ---- multi-block segmented exclusive scan over the 4 count arrays ----
__global__ __launch_bounds__(256) void scan_partial(
    const int* __restrict__ c0, int n0, const int* __restrict__ c1, int n1,
    const int* __restrict__ c2, int n2, const int* __restrict__ c3, int n3,
    int nb0, int nb1, int nb2, int nb3, int* __restrict__ bsums) {
  const int gb = blockIdx.x;
  const int* cnt;
  int lb, n;
  if (gb < nb0) { cnt = c0; lb = gb; n = n0; }
  else if (gb < nb0 + nb1) { cnt = c1; lb = gb - nb0; n = n1; }
  else if (gb < nb0 + nb1 + nb2) { cnt = c2; lb = gb - nb0 - nb1; n = n2; }
  else { cnt = c3; lb = gb - nb0 - nb1 - nb2; n = n3; }
  const int t = threadIdx.x;
  const int base = lb * 4096 + t * 16;
  int s = 0;
#pragma unroll
  for (int i = 0; i < 16; i++) {
    const int idx = base + i;
    if (idx < n) s += cnt[idx];
  }
  const int wsum = wave_sum_i(s);
  __shared__ int wsm[4];
  if ((t & 63) == 0) wsm[t >> 6] = wsum;
  __syncthreads();
  if (t == 0) bsums[gb] = wsm[0] + wsm[1] + wsm[2] + wsm[3];
}

__global__ void scan_bsums(const int* __restrict__ bsums, int nb0, int nb1, int nb2,
                           int nb3, int* __restrict__ bbase, int* __restrict__ totals) {
  if (threadIdx.x) return;
  int segs[4] = {nb0, nb1, nb2, nb3};
  int gb = 0;
  for (int a = 0; a < 4; a++) {
    int run = 0;
    for (int i = 0; i < segs[a]; i++) {
      bbase[gb] = run;
      run += bsums[gb];
      gb++;
    }
    totals[a] = run;
  }
}

// rowptr + optional rsqrt(1+deg) + optional ecoord divide (array 1)
__global__ __launch_bounds__(256) void scan_final(
    int* __restrict__ c0, int* rp0, float* rs0, float* ecd0, int n0,
    int* __restrict__ c1, int* rp1, float* rs1, float* ecd1, int n1,
    int* __restrict__ c2, int* rp2, float* rs2, float* ecd2, int n2,
    int* __restrict__ c3, int* rp3, float* rs3, float* ecd3, int n3,
    int nb0, int nb1, int nb2, int nb3, const int* __restrict__ bbase,
    const int* __restrict__ totals) {
  const int gb = blockIdx.x;
  int* cnt;
  int* rp;
  float* rs;
  float* ecd;
  int lb, n, a;
  if (gb < nb0) { cnt = c0; rp = rp0; rs = rs0; ecd = ecd0; lb = gb; n = n0; a = 0; }
  else if (gb < nb0 + nb1) { cnt = c1; rp = rp1; rs = rs1; ecd = ecd1; lb = gb - nb0; n = n1; a = 1; }
  else if (gb < nb0 + nb1 + nb2) { cnt = c2; rp = rp2; rs = rs2; ecd = ecd2; lb = gb - nb0 - nb1; n = n2; a = 2; }
  else { cnt = c3; rp = rp3; rs = rs3; ecd = ecd3; lb = gb - nb0 - nb1 - nb2; n = n3; a = 3; }
  const int t = threadIdx.x;
  const int base = lb * 4096 + t * 16;
  int vals[16];
  int s = 0;
#pragma unroll
  for (int i = 0; i < 16; i++) {
    const int idx = base + i;
    vals[i] = (idx < n) ? cnt[idx] : 0;
    s += vals[i];
  }
  __shared__ int tsum[256];
  tsum[t] = s;
  __syncthreads();
  for (int off = 1; off < 256; off <<= 1) {
    const int v = (t >= off) ? tsum[t - off] : 0;
    __syncthreads();
    tsum[t] += v;
    __syncthreads();
  }
  int run = bbase[gb] + (t ? tsum[t - 1] : 0);
#pragma unroll
  for (int i = 0; i < 16; i++) {
    const int idx = base + i;
    if (idx < n) {
      rp[idx] = run;
      if (rs) rs[idx] = rsqrtf(1.f + (float)vals[i]);
      if (ecd) {
        const float inv = 1.f / fmaxf((float)vals[i], 1.f);
        ecd[idx * 3 + 0] *= inv;
        ecd[idx * 3 + 1] *= inv;
        ecd[idx * 3 + 2] *= inv;
      }
      run += vals[i];
    }
  }
  if (t == 0 && lb == 0) rp[n] = totals[a];
}

// ---- fill (atomic-free, ranks precomputed) + batch_counts, one launch ----
__global__ __launch_bounds__(256) void fused_fill(
    const int* __restrict__ ni, const int* __restrict__ ei, int nnz,
    const int* __restrict__ xx, int eg, const int* __restrict__ ee, int eeN,
    const int* __restrict__ rp_n, const int* __restrict__ rp_e,
    const int* __restrict__ rp_gx, const int* __restrict__ rp_ge,
    const int* __restrict__ rank_pn, const int* __restrict__ rank_pe,
    const int* __restrict__ rank_g, const int* __restrict__ rank_h, int* adj_n,
    int* adj_e, int* adj_gx, int* adj_ge, int nbFill, const int* __restrict__ nbi,
    int n, int* cbn, const int* __restrict__ hbi, int m, int* cbe) {
  const int b = blockIdx.x;
  const int t = threadIdx.x;
  if (b < nbFill) {
    int i = b * 1024 + t;
#pragma unroll
    for (int k = 0; k < 4; k++, i += 256) {
      if (i < nnz) {
        const int n0 = ni[i], e0 = ei[i];
        adj_n[rp_n[n0] + rank_pn[i]] = e0;
        adj_e[rp_e[e0] + rank_pe[i]] = n0;
      } else if (i < nnz + eg) {
        const int j = i - nnz;
        adj_gx[rp_gx[xx[eg + j]] + rank_g[j]] = xx[j];
      } else if (i < nnz + eg + eeN) {
        const int j = i - nnz - eg;
        adj_ge[rp_ge[ee[eeN + j]] + rank_h[j]] = ee[j];
      }
    }
    return;
  }
  const bool B = (b - nbFill) != 0;
  const int* idx = B ? hbi : nbi;
  const int nn = B ? m : n;
  int* out = B ? cbe : cbn;
  const int g = t;
  if (g >= NB) return;
  int lo = 0, hi = nn;
  while (lo < hi) { int mid = (lo + hi) >> 1; if (idx[mid] < g) lo = mid + 1; else hi = mid; }
  const int l = lo;
  lo = 0; hi = nn;
  while (lo < hi) { int mid = (lo + hi) >> 1; if (idx[mid] < g + 1) lo = mid + 1; else hi = mid; }
  out[g] = lo - l;
}

// ---- GCN gather body (bf16 rows, f32 accumulate) ----
__device__ __forceinline__ void gcn_body(const unsigned short* __restrict__ xw,
                                         const int* __restrict__ rowptr,
                                         const int* __restrict__ adj,
                                         const float* __restrict__ rs,
                                         const float* __restrict__ bias,
                                         float* __restrict__ out, int n, int lb) {
  const int r = (lb * 256 + (int)threadIdx.x) >> 6;
  const int lane = threadIdx.x & 63;
  if (r >= n) return;
  const int lo = rowptr[r], hi = rowptr[r + 1];
  const float rd = rs[r];
  float2 acc = make_float2(0.f, 0.f);
  for (int base = lo; base < hi; base += 64) {
    const int mm = min(64, hi - base);
    int aj = 0;
    float rj = 0.f;
    if (base + lane < hi) {
      aj = adj[base + lane];
      rj = rs[aj];
    }
    for (int j = 0; j < mm; j++) {
      const int s = __shfl(aj, j);
      const float w = __shfl(rj, j);
      const ushort2 u = ((const ushort2*)xw)[(size_t)s * 64 + lane];
      acc.x = fmaf(w, bf2f(u.x), acc.x);
      acc.y = fmaf(w, bf2f(u.y), acc.y);
    }
  }
  const ushort2 su = ((const ushort2*)xw)[(size_t)r * 64 + lane];
  const float2 bb = ((const float2*)bias)[lane];
  float2 o;
  o.x = fmaf(rd, acc.x, fmaf(rd * rd, bf2f(su.x), bb.x));
  o.y = fmaf(rd, acc.y, fmaf(rd * rd, bf2f(su.y), bb.y));
  ((float2*)out)[(size_t)r * 64 + lane] = o;
}

// ---- all four gathers in one launch ----
__global__ __launch_bounds__(256) void fused_gathers(
    // node path (f32)
    const float* __restrict__ ew, const float* __restrict__ xw,
    const float* __restrict__ coord, const float* __restrict__ ecoord,
    const int* __restrict__ rp_n, const int* __restrict__ adj_n,
    float* __restrict__ z_conv, float* __restrict__ outc, int N, int nbNode,
    // gcn N (bf16)
    const unsigned short* __restrict__ xw2, const int* __restrict__ rp_gx,
    const int* __restrict__ adj_gx, const float* __restrict__ rs_gx,
    const float* __restrict__ bx, float* __restrict__ outz, int nbGcnN,
    // gcn M (bf16)
    const unsigned short* __restrict__ ew2, const int* __restrict__ rp_ge,
    const int* __restrict__ adj_ge, const float* __restrict__ rs_ge,
    const float* __restrict__ beg, float* __restrict__ oute, int M, int nbGcnM,
    // hedge (e_conv only, f32)
    const int* __restrict__ rp_e, const int* __restrict__ adj_e,
    float* __restrict__ e_conv) {
  const int b = blockIdx.x;
  const int t = threadIdx.x;
  const int lane = t & 63;
  if (b < nbNode) {
    const int r = (b * 256 + t) >> 6;
    if (r >= N) return;
    const int lo = rp_n[r], hi = rp_n[r + 1];
    const float2 a = ((const float2*)xw)[(size_t)r * 64 + lane];
    const float myc = (lane < 3) ? coord[r * 3 + lane] : 0.f;
    float2 acc = make_float2(0.f, 0.f);
    float cacc = 0.f;
    for (int base = lo; base < hi; base += 64) {
      const int mm = min(64, hi - base);
      int aj = (base + lane < hi) ? adj_n[base + lane] : 0;
      for (int j = 0; j < mm; j++) {
        const int e = __shfl(aj, j);
        const float2 bb = ((const float2*)ew)[(size_t)e * 64 + lane];
        acc.x += bb.x;
        acc.y += bb.y;
        const float dot = wave_sum(fmaf(a.x, bb.x, a.y * bb.y));
        const float ph = tanhf(dot * 0.08838834764831845f);  // 1/sqrt(128)
        if (lane < 3) cacc = fmaf(myc - ecoord[e * 3 + lane], ph, cacc);
      }
    }
    const float inv = 1.f / fmaxf((float)(hi - lo), 1.f);
    ((float2*)z_conv)[(size_t)r * 64 + lane] = make_float2(acc.x * inv, acc.y * inv);
    if (lane < 3) outc[r * 3 + lane] = myc + cacc * inv;
    return;
  }
  if (b < nbNode + nbGcnN) {
    gcn_body(xw2, rp_gx, adj_gx, rs_gx, bx, outz, N, b - nbNode);
    return;
  }
  if (b < nbNode + nbGcnN + nbGcnM) {
    gcn_body(ew2, rp_ge, adj_ge, rs_ge, beg, oute, M, b - nbNode - nbGcnN);
    return;
  }
  // hedge path
  const int lb = b - nbNode - nbGcnN - nbGcnM;
  const int e = (lb * 256 + t) >> 6;
  if (e >= M) return;
  const int lo = rp_e[e], hi = rp_e[e + 1];
  float2 acc = make_float2(0.f, 0.f);
  for (int base = lo; base < hi; base += 64) {
    const int mm = min(64, hi - base);
    int aj = (base + lane < hi) ? adj_e[base + lane] : 0;
    for (int j = 0; j < mm; j++) {
      const int nidx = __shfl(aj, j);
      const float2 v = ((const float2*)xw)[(size_t)nidx * 64 + lane];
      acc.x += v.x;
      acc.y += v.y;
    }
  }
  const float inv = 1.f / fmaxf((float)(hi - lo), 1.f);
  ((float2*)e_conv)[(size_t)e * 64 + lane] = make_float2(acc.x * inv, acc.y * inv);
}

// ---------- barlow: split-K gram + fused colstats ----------
__global__ __launch_bounds__(256) void gram_partial2(
    const float* __restrict__ Z1a, const float* __restrict__ Z2a, int na,
    float* __restrict__ parta, const float* __restrict__ Z1b,
    const float* __restrict__ Z2b, int nbm, float* __restrict__ partb,
    float* __restrict__ st, int nblkA) {
  const bool A = (int)blockIdx.x < nblkA;
  const int pid = A ? blockIdx.x : blockIdx.x - nblkA;
  const float* Z1 = A ? Z1a : Z1b;
  const float* Z2 = A ? Z2a : Z2b;
  const int n = A ? na : nbm;
  const int gparts = A ? GPN : GPM;
  float* part = (A ? parta : partb) + (size_t)pid * 16384;
  float* sum1 = st + (A ? 0 : 512);
  float* ssq1 = sum1 + 128;
  float* sum2 = sum1 + 256;
  float* ssq2 = sum1 + 384;
  __shared__ float4 s1[256], s2[256];
  const int t = threadIdx.x;
  const int ti = t >> 4, tj = t & 15;
  const int rpb = (n + gparts - 1) / gparts;
  const int lo = pid * rpb, hi = min(lo + rpb, n);
  float acc[8][8];
#pragma unroll
  for (int i = 0; i < 8; i++)
#pragma unroll
    for (int j = 0; j < 8; j++) acc[i][j] = 0.f;
  float cs = 0.f, cq = 0.f;
  const float* s1f = (const float*)s1;
  const float* s2f = (const float*)s2;
  const int c = t & 127;
  const bool low = t < 128;
  for (int rb = lo; rb < hi; rb += 8) {
    const int nr = min(8, hi - rb);
    __syncthreads();
    if (t < nr * 32) {
      const int rr = rb + (t >> 5);
      s1[t] = ((const float4*)Z1)[(size_t)rr * 32 + (t & 31)];
      s2[t] = ((const float4*)Z2)[(size_t)rr * 32 + (t & 31)];
    }
    __syncthreads();
    for (int r = 0; r < nr; r++) {
      const float4 a0 = s1[r * 32 + ti * 2], a1 = s1[r * 32 + ti * 2 + 1];
      const float4 b0 = s2[r * 32 + tj * 2], b1 = s2[r * 32 + tj * 2 + 1];
      const float av[8] = {a0.x, a0.y, a0.z, a0.w, a1.x, a1.y, a1.z, a1.w};
      const float bv[8] = {b0.x, b0.y, b0.z, b0.w, b1.x, b1.y, b1.z, b1.w};
#pragma unroll
      for (int i = 0; i < 8; i++)
#pragma unroll
        for (int j = 0; j < 8; j++) acc[i][j] = fmaf(av[i], bv[j], acc[i][j]);
      const float v = low ? s1f[r * 128 + c] : s2f[r * 128 + c];
      cs += v;
      cq = fmaf(v, v, cq);
    }
  }
  float4* P = (float4*)part;
#pragma unroll
  for (int i = 0; i < 8; i++) {
    P[(ti * 8 + i) * 32 + tj * 2] = make_float4(acc[i][0], acc[i][1], acc[i][2], acc[i][3]);
    P[(ti * 8 + i) * 32 + tj * 2 + 1] = make_float4(acc[i][4], acc[i][5], acc[i][6], acc[i][7]);
  }
  if (low) {
    atomicAdd(&sum1[c], cs);
    atomicAdd(&ssq1[c], cq);
  } else {
    atomicAdd(&sum2[c], cs);
    atomicAdd(&ssq2[c], cq);
  }
}

// ---- gram hierarchical reduce + layernorm/gelu/residual, one launch ----
__global__ __launch_bounds__(256) void fused_reduce_ln(
    const float* __restrict__ parta, float* __restrict__ G1,
    const float* __restrict__ partb, float* __restrict__ G2,
    const float* __restrict__ convA, const float* __restrict__ residA,
    float* __restrict__ outA, int nA, int lnA, const float* __restrict__ convB,
    const float* __restrict__ residB, float* __restrict__ outB, int nBm,
    const float* __restrict__ g, const float* __restrict__ bvec) {
  const int b = blockIdx.x;
  const int t = threadIdx.x;
  const int NRED = (GPN / RGRP + GPM / RGRP) * 16;  // 640
  if (b < NRED) {
    const int nga = GPN / RGRP;
    const int slice = b & 15;
    const int grp = b >> 4;
    const bool A = grp < nga;
    const float* part = A ? parta : partb;
    float* G = A ? G1 : G2;
    const int g0 = (A ? grp : grp - nga) * RGRP;
    const int e = slice * 1024 + t * 4;
    float4 s = make_float4(0.f, 0.f, 0.f, 0.f);
#pragma unroll 4
    for (int p = 0; p < RGRP; p++) {
      const float4 v = *(const float4*)&part[(size_t)(g0 + p) * 16384 + e];
      s.x += v.x;
      s.y += v.y;
      s.z += v.z;
      s.w += v.w;
    }
    atomicAdd(&G[e], s.x);
    atomicAdd(&G[e + 1], s.y);
    atomicAdd(&G[e + 2], s.z);
    atomicAdd(&G[e + 3], s.w);
    return;
  }
  const int b2 = b - NRED;
  const bool A = b2 < lnA;
  const int lb = A ? b2 : b2 - lnA;
  const float* conv = A ? convA : convB;
  const float* resid = A ? residA : residB;
  float* out = A ? outA : outB;
  const int rows = A ? nA : nBm;
  const int w = (lb * 256 + t) >> 6;
  const int lane = t & 63;
  if (w >= rows) return;
  const float2 v = ((const float2*)conv)[(size_t)w * 64 + lane];
  const float m = wave_sum(v.x + v.y) * (1.f / 128.f);
  const float q = wave_sum(fmaf(v.x, v.x, v.y * v.y)) * (1.f / 128.f);
  const float rstd = rsqrtf(q - m * m + 1e-5f);
  const float2 gg = ((const float2*)g)[lane];
  const float2 bb = ((const float2*)bvec)[lane];
  const float2 rr = ((const float2*)resid)[(size_t)w * 64 + lane];
  float y0 = fmaf(gg.x, (v.x - m) * rstd, bb.x);
  float y1 = fmaf(gg.y, (v.y - m) * rstd, bb.y);
  y0 = 0.5f * y0 * (1.f + erff(y0 * 0.7071067811865476f));
  y1 = 0.5f * y1 * (1.f + erff(y1 * 0.7071067811865476f));
  float2 o;
  o.x = y0 + rr.x;
  o.y = y1 + rr.y;
  ((float2*)out)[(size_t)w * 64 + lane] = o;
}

// ---- barlow finalize + segment pooling, one launch ----
__global__ __launch_bounds__(256) void fused_fin_pool(
    const float* __restrict__ G1, const float* __restrict__ G2,
    const float* __restrict__ st, float nA, float nB, float* outbt,
    const float* __restrict__ ZA, const int* __restrict__ bidxA, int n, int spA,
    float* poolA, const float* __restrict__ ZB, const int* __restrict__ bidxB, int m,
    float* poolB) {
  __shared__ float s1s[128], m1s[128], s2s[128], m2s[128];
  __shared__ float red[256];
  const int b = blockIdx.x;
  const int t = threadIdx.x;
  if (b < 2) {
    const bool A = b == 0;
    const float* G = A ? G1 : G2;
    const float* sum1 = st + (A ? 0 : 512);
    const float* ssq1 = sum1 + 128;
    const float* sum2 = sum1 + 256;
    const float* ssq2 = sum1 + 384;
    const float nn = A ? nA : nB;
    if (t < 128) {
      const float inv_n = 1.f / nn;
      const float bnf = (nn - 1.f) * inv_n + 1e-5f;
      float mu = sum1[t] * inv_n;
      float vu = (ssq1[t] * inv_n - mu * mu) * nn / (nn - 1.f);
      s1s[t] = rsqrtf(vu * bnf);
      m1s[t] = mu;
      mu = sum2[t] * inv_n;
      vu = (ssq2[t] * inv_n - mu * mu) * nn / (nn - 1.f);
      s2s[t] = rsqrtf(vu * bnf);
      m2s[t] = mu;
    }
    __syncthreads();
    float on = 0.f, off = 0.f;
    for (int idx = t; idx < 16384; idx += 256) {
      const int i = idx >> 7, j = idx & 127;
      const float c = s1s[i] * s2s[j] * (G[idx] - nn * m1s[i] * m2s[j]) * (1.f / 32.f);
      if (i == j) {
        const float dd = c - 1.f;
        on += dd * dd;
      } else {
        off += c * c;
      }
    }
    red[t] = on + 0.005f * off;
    __syncthreads();
    for (int s = 128; s; s >>= 1) {
      if (t < s) red[t] += red[t + s];
      __syncthreads();
    }
    if (t == 0) atomicAdd(outbt, red[0]);
    return;
  }
  const int pb = b - 2;
  const bool A = pb < spA;
  const int lb = A ? pb : pb - spA;
  const float* Z = A ? ZA : ZB;
  const int* bidx = A ? bidxA : bidxB;
  const int n2 = A ? n : m;
  float* pool = A ? poolA : poolB;
  const int c = t & 127;
  const int h = t >> 7;
  const int r0 = lb * 128 + h * 64;
  const int re = min(lb * 128 + (h + 1) * 64, n2);
  if (r0 >= n2) return;
  float acc = 0.f;
  int cur = bidx[r0];
  for (int r = r0; r < re; r++) {
    const int bb = bidx[r];
    if (bb != cur) {
      atomicAdd(&pool[cur * 128 + c], acc);
      acc = 0.f;
      cur = bb;
    }
    acc += Z[(size_t)r * 128 + c];
  }
  atomicAdd(&pool[cur * 128 + c], acc);
}

__global__ __launch_bounds__(128) void graph_gemm(
    const float* __restrict__ zg, const float* __restrict__ eg,
    const int* __restrict__ cnz, const int* __restrict__ cne,
    const float* __restrict__ Wf, const float* __restrict__ bf, float* out) {
  __shared__ float cat[256];
  const int g = blockIdx.x, t = threadIdx.x;
  cat[t] = zg[g * 128 + t] / fmaxf((float)cnz[g], 1.f);
  cat[128 + t] = eg[g * 128 + t] / fmaxf((float)cne[g], 1.f);
  __syncthreads();
  float acc = bf[t];
#pragma unroll 8
  for (int k = 0; k < 256; k++) acc = fmaf(cat[k], Wf[k * 128 + t], acc);
  out[g * 128 + t] = acc;
}

extern "C" void kernel_launch(void* const* d_in, const int* in_sizes, int n_in,
                              void* d_out, int out_size, void* d_ws, size_t ws_size,
                              hipStream_t stream) {
  const float* x = (const float*)d_in[0];
  const float* hf = (const float*)d_in[1];
  const float* coord = (const float*)d_in[2];
  const int* ni = (const int*)d_in[3];
  const int* ei = (const int*)d_in[4];
  const int* nb = (const int*)d_in[5];
  const int* hb = (const int*)d_in[6];
  const int* xx = (const int*)d_in[7];
  const int* ee = (const int*)d_in[8];
  const float* Wv = (const float*)d_in[10];
  const float* bv = (const float*)d_in[11];
  const float* We = (const float*)d_in[12];
  const float* be = (const float*)d_in[13];
  const float* Wx = (const float*)d_in[14];
  const float* bx = (const float*)d_in[15];
  const float* Weg = (const float*)d_in[16];
  const float* beg = (const float*)d_in[17];
  const float* lng = (const float*)d_in[18];
  const float* lnb = (const float*)d_in[19];
  const float* Wf = (const float*)d_in[20];
  const float* bf = (const float*)d_in[21];

  const int N = in_sizes[0] / 128;
  const int M = in_sizes[1] / 128;
  const int NNZ = in_sizes[3];
  const int EG = in_sizes[7] / 2;
  const int EE = in_sizes[8] / 2;

  float* ws = (float*)d_ws;
  size_t o = 0;
  float* xw = ws + o;     o += (size_t)N * 128;  // dead by gram time -> gpart alias
  float* ew = ws + o;     o += (size_t)M * 128;
  unsigned short* xw2 = (unsigned short*)(ws + o); o += (size_t)N * 64;  // bf16
  unsigned short* ew2 = (unsigned short*)(ws + o); o += (size_t)M * 64;  // bf16
  float* z_conv = ws + o; o += (size_t)N * 128;
  float* e_conv = ws + o; o += (size_t)M * 128;
  float* rs_gx = ws + o;  o += N;
  float* rs_ge = ws + o;  o += M;
  const size_t fz0 = o;  // zeroed float block
  float* ecoord = ws + o; o += (size_t)M * 3;  // accumulated by atomics in stage1
  float* G1 = ws + o;     o += 16384;          // accumulated by fused_reduce_ln
  float* G2 = ws + o;     o += 16384;
  float* st = ws + o;     o += 1024;
  float* zg = ws + o;     o += NB * 128;
  float* eg_p = ws + o;   o += NB * 128;
  const size_t fz1 = o;
  int* wsi = (int*)(ws + o);
  size_t oi = 0;
  int* cnt_n = wsi + oi;  oi += N;  // zeroed: counts after stage1
  int* cnt_e = wsi + oi;  oi += M;
  int* cnt_gx = wsi + oi; oi += N;
  int* cnt_ge = wsi + oi; oi += M;
  const size_t iz1 = oi;
  int* rp_n = wsi + oi;   oi += N + 1;
  int* rp_e = wsi + oi;   oi += M + 1;
  int* rp_gx = wsi + oi;  oi += N + 1;
  int* rp_ge = wsi + oi;  oi += M + 1;
  int* adj_n = wsi + oi;  oi += NNZ;
  int* adj_e = wsi + oi;  oi += NNZ;
  int* adj_gx = wsi + oi; oi += EG;
  int* adj_ge = wsi + oi; oi += EE;
  int* rank_pn = wsi + oi; oi += NNZ;
  int* rank_pe = wsi + oi; oi += NNZ;
  int* rank_g = wsi + oi;  oi += EG;
  int* rank_h = wsi + oi;  oi += EE;
  int* cbn = wsi + oi;    oi += NB;
  int* cbe = wsi + oi;    oi += NB;
  int* bsums = wsi + oi;  oi += 64;
  int* bbase = wsi + oi;  oi += 64;
  int* totals = wsi + oi; oi += 4;

  // gram partials alias the dead xw..ew2 region: need (GPN+GPM)*16384 = 10.49M
  // floats; available xw(6.4M)+ew(1.28M)+xw2b(3.2M)+ew2b(0.64M) = 11.52M floats.
  float* gpartA = xw;                        // GPN*16384 floats
  float* gpartB = xw + (size_t)GPN * 16384;  // GPM*16384 floats

  float* outz = (float*)d_out;           // temporarily z_imp
  float* oute = outz + (size_t)N * 128;  // temporarily e_imp
  float* outc = oute + (size_t)M * 128;
  float* outg = outc + (size_t)N * 3;
  float* outbt = outg + NB * 128;

  hipMemsetAsync(ws + fz0, 0, (fz1 - fz0) * 4, stream);
  hipMemsetAsync(wsi, 0, iz1 * 4, stream);
  hipMemsetAsync(outbt, 0, 4, stream);

  // stage 1: GEMMs || count/rank || ecoord COO sum
  const int nbGN = (N + 63) / 64, nbGM = (M + 63) / 64;
  const int tot = NNZ + EG + EE;
  const int nbCnt = (tot + 1023) >> 10;
  fused_stage1<<<nbGN + nbGM + nbCnt, 256, 0, stream>>>(
      x, Wv, bv, xw, Wx, xw2, N, nbGN, hf, We, be, ew, Weg, ew2, M, nbGM, ni, ei, NNZ,
      xx, EG, ee, EE, cnt_n, cnt_e, cnt_gx, cnt_ge, rank_pn, rank_pe, rank_g, rank_h,
      coord, ecoord);

  // scans (+ ecoord divide folded into array-1 pass)
  const int nb0 = (N + 4095) >> 12, nb1 = (M + 4095) >> 12;
  const int sgrid = 2 * nb0 + 2 * nb1;
  scan_partial<<<sgrid, 256, 0, stream>>>(cnt_n, N, cnt_e, M, cnt_gx, N, cnt_ge, M,
                                          nb0, nb1, nb0, nb1, bsums);
  scan_bsums<<<1, 64, 0, stream>>>(bsums, nb0, nb1, nb0, nb1, bbase, totals);
  scan_final<<<sgrid, 256, 0, stream>>>(
      cnt_n, rp_n, nullptr, nullptr, N, cnt_e, rp_e, nullptr, ecoord, M, cnt_gx,
      rp_gx, rs_gx, nullptr, N, cnt_ge, rp_ge, rs_ge, nullptr, M, nb0, nb1, nb0, nb1,
      bbase, totals);

  // fill (atomic-free) || batch counts
  const int nbFill = (tot + 1023) >> 10;
  fused_fill<<<nbFill + 2, 256, 0, stream>>>(
      ni, ei, NNZ, xx, EG, ee, EE, rp_n, rp_e, rp_gx, rp_ge, rank_pn, rank_pe, rank_g,
      rank_h, adj_n, adj_e, adj_gx, adj_ge, nbFill, nb, N, cbn, hb, M, cbe);

  // all gathers in one launch
  const int nbNode = (N + 3) / 4, nbGcnN = (N + 3) / 4, nbGcnM = (M + 3) / 4,
            nbHedge = (M + 3) / 4;
  fused_gathers<<<nbNode + nbGcnN + nbGcnM + nbHedge, 256, 0, stream>>>(
      ew, xw, coord, ecoord, rp_n, adj_n, z_conv, outc, N, nbNode, xw2, rp_gx, adj_gx,
      rs_gx, bx, outz, nbGcnN, ew2, rp_ge, adj_ge, rs_ge, beg, oute, M, nbGcnM, rp_e,
      adj_e, e_conv);

  // barlow gram partials (xw..ew2 dead now)
  gram_partial2<<<GPN + GPM, 256, 0, stream>>>(outz, z_conv, N, gpartA, oute, e_conv,
                                               M, gpartB, st, GPN);

  // gram reduce || layernorm+gelu+residual
  const int lnA = (N + 3) / 4;
  fused_reduce_ln<<<(GPN / RGRP + GPM / RGRP) * 16 + lnA + (M + 3) / 4, 256, 0,
                    stream>>>(gpartA, G1, gpartB, G2, z_conv, x, outz, N, lnA, e_conv,
                              hf, oute, M, lng, lnb);

  // barlow finalize || segment pooling
  const int spA = (N + 127) / 128, spB = (M + 127) / 128;
  fused_fin_pool<<<2 + spA + spB, 256, 0, stream>>>(G1, G2, st, (float)N, (float)M,
                                                    outbt, outz, nb, N, spA, zg, oute,
                                                    hb, M, eg_p);

  graph_gemm<<<NB, 128, 0, stream>>>(zg, eg_p, cbn, cbe, Wf, bf, outg);
}